// Round 4
// baseline (7208.967 us; speedup 1.0000x reference)
//
#include <hip/hip_runtime.h>
#include <math.h>

// ---------------------------------------------------------------------------
// PointNet++ part-seg forward. All features stored point-major: row = point,
// C contiguous floats per row. B=4, N=8192 fixed by the problem.
// ---------------------------------------------------------------------------

// ---------------- workspace layout (bytes) ----------------
static constexpr size_t O_FEATS0 = 0;                    // (4*8192, 64)  f32
static constexpr size_t O_FEATS1 = 8388608;              // (4*2048, 128)
static constexpr size_t O_FEATS2 = 12582912;             // (4*1024, 256)
static constexpr size_t O_FP0OUT = 16777216;             // (4*2048, 512)
static constexpr size_t O_XYZ1   = 33554432;             // (4*2048, 3)
static constexpr size_t O_XYZ2   = 33652736;             // (4*1024, 3)
static constexpr size_t O_FPS1   = 33701888;             // (4*2048) int
static constexpr size_t O_FPS2   = 33734656;             // (4*1024) int
static constexpr size_t O_BALL1  = 33751040;             // (4*2048*32) int
static constexpr size_t O_BALL2  = 34799616;             // (4*1024*32) int
static constexpr size_t O_NN0I   = 35323904;             // (4*2048*3) int
static constexpr size_t O_NN0W   = 35422208;             // (4*2048*3) f32
static constexpr size_t O_NN1I   = 35520512;             // (4*8192*3) int
static constexpr size_t O_NN1W   = 35913728;             // (4*8192*3) f32
static constexpr size_t O_REG0   = 36306944;             // 67108864 scratch
static constexpr size_t O_REG1   = 103415808;            // 67108864 scratch
static constexpr size_t WS_NEED  = 170524672;

// ---------------- emb: xyz -> relu(bn(W2*relu(bn(W1*xyz)))) ----------------
__global__ __launch_bounds__(256) void emb_kernel(
    const float* __restrict__ xyz, const float* __restrict__ w1,
    const float* __restrict__ g1, const float* __restrict__ b1,
    const float* __restrict__ w2, const float* __restrict__ g2,
    const float* __restrict__ b2, float* __restrict__ out) {
  const int t = threadIdx.x;
  const int o = t & 63, pl = t >> 6;
  const int pt = blockIdx.x * 4 + pl;
  const float x0 = xyz[(size_t)pt * 3 + 0];
  const float x1 = xyz[(size_t)pt * 3 + 1];
  const float x2 = xyz[(size_t)pt * 3 + 2];
  const float SQ = sqrtf(1.0f + 1e-5f);
  float v = w1[o * 3 + 0] * x0 + w1[o * 3 + 1] * x1 + w1[o * 3 + 2] * x2;
  v = fmaxf(v * (g1[o] / SQ) + b1[o], 0.0f);
  __shared__ float h[4][64];
  h[pl][o] = v;
  __syncthreads();
  float acc = 0.0f;
  #pragma unroll 8
  for (int i = 0; i < 64; ++i) acc += w2[o * 64 + i] * h[pl][i];
  float y = fmaxf(acc * (g2[o] / SQ) + b2[o], 0.0f);
  out[(size_t)pt * 64 + o] = y;
}

// ---------------- packed f32 helpers (VOP3P, IEEE RN per half) -------------
typedef float v2f __attribute__((ext_vector_type(2)));
__device__ __forceinline__ v2f pk_sub(v2f a, v2f b) {
  v2f d;
  asm("v_pk_add_f32 %0, %1, %2 neg_lo:[0,1] neg_hi:[0,1]"
      : "=v"(d) : "v"(a), "v"(b));
  return d;
}
__device__ __forceinline__ v2f pk_mul(v2f a, v2f b) {
  v2f d;
  asm("v_pk_mul_f32 %0, %1, %2" : "=v"(d) : "v"(a), "v"(b));
  return d;
}
__device__ __forceinline__ v2f pk_add(v2f a, v2f b) {
  v2f d;
  asm("v_pk_add_f32 %0, %1, %2" : "=v"(d) : "v"(a), "v"(b));
  return d;
}

// ---------------- farthest point sampling ----------------
// 1024 threads per batch. Packed-f32 distance update (bit-exact vs scalar:
// separate mul/add rounding, no FMA). Per-thread argmax = float max tree +
// equality index select (first occurrence). Cross-lane argmax via packed
// u64 key = bits(d)<<32 | ~idx (d>=0 so float bits are order-monotone;
// tie -> min idx, matching jnp.argmax). One barrier per iteration: 16 wave
// winners in parity-double-buffered LDS; each thread reads ONE key
// (broadcast) and a 4-stage butterfly converges all lanes. Winner coords
// come from a single broadcast ds_read_b128 on float4-packed LDS.
template <int N, int NP>
__global__ __launch_bounds__(1024, 1) void fps_kernel(
    const float* __restrict__ xyz, int* __restrict__ out) {
  constexpr int PPT = N / 1024;
  constexpr int PAIRS = PPT / 2;
  const int b = blockIdx.x, t = threadIdx.x;
  const float* xb = xyz + (size_t)b * N * 3;
  __shared__ float4 sxyz[N];
  __shared__ unsigned long long skey[2][16];
  for (int i = t; i < N; i += 1024)
    sxyz[i] = make_float4(xb[i * 3 + 0], xb[i * 3 + 1], xb[i * 3 + 2], 0.0f);
  __syncthreads();
  v2f px[PAIRS], py[PAIRS], pz[PAIRS], dst2[PAIRS];
  #pragma unroll
  for (int k = 0; k < PAIRS; ++k) {
    const float4 a = sxyz[t * PPT + 2 * k];
    const float4 c = sxyz[t * PPT + 2 * k + 1];
    px[k] = (v2f){a.x, c.x};
    py[k] = (v2f){a.y, c.y};
    pz[k] = (v2f){a.z, c.z};
    dst2[k] = (v2f){1e10f, 1e10f};
  }
  const int wid = t >> 6, lane = t & 63;
  int far = 0;
  float4 cc = sxyz[0];
  for (int it = 0; it < NP; ++it) {
    if (t == 0) out[(size_t)b * NP + it] = far;
    const v2f c2x = (v2f){cc.x, cc.x};
    const v2f c2y = (v2f){cc.y, cc.y};
    const v2f c2z = (v2f){cc.z, cc.z};
    float nds[PPT];
    #pragma unroll
    for (int k = 0; k < PAIRS; ++k) {
      const v2f dx = pk_sub(px[k], c2x);
      const v2f dy = pk_sub(py[k], c2y);
      const v2f dz = pk_sub(pz[k], c2z);
      const v2f d =
          pk_add(pk_add(pk_mul(dx, dx), pk_mul(dy, dy)), pk_mul(dz, dz));
      v2f nd;
      nd.x = fminf(dst2[k].x, d.x);
      nd.y = fminf(dst2[k].y, d.y);
      dst2[k] = nd;
      nds[2 * k] = nd.x;
      nds[2 * k + 1] = nd.y;
    }
    float bv = nds[0];
    #pragma unroll
    for (int j = 1; j < PPT; ++j) bv = fmaxf(bv, nds[j]);
    int bjl = 0;
    #pragma unroll
    for (int j = PPT - 1; j >= 0; --j) bjl = (nds[j] == bv) ? j : bjl;
    unsigned long long bk =
        ((unsigned long long)__float_as_uint(bv) << 32) |
        (unsigned long long)(unsigned)(~(unsigned)(t * PPT + bjl));
    #pragma unroll
    for (int m = 32; m >= 1; m >>= 1) {
      const unsigned long long ok = __shfl_xor(bk, m, 64);
      bk = (ok > bk) ? ok : bk;
    }
    const int p = it & 1;
    if (lane == 0) skey[p][wid] = bk;
    __syncthreads();
    unsigned long long wk = skey[p][lane & 15];
    #pragma unroll
    for (int m = 1; m <= 8; m <<= 1) {
      const unsigned long long ok = __shfl_xor(wk, m, 64);
      wk = (ok > wk) ? ok : wk;
    }
    far = (int)(~(unsigned)wk);
    cc = sxyz[far];
  }
}

// ---------------- gather xyz by index ----------------
__global__ __launch_bounds__(256) void gatherxyz_kernel(
    const float* __restrict__ xyz, const int* __restrict__ idx,
    float* __restrict__ out, int sbits, int N) {
  const int id = blockIdx.x * 256 + threadIdx.x;
  const int b = id >> sbits;
  const int n = idx[id];
  out[(size_t)id * 3 + 0] = xyz[((size_t)b * N + n) * 3 + 0];
  out[(size_t)id * 3 + 1] = xyz[((size_t)b * N + n) * 3 + 1];
  out[(size_t)id * 3 + 2] = xyz[((size_t)b * N + n) * 3 + 2];
}

// ---------------- ball query: first 32 indices with d2 <= 1 ----------------
__global__ __launch_bounds__(256) void ball_kernel(
    const float* __restrict__ xyz, const float* __restrict__ ctr,
    int* __restrict__ out, int sbits, int N) {
  const int t = threadIdx.x;
  const int lane = t & 63, wid = t >> 6;
  const int wg = blockIdx.x * 4 + wid;   // global center id
  const int b = wg >> sbits;
  __shared__ int lists[4][32];
  const float cx = ctr[(size_t)wg * 3 + 0];
  const float cy = ctr[(size_t)wg * 3 + 1];
  const float cz = ctr[(size_t)wg * 3 + 2];
  const float an = __fadd_rn(__fadd_rn(__fmul_rn(cx, cx), __fmul_rn(cy, cy)),
                             __fmul_rn(cz, cz));
  int fill = 0;
  for (int ch = 0; ch < (N >> 6) && fill < 32; ++ch) {
    const int n = ch * 64 + lane;
    const float bx = xyz[((size_t)b * N + n) * 3 + 0];
    const float by = xyz[((size_t)b * N + n) * 3 + 1];
    const float bz = xyz[((size_t)b * N + n) * 3 + 2];
    const float bb = __fadd_rn(__fadd_rn(__fmul_rn(bx, bx), __fmul_rn(by, by)),
                               __fmul_rn(bz, bz));
    const float dot = __fadd_rn(__fadd_rn(__fmul_rn(cx, bx), __fmul_rn(cy, by)),
                                __fmul_rn(cz, bz));
    const float d2 = __fsub_rn(__fadd_rn(an, bb), __fmul_rn(2.0f, dot));
    const bool q = (d2 <= 1.0f);
    const unsigned long long mask = __ballot(q);
    if (q) {
      const int pos = fill + __popcll(mask & ((1ull << lane) - 1ull));
      if (pos < 32) lists[wid][pos] = n;
    }
    fill += (int)__popcll(mask);
  }
  __syncthreads();
  if (lane < 32) {
    int v = lists[wid][0];
    if (lane < fill) v = lists[wid][lane];
    out[(size_t)wg * 32 + lane] = v;
  }
}

// ---------------- grouped feature materialization ----------------
// row (chunk-local) -> [f[src]-f[ctr] (Cf) ; f[ctr] (Cf)]
__global__ __launch_bounds__(256) void groupmat_kernel(
    float* __restrict__ Xo, const float* __restrict__ f,
    const int* __restrict__ ball, const int* __restrict__ fps, int g0, int Cf,
    int c4bits, int sbits, int Npts) {
  const int id = blockIdx.x * 256 + threadIdx.x;
  const int c4mask = (1 << c4bits) - 1;
  const int row = id >> c4bits;
  const int col = (id & c4mask) * 4;
  const int gl = g0 + (row >> 5);
  const int k = row & 31;
  const int b = gl >> sbits;
  const int src = ball[(size_t)gl * 32 + k];
  const int ctr = fps[gl];
  const int C = Cf * 2;
  const float* fb = f + (size_t)b * Npts * Cf;
  float4 v;
  if (col < Cf) {
    const float4 a = *(const float4*)(fb + (size_t)src * Cf + col);
    const float4 c = *(const float4*)(fb + (size_t)ctr * Cf + col);
    v = make_float4(a.x - c.x, a.y - c.y, a.z - c.z, a.w - c.w);
  } else {
    v = *(const float4*)(fb + (size_t)ctr * Cf + (col - Cf));
  }
  *(float4*)(Xo + (size_t)row * C + col) = v;
}

// ---------------- generic 1x1 conv (GEMM) with BN/bias/ReLU epilogue -------
// Y[(m), o] = relu( (sum_i X[m,i] W[o,i] + bias[o]) * g[o]/sqrt(1+eps) + beta[o] )
__global__ __launch_bounds__(256) void conv_kernel(
    const float* __restrict__ X, const float* __restrict__ W,
    float* __restrict__ Y, int C, int O, const float* __restrict__ gamma,
    const float* __restrict__ beta, const float* __restrict__ bias, int relu) {
  __shared__ float Xs[16][132];
  __shared__ float Ws[16][132];
  const int t = threadIdx.x;
  const size_t m0 = (size_t)blockIdx.x * 128;
  const int o0 = blockIdx.y * 128;
  const int r0 = t >> 2;
  const int cq0 = (t & 3) * 4;
  const int mq = t & 15, nq = t >> 4;
  float acc[8][8];
  #pragma unroll
  for (int i = 0; i < 8; ++i)
    #pragma unroll
    for (int j = 0; j < 8; ++j) acc[i][j] = 0.0f;

  for (int kk = 0; kk < C; kk += 16) {
    const float4 xa = *(const float4*)(X + (m0 + r0) * C + kk + cq0);
    const float4 xb = *(const float4*)(X + (m0 + r0 + 64) * C + kk + cq0);
    const float4 wa = *(const float4*)(W + (size_t)(o0 + r0) * C + kk + cq0);
    const float4 wb = *(const float4*)(W + (size_t)(o0 + r0 + 64) * C + kk + cq0);
    __syncthreads();
    Xs[cq0 + 0][r0] = xa.x; Xs[cq0 + 1][r0] = xa.y;
    Xs[cq0 + 2][r0] = xa.z; Xs[cq0 + 3][r0] = xa.w;
    Xs[cq0 + 0][r0 + 64] = xb.x; Xs[cq0 + 1][r0 + 64] = xb.y;
    Xs[cq0 + 2][r0 + 64] = xb.z; Xs[cq0 + 3][r0 + 64] = xb.w;
    Ws[cq0 + 0][r0] = wa.x; Ws[cq0 + 1][r0] = wa.y;
    Ws[cq0 + 2][r0] = wa.z; Ws[cq0 + 3][r0] = wa.w;
    Ws[cq0 + 0][r0 + 64] = wb.x; Ws[cq0 + 1][r0 + 64] = wb.y;
    Ws[cq0 + 2][r0 + 64] = wb.z; Ws[cq0 + 3][r0 + 64] = wb.w;
    __syncthreads();
    #pragma unroll
    for (int k = 0; k < 16; ++k) {
      const float4 a0 = *(const float4*)&Xs[k][mq * 8];
      const float4 a1 = *(const float4*)&Xs[k][mq * 8 + 4];
      const float4 b0 = *(const float4*)&Ws[k][nq * 8];
      const float4 b1 = *(const float4*)&Ws[k][nq * 8 + 4];
      const float am[8] = {a0.x, a0.y, a0.z, a0.w, a1.x, a1.y, a1.z, a1.w};
      const float bm[8] = {b0.x, b0.y, b0.z, b0.w, b1.x, b1.y, b1.z, b1.w};
      #pragma unroll
      for (int i = 0; i < 8; ++i)
        #pragma unroll
        for (int j = 0; j < 8; ++j) acc[i][j] += am[i] * bm[j];
    }
  }

  const float SQ = sqrtf(1.0f + 1e-5f);
  float s[8], sh[8];
  #pragma unroll
  for (int j = 0; j < 8; ++j) {
    const int o = o0 + nq * 8 + j;
    const float sc = gamma ? (gamma[o] / SQ) : 1.0f;
    float bb = beta ? beta[o] : 0.0f;
    if (bias) bb = bb + bias[o] * sc;
    s[j] = sc; sh[j] = bb;
  }
  #pragma unroll
  for (int i = 0; i < 8; ++i) {
    float y[8];
    #pragma unroll
    for (int j = 0; j < 8; ++j) {
      float v = acc[i][j] * s[j] + sh[j];
      y[j] = relu ? fmaxf(v, 0.0f) : v;
    }
    const size_t off = (m0 + mq * 8 + i) * O + o0 + nq * 8;
    *(float4*)(Y + off) = make_float4(y[0], y[1], y[2], y[3]);
    *(float4*)(Y + off + 4) = make_float4(y[4], y[5], y[6], y[7]);
  }
}

// ---------------- segmented max over 32 samples ----------------
__global__ __launch_bounds__(256) void segmax_kernel(
    const float* __restrict__ Y, float* __restrict__ F, int O, int obits) {
  const int id = blockIdx.x * 256 + threadIdx.x;
  const int g = id >> obits;
  const int o = id & (O - 1);
  float m = -3.4e38f;
  #pragma unroll 8
  for (int k = 0; k < 32; ++k)
    m = fmaxf(m, Y[((size_t)g * 32 + k) * O + o]);
  F[(size_t)g * O + o] = m;
}

// ---------------- 3-NN search (stable, strict <) ----------------
__global__ __launch_bounds__(256) void nn3_kernel(
    const float* __restrict__ txyz, const float* __restrict__ sxyz,
    int* __restrict__ oi, float* __restrict__ ow, int s1bits, int S2) {
  __shared__ float ss[6144];
  const int t = threadIdx.x;
  const int row = blockIdx.x * 256 + t;
  const int b = row >> s1bits;
  for (int i = t; i < S2 * 3; i += 256) ss[i] = sxyz[(size_t)b * S2 * 3 + i];
  __syncthreads();
  const float ax = txyz[(size_t)row * 3 + 0];
  const float ay = txyz[(size_t)row * 3 + 1];
  const float az = txyz[(size_t)row * 3 + 2];
  const float an = __fadd_rn(__fadd_rn(__fmul_rn(ax, ax), __fmul_rn(ay, ay)),
                             __fmul_rn(az, az));
  float d0 = 3.4e38f, d1 = 3.4e38f, d2v = 3.4e38f;
  int i0 = 0, i1 = 0, i2 = 0;
  for (int j = 0; j < S2; ++j) {
    const float bx = ss[j * 3 + 0], by = ss[j * 3 + 1], bz = ss[j * 3 + 2];
    const float bb = __fadd_rn(__fadd_rn(__fmul_rn(bx, bx), __fmul_rn(by, by)),
                               __fmul_rn(bz, bz));
    const float dot = __fadd_rn(__fadd_rn(__fmul_rn(ax, bx), __fmul_rn(ay, by)),
                                __fmul_rn(az, bz));
    const float dd = __fsub_rn(__fadd_rn(an, bb), __fmul_rn(2.0f, dot));
    if (dd < d0) {
      d2v = d1; i2 = i1; d1 = d0; i1 = i0; d0 = dd; i0 = j;
    } else if (dd < d1) {
      d2v = d1; i2 = i1; d1 = dd; i1 = j;
    } else if (dd < d2v) {
      d2v = dd; i2 = j;
    }
  }
  const float r0 = 1.0f / (d0 + 1e-8f);
  const float r1 = 1.0f / (d1 + 1e-8f);
  const float r2 = 1.0f / (d2v + 1e-8f);
  const float sum = __fadd_rn(__fadd_rn(r0, r1), r2);
  oi[(size_t)row * 3 + 0] = i0;
  oi[(size_t)row * 3 + 1] = i1;
  oi[(size_t)row * 3 + 2] = i2;
  ow[(size_t)row * 3 + 0] = r0 / sum;
  ow[(size_t)row * 3 + 1] = r1 / sum;
  ow[(size_t)row * 3 + 2] = r2 / sum;
}

// ---------------- weighted 3-point interpolation into concat columns -------
__global__ __launch_bounds__(256) void interp_kernel(
    float* __restrict__ dst, int CT, int c0, const float* __restrict__ src,
    const int* __restrict__ idx, const float* __restrict__ w, int csbits,
    int s1bits, int S2) {
  const int id = blockIdx.x * 256 + threadIdx.x;
  const int row = id >> csbits;
  const int c4 = (id & ((1 << csbits) - 1)) * 4;
  const int Cs = 4 << csbits;
  const int b = row >> s1bits;
  const int j0 = idx[(size_t)row * 3 + 0];
  const int j1 = idx[(size_t)row * 3 + 1];
  const int j2 = idx[(size_t)row * 3 + 2];
  const float w0 = w[(size_t)row * 3 + 0];
  const float w1 = w[(size_t)row * 3 + 1];
  const float w2 = w[(size_t)row * 3 + 2];
  const float4 f0 = *(const float4*)(src + ((size_t)b * S2 + j0) * Cs + c4);
  const float4 f1 = *(const float4*)(src + ((size_t)b * S2 + j1) * Cs + c4);
  const float4 f2 = *(const float4*)(src + ((size_t)b * S2 + j2) * Cs + c4);
  float4 v;
  v.x = f0.x * w0 + f1.x * w1 + f2.x * w2;
  v.y = f0.y * w0 + f1.y * w1 + f2.y * w2;
  v.z = f0.z * w0 + f1.z * w1 + f2.z * w2;
  v.w = f0.w * w0 + f1.w * w1 + f2.w * w2;
  *(float4*)(dst + (size_t)row * CT + c0 + c4) = v;
}

// ---------------- copy columns into concat buffer ----------------
__global__ __launch_bounds__(256) void copycols_kernel(
    float* __restrict__ dst, int CT, int c0, const float* __restrict__ src,
    int csbits) {
  const int id = blockIdx.x * 256 + threadIdx.x;
  const int row = id >> csbits;
  const int c4 = (id & ((1 << csbits) - 1)) * 4;
  const int Cs = 4 << csbits;
  const float4 v = *(const float4*)(src + (size_t)row * Cs + c4);
  *(float4*)(dst + (size_t)row * CT + c0 + c4) = v;
}

// ---------------- final 128->8 conv + bias, point-major out ----------------
__global__ __launch_bounds__(256) void outfinal_kernel(
    const float* __restrict__ X, const float* __restrict__ Wt,
    const float* __restrict__ bias, float* __restrict__ out) {
  __shared__ float Xs[32][132];
  const int t = threadIdx.x;
  const int p0 = blockIdx.x * 32;
  #pragma unroll
  for (int q = 0; q < 4; ++q) {
    const int id = t + q * 256;
    const int r = id >> 5, c4 = (id & 31) * 4;
    const float4 v = *(const float4*)(X + (size_t)(p0 + r) * 128 + c4);
    Xs[r][c4 + 0] = v.x; Xs[r][c4 + 1] = v.y;
    Xs[r][c4 + 2] = v.z; Xs[r][c4 + 3] = v.w;
  }
  __syncthreads();
  const int p = t >> 3, o = t & 7;
  float acc = 0.0f;
  #pragma unroll 8
  for (int i = 0; i < 128; ++i) acc += Wt[o * 128 + i] * Xs[p][i];
  out[(size_t)(p0 + p) * 8 + o] = acc + bias[o];
}

// ---------------------------------------------------------------------------
extern "C" void kernel_launch(void* const* d_in, const int* in_sizes, int n_in,
                              void* d_out, int out_size, void* d_ws,
                              size_t ws_size, hipStream_t stream) {
  const float* x       = (const float*)d_in[0];
  const float* w_emb1  = (const float*)d_in[1];
  const float* g_emb1  = (const float*)d_in[2];
  const float* be_emb1 = (const float*)d_in[3];
  const float* w_emb2  = (const float*)d_in[4];
  const float* g_emb2  = (const float*)d_in[5];
  const float* be_emb2 = (const float*)d_in[6];
  const float* l0_w1 = (const float*)d_in[7];
  const float* l0_g1 = (const float*)d_in[8];
  const float* l0_b1 = (const float*)d_in[9];
  const float* l0_w2 = (const float*)d_in[10];
  const float* l0_g2 = (const float*)d_in[11];
  const float* l0_b2 = (const float*)d_in[12];
  const float* l1_w1 = (const float*)d_in[13];
  const float* l1_g1 = (const float*)d_in[14];
  const float* l1_b1 = (const float*)d_in[15];
  const float* l1_w2 = (const float*)d_in[16];
  const float* l1_g2 = (const float*)d_in[17];
  const float* l1_b2 = (const float*)d_in[18];
  const float* f0_w1 = (const float*)d_in[19];
  const float* f0_g1 = (const float*)d_in[20];
  const float* f0_b1 = (const float*)d_in[21];
  const float* f0_w2 = (const float*)d_in[22];
  const float* f0_g2 = (const float*)d_in[23];
  const float* f0_b2 = (const float*)d_in[24];
  const float* f1_w1 = (const float*)d_in[25];
  const float* f1_g1 = (const float*)d_in[26];
  const float* f1_b1 = (const float*)d_in[27];
  const float* f1_w2 = (const float*)d_in[28];
  const float* f1_g2 = (const float*)d_in[29];
  const float* f1_b2 = (const float*)d_in[30];
  const float* c1_w    = (const float*)d_in[31];
  const float* c1_bias = (const float*)d_in[32];
  const float* c1_g    = (const float*)d_in[33];
  const float* c1_beta = (const float*)d_in[34];
  const float* c2_w    = (const float*)d_in[35];
  const float* c2_bias = (const float*)d_in[36];
  const float* c2_g    = (const float*)d_in[37];
  const float* c2_beta = (const float*)d_in[38];
  const float* out_w    = (const float*)d_in[39];
  const float* out_bias = (const float*)d_in[40];

  if (ws_size < WS_NEED) return;  // cannot run without scratch

  char* ws = (char*)d_ws;
  float* feats0 = (float*)(ws + O_FEATS0);
  float* feats1 = (float*)(ws + O_FEATS1);
  float* feats2 = (float*)(ws + O_FEATS2);
  float* fp0out = (float*)(ws + O_FP0OUT);
  float* xyz1   = (float*)(ws + O_XYZ1);
  float* xyz2   = (float*)(ws + O_XYZ2);
  int*   fps1   = (int*)(ws + O_FPS1);
  int*   fps2   = (int*)(ws + O_FPS2);
  int*   ball1  = (int*)(ws + O_BALL1);
  int*   ball2  = (int*)(ws + O_BALL2);
  int*   nn0i   = (int*)(ws + O_NN0I);
  float* nn0w   = (float*)(ws + O_NN0W);
  int*   nn1i   = (int*)(ws + O_NN1I);
  float* nn1w   = (float*)(ws + O_NN1W);
  float* REG0   = (float*)(ws + O_REG0);
  float* REG1   = (float*)(ws + O_REG1);
  float* outp   = (float*)d_out;
  hipStream_t s = stream;

  // ---- embedding MLP: (B*8192, 64) ----
  emb_kernel<<<8192, 256, 0, s>>>(x, w_emb1, g_emb1, be_emb1, w_emb2, g_emb2,
                                  be_emb2, feats0);

  // ---- SA layer 1 ----
  fps_kernel<8192, 2048><<<4, 1024, 0, s>>>(x, fps1);
  gatherxyz_kernel<<<32, 256, 0, s>>>(x, fps1, xyz1, 11, 8192);
  ball_kernel<<<2048, 256, 0, s>>>(x, xyz1, ball1, 11, 8192);
  for (int c = 0; c < 2; ++c) {
    groupmat_kernel<<<16384, 256, 0, s>>>(REG0, feats0, ball1, fps1, c * 4096,
                                          64, 5, 11, 8192);
    conv_kernel<<<dim3(1024, 1), 256, 0, s>>>(REG0, l0_w1, REG1, 128, 128,
                                              l0_g1, l0_b1, nullptr, 1);
    conv_kernel<<<dim3(1024, 1), 256, 0, s>>>(REG1, l0_w2, REG0, 128, 128,
                                              l0_g2, l0_b2, nullptr, 1);
    segmax_kernel<<<2048, 256, 0, s>>>(REG0, feats1 + (size_t)c * 4096 * 128,
                                       128, 7);
  }

  // ---- SA layer 2 ----
  fps_kernel<2048, 1024><<<4, 1024, 0, s>>>(xyz1, fps2);
  gatherxyz_kernel<<<16, 256, 0, s>>>(xyz1, fps2, xyz2, 10, 2048);
  ball_kernel<<<1024, 256, 0, s>>>(xyz1, xyz2, ball2, 10, 2048);
  for (int c = 0; c < 2; ++c) {
    groupmat_kernel<<<16384, 256, 0, s>>>(REG0, feats1, ball2, fps2, c * 2048,
                                          128, 6, 10, 2048);
    conv_kernel<<<dim3(512, 2), 256, 0, s>>>(REG0, l1_w1, REG1, 256, 256,
                                             l1_g1, l1_b1, nullptr, 1);
    conv_kernel<<<dim3(512, 2), 256, 0, s>>>(REG1, l1_w2, REG0, 256, 256,
                                             l1_g2, l1_b2, nullptr, 1);
    segmax_kernel<<<2048, 256, 0, s>>>(REG0, feats2 + (size_t)c * 2048 * 256,
                                       256, 8);
  }

  // ---- feature propagation 0: 1024 -> 2048 points ----
  nn3_kernel<<<32, 256, 0, s>>>(xyz1, xyz2, nn0i, nn0w, 11, 1024);
  copycols_kernel<<<1024, 256, 0, s>>>(REG0, 384, 0, feats1, 5);
  interp_kernel<<<2048, 256, 0, s>>>(REG0, 384, 128, feats2, nn0i, nn0w, 6, 11,
                                     1024);
  conv_kernel<<<dim3(64, 2), 256, 0, s>>>(REG0, f0_w1, REG1, 384, 256, f0_g1,
                                          f0_b1, nullptr, 1);
  conv_kernel<<<dim3(64, 4), 256, 0, s>>>(REG1, f0_w2, fp0out, 256, 512, f0_g2,
                                          f0_b2, nullptr, 1);

  // ---- feature propagation 1 + head, chunked per batch ----
  nn3_kernel<<<128, 256, 0, s>>>(x, xyz1, nn1i, nn1w, 13, 2048);
  for (int b = 0; b < 4; ++b) {
    copycols_kernel<<<512, 256, 0, s>>>(REG0, 576, 0,
                                        feats0 + (size_t)b * 8192 * 64, 4);
    interp_kernel<<<4096, 256, 0, s>>>(REG0, 576, 64,
                                       fp0out + (size_t)b * 2048 * 512,
                                       nn1i + (size_t)b * 8192 * 3,
                                       nn1w + (size_t)b * 8192 * 3, 7, 13,
                                       2048);
    conv_kernel<<<dim3(64, 4), 256, 0, s>>>(REG0, f1_w1, REG1, 576, 512, f1_g1,
                                            f1_b1, nullptr, 1);
    conv_kernel<<<dim3(64, 8), 256, 0, s>>>(REG1, f1_w2, REG0, 512, 1024,
                                            f1_g2, f1_b2, nullptr, 1);
    conv_kernel<<<dim3(64, 4), 256, 0, s>>>(REG0, c1_w, REG1, 1024, 512, c1_g,
                                            c1_beta, c1_bias, 1);
    conv_kernel<<<dim3(64, 1), 256, 0, s>>>(REG1, c2_w, REG0, 512, 128, c2_g,
                                            c2_beta, c2_bias, 1);
    outfinal_kernel<<<256, 256, 0, s>>>(REG0, out_w, out_bias,
                                        outp + (size_t)b * 8192 * 8);
  }
}

// Round 5
// 5795.853 us; speedup vs baseline: 1.2438x; 1.2438x over previous
//
#include <hip/hip_runtime.h>
#include <math.h>

// ---------------------------------------------------------------------------
// PointNet++ part-seg forward. All features stored point-major: row = point,
// C contiguous floats per row. B=4, N=8192 fixed by the problem.
// ---------------------------------------------------------------------------

// ---------------- workspace layout (bytes) ----------------
static constexpr size_t O_FEATS0 = 0;                    // (4*8192, 64)  f32
static constexpr size_t O_FEATS1 = 8388608;              // (4*2048, 128)
static constexpr size_t O_FEATS2 = 12582912;             // (4*1024, 256)
static constexpr size_t O_FP0OUT = 16777216;             // (4*2048, 512)
static constexpr size_t O_XYZ1   = 33554432;             // (4*2048, 3)
static constexpr size_t O_XYZ2   = 33652736;             // (4*1024, 3)
static constexpr size_t O_FPS1   = 33701888;             // (4*2048) int
static constexpr size_t O_FPS2   = 33734656;             // (4*1024) int
static constexpr size_t O_BALL1  = 33751040;             // (4*2048*32) int
static constexpr size_t O_BALL2  = 34799616;             // (4*1024*32) int
static constexpr size_t O_NN0I   = 35323904;             // (4*2048*3) int
static constexpr size_t O_NN0W   = 35422208;             // (4*2048*3) f32
static constexpr size_t O_NN1I   = 35520512;             // (4*8192*3) int
static constexpr size_t O_NN1W   = 35913728;             // (4*8192*3) f32
static constexpr size_t O_REG0   = 36306944;             // 67108864 scratch
static constexpr size_t O_REG1   = 103415808;            // 67108864 scratch
static constexpr size_t WS_NEED  = 170524672;

// ---------------- emb: xyz -> relu(bn(W2*relu(bn(W1*xyz)))) ----------------
__global__ __launch_bounds__(256) void emb_kernel(
    const float* __restrict__ xyz, const float* __restrict__ w1,
    const float* __restrict__ g1, const float* __restrict__ b1,
    const float* __restrict__ w2, const float* __restrict__ g2,
    const float* __restrict__ b2, float* __restrict__ out) {
  const int t = threadIdx.x;
  const int o = t & 63, pl = t >> 6;
  const int pt = blockIdx.x * 4 + pl;
  const float x0 = xyz[(size_t)pt * 3 + 0];
  const float x1 = xyz[(size_t)pt * 3 + 1];
  const float x2 = xyz[(size_t)pt * 3 + 2];
  const float SQ = sqrtf(1.0f + 1e-5f);
  float v = w1[o * 3 + 0] * x0 + w1[o * 3 + 1] * x1 + w1[o * 3 + 2] * x2;
  v = fmaxf(v * (g1[o] / SQ) + b1[o], 0.0f);
  __shared__ float h[4][64];
  h[pl][o] = v;
  __syncthreads();
  float acc = 0.0f;
  #pragma unroll 8
  for (int i = 0; i < 64; ++i) acc += w2[o * 64 + i] * h[pl][i];
  float y = fmaxf(acc * (g2[o] / SQ) + b2[o], 0.0f);
  out[(size_t)pt * 64 + o] = y;
}

// ---------------- farthest point sampling ----------------
// 512 threads per batch (2 waves/SIMD). Scalar distance math (R3-proven,
// bit-exact vs numpy: separate mul/add rounding, no FMA). Per-thread local
// argmax = float max chain + first-occurrence equality select (key packing
// hoisted OUT of the per-point loop). Cross-lane argmax via packed u64 key
// = bits(d)<<32 | ~idx (d>=0 so float bits order-monotone; tie -> min idx,
// matching jnp.argmax). One barrier per iteration (parity double-buffered
// 8-entry key scratch); stage 2 = 8 PIPELINED broadcast ds_read_b64 + 7
// u64 compares (no dependent bpermute chain). Winner coords broadcast-read
// from LDS.
template <int N, int NP>
__global__ __launch_bounds__(512, 1) void fps_kernel(
    const float* __restrict__ xyz, int* __restrict__ out) {
  constexpr int PPT = N / 512;
  const int b = blockIdx.x, t = threadIdx.x;
  const float* xb = xyz + (size_t)b * N * 3;
  __shared__ float sx[N], sy[N], sz[N];
  __shared__ unsigned long long skey[2][8];
  for (int i = t; i < N; i += 512) {
    sx[i] = xb[i * 3 + 0];
    sy[i] = xb[i * 3 + 1];
    sz[i] = xb[i * 3 + 2];
  }
  __syncthreads();
  float px[PPT], py[PPT], pz[PPT], dist[PPT];
  #pragma unroll
  for (int j = 0; j < PPT; ++j) {
    px[j] = sx[t * PPT + j];
    py[j] = sy[t * PPT + j];
    pz[j] = sz[t * PPT + j];
    dist[j] = 1e10f;
  }
  const int wid = t >> 6, lane = t & 63;
  int far = 0;
  float ccx = sx[0], ccy = sy[0], ccz = sz[0];
  for (int it = 0; it < NP; ++it) {
    if (t == 0) out[(size_t)b * NP + it] = far;
    // ---- distance update ----
    float nds[PPT];
    #pragma unroll
    for (int j = 0; j < PPT; ++j) {
      const float dx = __fsub_rn(px[j], ccx);
      const float dy = __fsub_rn(py[j], ccy);
      const float dz = __fsub_rn(pz[j], ccz);
      const float d = __fadd_rn(__fadd_rn(__fmul_rn(dx, dx), __fmul_rn(dy, dy)),
                                __fmul_rn(dz, dz));
      const float nd = fminf(dist[j], d);
      dist[j] = nd;
      nds[j] = nd;
    }
    // ---- local argmax: max chain + first-occurrence equality select ----
    float bv = nds[0];
    #pragma unroll
    for (int j = 1; j < PPT; ++j) bv = fmaxf(bv, nds[j]);
    int bjl = 0;
    #pragma unroll
    for (int j = PPT - 1; j >= 0; --j) bjl = (nds[j] == bv) ? j : bjl;
    unsigned long long bk =
        ((unsigned long long)__float_as_uint(bv) << 32) |
        (unsigned long long)(unsigned)(~(unsigned)(t * PPT + bjl));
    // ---- in-wave butterfly on packed keys ----
    #pragma unroll
    for (int m = 32; m >= 1; m >>= 1) {
      const unsigned long long ok = __shfl_xor(bk, m, 64);
      bk = (ok > bk) ? ok : bk;
    }
    const int p = it & 1;
    if (lane == 0) skey[p][wid] = bk;
    __syncthreads();
    // ---- every thread reduces the 8 wave winners (pipelined reads) ----
    unsigned long long wk = skey[p][0];
    #pragma unroll
    for (int q = 1; q < 8; ++q) {
      const unsigned long long k2 = skey[p][q];
      wk = (k2 > wk) ? k2 : wk;
    }
    far = (int)(~(unsigned)wk);
    ccx = sx[far]; ccy = sy[far]; ccz = sz[far];
  }
}

// ---------------- gather xyz by index ----------------
__global__ __launch_bounds__(256) void gatherxyz_kernel(
    const float* __restrict__ xyz, const int* __restrict__ idx,
    float* __restrict__ out, int sbits, int N) {
  const int id = blockIdx.x * 256 + threadIdx.x;
  const int b = id >> sbits;
  const int n = idx[id];
  out[(size_t)id * 3 + 0] = xyz[((size_t)b * N + n) * 3 + 0];
  out[(size_t)id * 3 + 1] = xyz[((size_t)b * N + n) * 3 + 1];
  out[(size_t)id * 3 + 2] = xyz[((size_t)b * N + n) * 3 + 2];
}

// ---------------- ball query: first 32 indices with d2 <= 1 ----------------
__global__ __launch_bounds__(256) void ball_kernel(
    const float* __restrict__ xyz, const float* __restrict__ ctr,
    int* __restrict__ out, int sbits, int N) {
  const int t = threadIdx.x;
  const int lane = t & 63, wid = t >> 6;
  const int wg = blockIdx.x * 4 + wid;   // global center id
  const int b = wg >> sbits;
  __shared__ int lists[4][32];
  const float cx = ctr[(size_t)wg * 3 + 0];
  const float cy = ctr[(size_t)wg * 3 + 1];
  const float cz = ctr[(size_t)wg * 3 + 2];
  const float an = __fadd_rn(__fadd_rn(__fmul_rn(cx, cx), __fmul_rn(cy, cy)),
                             __fmul_rn(cz, cz));
  int fill = 0;
  for (int ch = 0; ch < (N >> 6) && fill < 32; ++ch) {
    const int n = ch * 64 + lane;
    const float bx = xyz[((size_t)b * N + n) * 3 + 0];
    const float by = xyz[((size_t)b * N + n) * 3 + 1];
    const float bz = xyz[((size_t)b * N + n) * 3 + 2];
    const float bb = __fadd_rn(__fadd_rn(__fmul_rn(bx, bx), __fmul_rn(by, by)),
                               __fmul_rn(bz, bz));
    const float dot = __fadd_rn(__fadd_rn(__fmul_rn(cx, bx), __fmul_rn(cy, by)),
                                __fmul_rn(cz, bz));
    const float d2 = __fsub_rn(__fadd_rn(an, bb), __fmul_rn(2.0f, dot));
    const bool q = (d2 <= 1.0f);
    const unsigned long long mask = __ballot(q);
    if (q) {
      const int pos = fill + __popcll(mask & ((1ull << lane) - 1ull));
      if (pos < 32) lists[wid][pos] = n;
    }
    fill += (int)__popcll(mask);
  }
  __syncthreads();
  if (lane < 32) {
    int v = lists[wid][0];
    if (lane < fill) v = lists[wid][lane];
    out[(size_t)wg * 32 + lane] = v;
  }
}

// ---------------- grouped feature materialization ----------------
// row (chunk-local) -> [f[src]-f[ctr] (Cf) ; f[ctr] (Cf)]
__global__ __launch_bounds__(256) void groupmat_kernel(
    float* __restrict__ Xo, const float* __restrict__ f,
    const int* __restrict__ ball, const int* __restrict__ fps, int g0, int Cf,
    int c4bits, int sbits, int Npts) {
  const int id = blockIdx.x * 256 + threadIdx.x;
  const int c4mask = (1 << c4bits) - 1;
  const int row = id >> c4bits;
  const int col = (id & c4mask) * 4;
  const int gl = g0 + (row >> 5);
  const int k = row & 31;
  const int b = gl >> sbits;
  const int src = ball[(size_t)gl * 32 + k];
  const int ctr = fps[gl];
  const int C = Cf * 2;
  const float* fb = f + (size_t)b * Npts * Cf;
  float4 v;
  if (col < Cf) {
    const float4 a = *(const float4*)(fb + (size_t)src * Cf + col);
    const float4 c = *(const float4*)(fb + (size_t)ctr * Cf + col);
    v = make_float4(a.x - c.x, a.y - c.y, a.z - c.z, a.w - c.w);
  } else {
    v = *(const float4*)(fb + (size_t)ctr * Cf + (col - Cf));
  }
  *(float4*)(Xo + (size_t)row * C + col) = v;
}

// ---------------- generic 1x1 conv (GEMM) with BN/bias/ReLU epilogue -------
// Y[(m), o] = relu( (sum_i X[m,i] W[o,i] + bias[o]) * g[o]/sqrt(1+eps) + beta[o] )
__global__ __launch_bounds__(256) void conv_kernel(
    const float* __restrict__ X, const float* __restrict__ W,
    float* __restrict__ Y, int C, int O, const float* __restrict__ gamma,
    const float* __restrict__ beta, const float* __restrict__ bias, int relu) {
  __shared__ float Xs[16][132];
  __shared__ float Ws[16][132];
  const int t = threadIdx.x;
  const size_t m0 = (size_t)blockIdx.x * 128;
  const int o0 = blockIdx.y * 128;
  const int r0 = t >> 2;
  const int cq0 = (t & 3) * 4;
  const int mq = t & 15, nq = t >> 4;
  float acc[8][8];
  #pragma unroll
  for (int i = 0; i < 8; ++i)
    #pragma unroll
    for (int j = 0; j < 8; ++j) acc[i][j] = 0.0f;

  for (int kk = 0; kk < C; kk += 16) {
    const float4 xa = *(const float4*)(X + (m0 + r0) * C + kk + cq0);
    const float4 xb = *(const float4*)(X + (m0 + r0 + 64) * C + kk + cq0);
    const float4 wa = *(const float4*)(W + (size_t)(o0 + r0) * C + kk + cq0);
    const float4 wb = *(const float4*)(W + (size_t)(o0 + r0 + 64) * C + kk + cq0);
    __syncthreads();
    Xs[cq0 + 0][r0] = xa.x; Xs[cq0 + 1][r0] = xa.y;
    Xs[cq0 + 2][r0] = xa.z; Xs[cq0 + 3][r0] = xa.w;
    Xs[cq0 + 0][r0 + 64] = xb.x; Xs[cq0 + 1][r0 + 64] = xb.y;
    Xs[cq0 + 2][r0 + 64] = xb.z; Xs[cq0 + 3][r0 + 64] = xb.w;
    Ws[cq0 + 0][r0] = wa.x; Ws[cq0 + 1][r0] = wa.y;
    Ws[cq0 + 2][r0] = wa.z; Ws[cq0 + 3][r0] = wa.w;
    Ws[cq0 + 0][r0 + 64] = wb.x; Ws[cq0 + 1][r0 + 64] = wb.y;
    Ws[cq0 + 2][r0 + 64] = wb.z; Ws[cq0 + 3][r0 + 64] = wb.w;
    __syncthreads();
    #pragma unroll
    for (int k = 0; k < 16; ++k) {
      const float4 a0 = *(const float4*)&Xs[k][mq * 8];
      const float4 a1 = *(const float4*)&Xs[k][mq * 8 + 4];
      const float4 b0 = *(const float4*)&Ws[k][nq * 8];
      const float4 b1 = *(const float4*)&Ws[k][nq * 8 + 4];
      const float am[8] = {a0.x, a0.y, a0.z, a0.w, a1.x, a1.y, a1.z, a1.w};
      const float bm[8] = {b0.x, b0.y, b0.z, b0.w, b1.x, b1.y, b1.z, b1.w};
      #pragma unroll
      for (int i = 0; i < 8; ++i)
        #pragma unroll
        for (int j = 0; j < 8; ++j) acc[i][j] += am[i] * bm[j];
    }
  }

  const float SQ = sqrtf(1.0f + 1e-5f);
  float s[8], sh[8];
  #pragma unroll
  for (int j = 0; j < 8; ++j) {
    const int o = o0 + nq * 8 + j;
    const float sc = gamma ? (gamma[o] / SQ) : 1.0f;
    float bb = beta ? beta[o] : 0.0f;
    if (bias) bb = bb + bias[o] * sc;
    s[j] = sc; sh[j] = bb;
  }
  #pragma unroll
  for (int i = 0; i < 8; ++i) {
    float y[8];
    #pragma unroll
    for (int j = 0; j < 8; ++j) {
      float v = acc[i][j] * s[j] + sh[j];
      y[j] = relu ? fmaxf(v, 0.0f) : v;
    }
    const size_t off = (m0 + mq * 8 + i) * O + o0 + nq * 8;
    *(float4*)(Y + off) = make_float4(y[0], y[1], y[2], y[3]);
    *(float4*)(Y + off + 4) = make_float4(y[4], y[5], y[6], y[7]);
  }
}

// ---------------- segmented max over 32 samples ----------------
__global__ __launch_bounds__(256) void segmax_kernel(
    const float* __restrict__ Y, float* __restrict__ F, int O, int obits) {
  const int id = blockIdx.x * 256 + threadIdx.x;
  const int g = id >> obits;
  const int o = id & (O - 1);
  float m = -3.4e38f;
  #pragma unroll 8
  for (int k = 0; k < 32; ++k)
    m = fmaxf(m, Y[((size_t)g * 32 + k) * O + o]);
  F[(size_t)g * O + o] = m;
}

// ---------------- 3-NN search (stable, strict <) ----------------
__global__ __launch_bounds__(256) void nn3_kernel(
    const float* __restrict__ txyz, const float* __restrict__ sxyz,
    int* __restrict__ oi, float* __restrict__ ow, int s1bits, int S2) {
  __shared__ float ss[6144];
  const int t = threadIdx.x;
  const int row = blockIdx.x * 256 + t;
  const int b = row >> s1bits;
  for (int i = t; i < S2 * 3; i += 256) ss[i] = sxyz[(size_t)b * S2 * 3 + i];
  __syncthreads();
  const float ax = txyz[(size_t)row * 3 + 0];
  const float ay = txyz[(size_t)row * 3 + 1];
  const float az = txyz[(size_t)row * 3 + 2];
  const float an = __fadd_rn(__fadd_rn(__fmul_rn(ax, ax), __fmul_rn(ay, ay)),
                             __fmul_rn(az, az));
  float d0 = 3.4e38f, d1 = 3.4e38f, d2v = 3.4e38f;
  int i0 = 0, i1 = 0, i2 = 0;
  for (int j = 0; j < S2; ++j) {
    const float bx = ss[j * 3 + 0], by = ss[j * 3 + 1], bz = ss[j * 3 + 2];
    const float bb = __fadd_rn(__fadd_rn(__fmul_rn(bx, bx), __fmul_rn(by, by)),
                               __fmul_rn(bz, bz));
    const float dot = __fadd_rn(__fadd_rn(__fmul_rn(ax, bx), __fmul_rn(ay, by)),
                                __fmul_rn(az, bz));
    const float dd = __fsub_rn(__fadd_rn(an, bb), __fmul_rn(2.0f, dot));
    if (dd < d0) {
      d2v = d1; i2 = i1; d1 = d0; i1 = i0; d0 = dd; i0 = j;
    } else if (dd < d1) {
      d2v = d1; i2 = i1; d1 = dd; i1 = j;
    } else if (dd < d2v) {
      d2v = dd; i2 = j;
    }
  }
  const float r0 = 1.0f / (d0 + 1e-8f);
  const float r1 = 1.0f / (d1 + 1e-8f);
  const float r2 = 1.0f / (d2v + 1e-8f);
  const float sum = __fadd_rn(__fadd_rn(r0, r1), r2);
  oi[(size_t)row * 3 + 0] = i0;
  oi[(size_t)row * 3 + 1] = i1;
  oi[(size_t)row * 3 + 2] = i2;
  ow[(size_t)row * 3 + 0] = r0 / sum;
  ow[(size_t)row * 3 + 1] = r1 / sum;
  ow[(size_t)row * 3 + 2] = r2 / sum;
}

// ---------------- weighted 3-point interpolation into concat columns -------
__global__ __launch_bounds__(256) void interp_kernel(
    float* __restrict__ dst, int CT, int c0, const float* __restrict__ src,
    const int* __restrict__ idx, const float* __restrict__ w, int csbits,
    int s1bits, int S2) {
  const int id = blockIdx.x * 256 + threadIdx.x;
  const int row = id >> csbits;
  const int c4 = (id & ((1 << csbits) - 1)) * 4;
  const int Cs = 4 << csbits;
  const int b = row >> s1bits;
  const int j0 = idx[(size_t)row * 3 + 0];
  const int j1 = idx[(size_t)row * 3 + 1];
  const int j2 = idx[(size_t)row * 3 + 2];
  const float w0 = w[(size_t)row * 3 + 0];
  const float w1 = w[(size_t)row * 3 + 1];
  const float w2 = w[(size_t)row * 3 + 2];
  const float4 f0 = *(const float4*)(src + ((size_t)b * S2 + j0) * Cs + c4);
  const float4 f1 = *(const float4*)(src + ((size_t)b * S2 + j1) * Cs + c4);
  const float4 f2 = *(const float4*)(src + ((size_t)b * S2 + j2) * Cs + c4);
  float4 v;
  v.x = f0.x * w0 + f1.x * w1 + f2.x * w2;
  v.y = f0.y * w0 + f1.y * w1 + f2.y * w2;
  v.z = f0.z * w0 + f1.z * w1 + f2.z * w2;
  v.w = f0.w * w0 + f1.w * w1 + f2.w * w2;
  *(float4*)(dst + (size_t)row * CT + c0 + c4) = v;
}

// ---------------- copy columns into concat buffer ----------------
__global__ __launch_bounds__(256) void copycols_kernel(
    float* __restrict__ dst, int CT, int c0, const float* __restrict__ src,
    int csbits) {
  const int id = blockIdx.x * 256 + threadIdx.x;
  const int row = id >> csbits;
  const int c4 = (id & ((1 << csbits) - 1)) * 4;
  const int Cs = 4 << csbits;
  const float4 v = *(const float4*)(src + (size_t)row * Cs + c4);
  *(float4*)(dst + (size_t)row * CT + c0 + c4) = v;
}

// ---------------- final 128->8 conv + bias, point-major out ----------------
__global__ __launch_bounds__(256) void outfinal_kernel(
    const float* __restrict__ X, const float* __restrict__ Wt,
    const float* __restrict__ bias, float* __restrict__ out) {
  __shared__ float Xs[32][132];
  const int t = threadIdx.x;
  const int p0 = blockIdx.x * 32;
  #pragma unroll
  for (int q = 0; q < 4; ++q) {
    const int id = t + q * 256;
    const int r = id >> 5, c4 = (id & 31) * 4;
    const float4 v = *(const float4*)(X + (size_t)(p0 + r) * 128 + c4);
    Xs[r][c4 + 0] = v.x; Xs[r][c4 + 1] = v.y;
    Xs[r][c4 + 2] = v.z; Xs[r][c4 + 3] = v.w;
  }
  __syncthreads();
  const int p = t >> 3, o = t & 7;
  float acc = 0.0f;
  #pragma unroll 8
  for (int i = 0; i < 128; ++i) acc += Wt[o * 128 + i] * Xs[p][i];
  out[(size_t)(p0 + p) * 8 + o] = acc + bias[o];
}

// ---------------------------------------------------------------------------
extern "C" void kernel_launch(void* const* d_in, const int* in_sizes, int n_in,
                              void* d_out, int out_size, void* d_ws,
                              size_t ws_size, hipStream_t stream) {
  const float* x       = (const float*)d_in[0];
  const float* w_emb1  = (const float*)d_in[1];
  const float* g_emb1  = (const float*)d_in[2];
  const float* be_emb1 = (const float*)d_in[3];
  const float* w_emb2  = (const float*)d_in[4];
  const float* g_emb2  = (const float*)d_in[5];
  const float* be_emb2 = (const float*)d_in[6];
  const float* l0_w1 = (const float*)d_in[7];
  const float* l0_g1 = (const float*)d_in[8];
  const float* l0_b1 = (const float*)d_in[9];
  const float* l0_w2 = (const float*)d_in[10];
  const float* l0_g2 = (const float*)d_in[11];
  const float* l0_b2 = (const float*)d_in[12];
  const float* l1_w1 = (const float*)d_in[13];
  const float* l1_g1 = (const float*)d_in[14];
  const float* l1_b1 = (const float*)d_in[15];
  const float* l1_w2 = (const float*)d_in[16];
  const float* l1_g2 = (const float*)d_in[17];
  const float* l1_b2 = (const float*)d_in[18];
  const float* f0_w1 = (const float*)d_in[19];
  const float* f0_g1 = (const float*)d_in[20];
  const float* f0_b1 = (const float*)d_in[21];
  const float* f0_w2 = (const float*)d_in[22];
  const float* f0_g2 = (const float*)d_in[23];
  const float* f0_b2 = (const float*)d_in[24];
  const float* f1_w1 = (const float*)d_in[25];
  const float* f1_g1 = (const float*)d_in[26];
  const float* f1_b1 = (const float*)d_in[27];
  const float* f1_w2 = (const float*)d_in[28];
  const float* f1_g2 = (const float*)d_in[29];
  const float* f1_b2 = (const float*)d_in[30];
  const float* c1_w    = (const float*)d_in[31];
  const float* c1_bias = (const float*)d_in[32];
  const float* c1_g    = (const float*)d_in[33];
  const float* c1_beta = (const float*)d_in[34];
  const float* c2_w    = (const float*)d_in[35];
  const float* c2_bias = (const float*)d_in[36];
  const float* c2_g    = (const float*)d_in[37];
  const float* c2_beta = (const float*)d_in[38];
  const float* out_w    = (const float*)d_in[39];
  const float* out_bias = (const float*)d_in[40];

  if (ws_size < WS_NEED) return;  // cannot run without scratch

  char* ws = (char*)d_ws;
  float* feats0 = (float*)(ws + O_FEATS0);
  float* feats1 = (float*)(ws + O_FEATS1);
  float* feats2 = (float*)(ws + O_FEATS2);
  float* fp0out = (float*)(ws + O_FP0OUT);
  float* xyz1   = (float*)(ws + O_XYZ1);
  float* xyz2   = (float*)(ws + O_XYZ2);
  int*   fps1   = (int*)(ws + O_FPS1);
  int*   fps2   = (int*)(ws + O_FPS2);
  int*   ball1  = (int*)(ws + O_BALL1);
  int*   ball2  = (int*)(ws + O_BALL2);
  int*   nn0i   = (int*)(ws + O_NN0I);
  float* nn0w   = (float*)(ws + O_NN0W);
  int*   nn1i   = (int*)(ws + O_NN1I);
  float* nn1w   = (float*)(ws + O_NN1W);
  float* REG0   = (float*)(ws + O_REG0);
  float* REG1   = (float*)(ws + O_REG1);
  float* outp   = (float*)d_out;
  hipStream_t s = stream;

  // ---- embedding MLP: (B*8192, 64) ----
  emb_kernel<<<8192, 256, 0, s>>>(x, w_emb1, g_emb1, be_emb1, w_emb2, g_emb2,
                                  be_emb2, feats0);

  // ---- SA layer 1 ----
  fps_kernel<8192, 2048><<<4, 512, 0, s>>>(x, fps1);
  gatherxyz_kernel<<<32, 256, 0, s>>>(x, fps1, xyz1, 11, 8192);
  ball_kernel<<<2048, 256, 0, s>>>(x, xyz1, ball1, 11, 8192);
  for (int c = 0; c < 2; ++c) {
    groupmat_kernel<<<16384, 256, 0, s>>>(REG0, feats0, ball1, fps1, c * 4096,
                                          64, 5, 11, 8192);
    conv_kernel<<<dim3(1024, 1), 256, 0, s>>>(REG0, l0_w1, REG1, 128, 128,
                                              l0_g1, l0_b1, nullptr, 1);
    conv_kernel<<<dim3(1024, 1), 256, 0, s>>>(REG1, l0_w2, REG0, 128, 128,
                                              l0_g2, l0_b2, nullptr, 1);
    segmax_kernel<<<2048, 256, 0, s>>>(REG0, feats1 + (size_t)c * 4096 * 128,
                                       128, 7);
  }

  // ---- SA layer 2 ----
  fps_kernel<2048, 1024><<<4, 512, 0, s>>>(xyz1, fps2);
  gatherxyz_kernel<<<16, 256, 0, s>>>(xyz1, fps2, xyz2, 10, 2048);
  ball_kernel<<<1024, 256, 0, s>>>(xyz1, xyz2, ball2, 10, 2048);
  for (int c = 0; c < 2; ++c) {
    groupmat_kernel<<<16384, 256, 0, s>>>(REG0, feats1, ball2, fps2, c * 2048,
                                          128, 6, 10, 2048);
    conv_kernel<<<dim3(512, 2), 256, 0, s>>>(REG0, l1_w1, REG1, 256, 256,
                                             l1_g1, l1_b1, nullptr, 1);
    conv_kernel<<<dim3(512, 2), 256, 0, s>>>(REG1, l1_w2, REG0, 256, 256,
                                             l1_g2, l1_b2, nullptr, 1);
    segmax_kernel<<<2048, 256, 0, s>>>(REG0, feats2 + (size_t)c * 2048 * 256,
                                       256, 8);
  }

  // ---- feature propagation 0: 1024 -> 2048 points ----
  nn3_kernel<<<32, 256, 0, s>>>(xyz1, xyz2, nn0i, nn0w, 11, 1024);
  copycols_kernel<<<1024, 256, 0, s>>>(REG0, 384, 0, feats1, 5);
  interp_kernel<<<2048, 256, 0, s>>>(REG0, 384, 128, feats2, nn0i, nn0w, 6, 11,
                                     1024);
  conv_kernel<<<dim3(64, 2), 256, 0, s>>>(REG0, f0_w1, REG1, 384, 256, f0_g1,
                                          f0_b1, nullptr, 1);
  conv_kernel<<<dim3(64, 4), 256, 0, s>>>(REG1, f0_w2, fp0out, 256, 512, f0_g2,
                                          f0_b2, nullptr, 1);

  // ---- feature propagation 1 + head, chunked per batch ----
  nn3_kernel<<<128, 256, 0, s>>>(x, xyz1, nn1i, nn1w, 13, 2048);
  for (int b = 0; b < 4; ++b) {
    copycols_kernel<<<512, 256, 0, s>>>(REG0, 576, 0,
                                        feats0 + (size_t)b * 8192 * 64, 4);
    interp_kernel<<<4096, 256, 0, s>>>(REG0, 576, 64,
                                       fp0out + (size_t)b * 2048 * 512,
                                       nn1i + (size_t)b * 8192 * 3,
                                       nn1w + (size_t)b * 8192 * 3, 7, 13,
                                       2048);
    conv_kernel<<<dim3(64, 4), 256, 0, s>>>(REG0, f1_w1, REG1, 576, 512, f1_g1,
                                            f1_b1, nullptr, 1);
    conv_kernel<<<dim3(64, 8), 256, 0, s>>>(REG1, f1_w2, REG0, 512, 1024,
                                            f1_g2, f1_b2, nullptr, 1);
    conv_kernel<<<dim3(64, 4), 256, 0, s>>>(REG0, c1_w, REG1, 1024, 512, c1_g,
                                            c1_beta, c1_bias, 1);
    conv_kernel<<<dim3(64, 1), 256, 0, s>>>(REG1, c2_w, REG0, 512, 128, c2_g,
                                            c2_beta, c2_bias, 1);
    outfinal_kernel<<<256, 256, 0, s>>>(REG0, out_w, out_bias,
                                        outp + (size_t)b * 8192 * 8);
  }
}

// Round 6
// 5196.087 us; speedup vs baseline: 1.3874x; 1.1154x over previous
//
#include <hip/hip_runtime.h>
#include <math.h>

// ---------------------------------------------------------------------------
// PointNet++ part-seg forward. All features stored point-major: row = point,
// C contiguous floats per row. B=4, N=8192 fixed by the problem.
// ---------------------------------------------------------------------------

// ---------------- workspace layout (bytes) ----------------
static constexpr size_t O_FEATS0 = 0;                    // (4*8192, 64)  f32
static constexpr size_t O_FEATS1 = 8388608;              // (4*2048, 128)
static constexpr size_t O_FEATS2 = 12582912;             // (4*1024, 256)
static constexpr size_t O_FP0OUT = 16777216;             // (4*2048, 512)
static constexpr size_t O_XYZ1   = 33554432;             // (4*2048, 3)
static constexpr size_t O_XYZ2   = 33652736;             // (4*1024, 3)
static constexpr size_t O_FPS1   = 33701888;             // (4*2048) int
static constexpr size_t O_FPS2   = 33734656;             // (4*1024) int
static constexpr size_t O_BALL1  = 33751040;             // (4*2048*32) int
static constexpr size_t O_BALL2  = 34799616;             // (4*1024*32) int
static constexpr size_t O_NN0I   = 35323904;             // (4*2048*3) int
static constexpr size_t O_NN0W   = 35422208;             // (4*2048*3) f32
static constexpr size_t O_NN1I   = 35520512;             // (4*8192*3) int
static constexpr size_t O_NN1W   = 35913728;             // (4*8192*3) f32
static constexpr size_t O_REG0   = 36306944;             // 67108864 scratch
static constexpr size_t O_REG1   = 103415808;            // 67108864 scratch
static constexpr size_t WS_NEED  = 170524672;

typedef float v2f __attribute__((ext_vector_type(2)));

// ---------------- emb: xyz -> relu(bn(W2*relu(bn(W1*xyz)))) ----------------
__global__ __launch_bounds__(256) void emb_kernel(
    const float* __restrict__ xyz, const float* __restrict__ w1,
    const float* __restrict__ g1, const float* __restrict__ b1,
    const float* __restrict__ w2, const float* __restrict__ g2,
    const float* __restrict__ b2, float* __restrict__ out) {
  const int t = threadIdx.x;
  const int o = t & 63, pl = t >> 6;
  const int pt = blockIdx.x * 4 + pl;
  const float x0 = xyz[(size_t)pt * 3 + 0];
  const float x1 = xyz[(size_t)pt * 3 + 1];
  const float x2 = xyz[(size_t)pt * 3 + 2];
  const float SQ = sqrtf(1.0f + 1e-5f);
  float v = w1[o * 3 + 0] * x0 + w1[o * 3 + 1] * x1 + w1[o * 3 + 2] * x2;
  v = fmaxf(v * (g1[o] / SQ) + b1[o], 0.0f);
  __shared__ float h[4][64];
  h[pl][o] = v;
  __syncthreads();
  float acc = 0.0f;
  #pragma unroll 8
  for (int i = 0; i < 64; ++i) acc += w2[o * 64 + i] * h[pl][i];
  float y = fmaxf(acc * (g2[o] / SQ) + b2[o], 0.0f);
  out[(size_t)pt * 64 + o] = y;
}

// ---------------- DPP helpers for wave-64 u64 max reduce -------------------
__device__ __forceinline__ unsigned long long u64max(unsigned long long a,
                                                     unsigned long long b) {
  return a > b ? a : b;
}
template <int CTRL>
__device__ __forceinline__ unsigned long long dpp_step(unsigned long long k) {
  const int lo = (int)(unsigned)k;
  const int hi = (int)(unsigned)(k >> 32);
  // old = self, bound_ctrl = false -> invalid source lanes keep own value
  const int nlo = __builtin_amdgcn_update_dpp(lo, lo, CTRL, 0xf, 0xf, false);
  const int nhi = __builtin_amdgcn_update_dpp(hi, hi, CTRL, 0xf, 0xf, false);
  return ((unsigned long long)(unsigned)nhi << 32) | (unsigned)nlo;
}

// ---------------- farthest point sampling ----------------
// 512 threads per batch (2 waves/SIMD). Packed v2f distance math (VOP3P is
// IEEE RN per lane; fp contract(off) so no FMA fusion -> bit-exact vs numpy).
// Per-thread argmax = packed max chain + first-occurrence equality select.
// Cross-lane argmax on packed u64 key = bits(d)<<32 | ~idx (d>=0 so float
// bits order-monotone; tie -> min idx, matching jnp.argmax). In-wave reduce
// via DPP (row_shr 1/2/4/8 + bcast15 + bcast31 -> lane 63), pure VALU, no
// LDS round. One barrier/iter (parity double-buffered 8-key scratch);
// stage 2 = 8 pipelined broadcast u64 LDS reads + 7 compares.
template <int N, int NP>
__global__ __launch_bounds__(512, 1) void fps_kernel(
    const float* __restrict__ xyz, int* __restrict__ out) {
  #pragma clang fp contract(off)
  constexpr int PPT = N / 512;
  constexpr int PAIRS = PPT / 2;
  const int b = blockIdx.x, t = threadIdx.x;
  const float* xb = xyz + (size_t)b * N * 3;
  __shared__ float sx[N], sy[N], sz[N];
  __shared__ unsigned long long skey[2][8];
  for (int i = t; i < N; i += 512) {
    sx[i] = xb[i * 3 + 0];
    sy[i] = xb[i * 3 + 1];
    sz[i] = xb[i * 3 + 2];
  }
  __syncthreads();
  v2f px[PAIRS], py[PAIRS], pz[PAIRS], ds[PAIRS];
  #pragma unroll
  for (int k = 0; k < PAIRS; ++k) {
    const int g = t * PPT + 2 * k;
    px[k].x = sx[g]; px[k].y = sx[g + 1];
    py[k].x = sy[g]; py[k].y = sy[g + 1];
    pz[k].x = sz[g]; pz[k].y = sz[g + 1];
    ds[k].x = 1e10f; ds[k].y = 1e10f;
  }
  const int wid = t >> 6, lane = t & 63;
  int far = 0;
  float ccx = sx[0], ccy = sy[0], ccz = sz[0];
  for (int it = 0; it < NP; ++it) {
    if (t == 0) out[(size_t)b * NP + it] = far;
    v2f cx2, cy2, cz2;
    cx2.x = ccx; cx2.y = ccx;
    cy2.x = ccy; cy2.y = ccy;
    cz2.x = ccz; cz2.y = ccz;
    // ---- packed distance update ----
    #pragma unroll
    for (int k = 0; k < PAIRS; ++k) {
      const v2f dx = px[k] - cx2;
      const v2f dy = py[k] - cy2;
      const v2f dz = pz[k] - cz2;
      const v2f d = dx * dx + dy * dy + dz * dz;
      v2f nd;
      nd.x = fminf(ds[k].x, d.x);
      nd.y = fminf(ds[k].y, d.y);
      ds[k] = nd;
    }
    // ---- local argmax: max chain + first-occurrence equality select ----
    v2f vm = ds[0];
    #pragma unroll
    for (int k = 1; k < PAIRS; ++k) {
      vm.x = fmaxf(vm.x, ds[k].x);
      vm.y = fmaxf(vm.y, ds[k].y);
    }
    const float bv = fmaxf(vm.x, vm.y);
    int bjl = 0;
    #pragma unroll
    for (int k = PAIRS - 1; k >= 0; --k) {
      bjl = (ds[k].y == bv) ? 2 * k + 1 : bjl;
      bjl = (ds[k].x == bv) ? 2 * k : bjl;
    }
    unsigned long long bk =
        ((unsigned long long)__float_as_uint(bv) << 32) |
        (unsigned long long)(unsigned)(~(unsigned)(t * PPT + bjl));
    // ---- in-wave max reduce to lane 63 via DPP (pure VALU) ----
    bk = u64max(bk, dpp_step<0x111>(bk));  // row_shr:1
    bk = u64max(bk, dpp_step<0x112>(bk));  // row_shr:2
    bk = u64max(bk, dpp_step<0x114>(bk));  // row_shr:4
    bk = u64max(bk, dpp_step<0x118>(bk));  // row_shr:8
    bk = u64max(bk, dpp_step<0x142>(bk));  // row_bcast:15
    bk = u64max(bk, dpp_step<0x143>(bk));  // row_bcast:31
    const int p = it & 1;
    if (lane == 63) skey[p][wid] = bk;
    __syncthreads();
    // ---- every thread reduces the 8 wave winners (pipelined reads) ----
    unsigned long long wk = skey[p][0];
    #pragma unroll
    for (int q = 1; q < 8; ++q) {
      const unsigned long long k2 = skey[p][q];
      wk = (k2 > wk) ? k2 : wk;
    }
    far = (int)(~(unsigned)wk);
    ccx = sx[far]; ccy = sy[far]; ccz = sz[far];
  }
}

// ---------------- gather xyz by index ----------------
__global__ __launch_bounds__(256) void gatherxyz_kernel(
    const float* __restrict__ xyz, const int* __restrict__ idx,
    float* __restrict__ out, int sbits, int N) {
  const int id = blockIdx.x * 256 + threadIdx.x;
  const int b = id >> sbits;
  const int n = idx[id];
  out[(size_t)id * 3 + 0] = xyz[((size_t)b * N + n) * 3 + 0];
  out[(size_t)id * 3 + 1] = xyz[((size_t)b * N + n) * 3 + 1];
  out[(size_t)id * 3 + 2] = xyz[((size_t)b * N + n) * 3 + 2];
}

// ---------------- ball query: first 32 indices with d2 <= 1 ----------------
__global__ __launch_bounds__(256) void ball_kernel(
    const float* __restrict__ xyz, const float* __restrict__ ctr,
    int* __restrict__ out, int sbits, int N) {
  const int t = threadIdx.x;
  const int lane = t & 63, wid = t >> 6;
  const int wg = blockIdx.x * 4 + wid;   // global center id
  const int b = wg >> sbits;
  __shared__ int lists[4][32];
  const float cx = ctr[(size_t)wg * 3 + 0];
  const float cy = ctr[(size_t)wg * 3 + 1];
  const float cz = ctr[(size_t)wg * 3 + 2];
  const float an = __fadd_rn(__fadd_rn(__fmul_rn(cx, cx), __fmul_rn(cy, cy)),
                             __fmul_rn(cz, cz));
  int fill = 0;
  for (int ch = 0; ch < (N >> 6) && fill < 32; ++ch) {
    const int n = ch * 64 + lane;
    const float bx = xyz[((size_t)b * N + n) * 3 + 0];
    const float by = xyz[((size_t)b * N + n) * 3 + 1];
    const float bz = xyz[((size_t)b * N + n) * 3 + 2];
    const float bb = __fadd_rn(__fadd_rn(__fmul_rn(bx, bx), __fmul_rn(by, by)),
                               __fmul_rn(bz, bz));
    const float dot = __fadd_rn(__fadd_rn(__fmul_rn(cx, bx), __fmul_rn(cy, by)),
                                __fmul_rn(cz, bz));
    const float d2 = __fsub_rn(__fadd_rn(an, bb), __fmul_rn(2.0f, dot));
    const bool q = (d2 <= 1.0f);
    const unsigned long long mask = __ballot(q);
    if (q) {
      const int pos = fill + __popcll(mask & ((1ull << lane) - 1ull));
      if (pos < 32) lists[wid][pos] = n;
    }
    fill += (int)__popcll(mask);
  }
  __syncthreads();
  if (lane < 32) {
    int v = lists[wid][0];
    if (lane < fill) v = lists[wid][lane];
    out[(size_t)wg * 32 + lane] = v;
  }
}

// ---------------- grouped feature materialization ----------------
// row (chunk-local) -> [f[src]-f[ctr] (Cf) ; f[ctr] (Cf)]
__global__ __launch_bounds__(256) void groupmat_kernel(
    float* __restrict__ Xo, const float* __restrict__ f,
    const int* __restrict__ ball, const int* __restrict__ fps, int g0, int Cf,
    int c4bits, int sbits, int Npts) {
  const int id = blockIdx.x * 256 + threadIdx.x;
  const int c4mask = (1 << c4bits) - 1;
  const int row = id >> c4bits;
  const int col = (id & c4mask) * 4;
  const int gl = g0 + (row >> 5);
  const int k = row & 31;
  const int b = gl >> sbits;
  const int src = ball[(size_t)gl * 32 + k];
  const int ctr = fps[gl];
  const int C = Cf * 2;
  const float* fb = f + (size_t)b * Npts * Cf;
  float4 v;
  if (col < Cf) {
    const float4 a = *(const float4*)(fb + (size_t)src * Cf + col);
    const float4 c = *(const float4*)(fb + (size_t)ctr * Cf + col);
    v = make_float4(a.x - c.x, a.y - c.y, a.z - c.z, a.w - c.w);
  } else {
    v = *(const float4*)(fb + (size_t)ctr * Cf + (col - Cf));
  }
  *(float4*)(Xo + (size_t)row * C + col) = v;
}

// ---------------- generic 1x1 conv (GEMM) with BN/bias/ReLU epilogue -------
// LDS tiles chunk-padded: 8-float chunk stored in a 12-float slot so the 16
// lanes' ds_read_b128 hit disjoint 16B bank ranges (kills the 4-way read
// conflict of the 32B-strided layout; writes stay <=2-way = free).
#define CMAP(c) ((((c) >> 3) * 12) + ((c) & 7))
__global__ __launch_bounds__(256) void conv_kernel(
    const float* __restrict__ X, const float* __restrict__ W,
    float* __restrict__ Y, int C, int O, const float* __restrict__ gamma,
    const float* __restrict__ beta, const float* __restrict__ bias, int relu) {
  __shared__ float Xs[16][188];
  __shared__ float Ws[16][188];
  const int t = threadIdx.x;
  const size_t m0 = (size_t)blockIdx.x * 128;
  const int o0 = blockIdx.y * 128;
  const int r0 = t >> 2;
  const int cq0 = (t & 3) * 4;
  const int mq = t & 15, nq = t >> 4;
  const int ca = CMAP(r0), cb = CMAP(r0 + 64);
  float acc[8][8];
  #pragma unroll
  for (int i = 0; i < 8; ++i)
    #pragma unroll
    for (int j = 0; j < 8; ++j) acc[i][j] = 0.0f;

  for (int kk = 0; kk < C; kk += 16) {
    const float4 xa = *(const float4*)(X + (m0 + r0) * C + kk + cq0);
    const float4 xb = *(const float4*)(X + (m0 + r0 + 64) * C + kk + cq0);
    const float4 wa = *(const float4*)(W + (size_t)(o0 + r0) * C + kk + cq0);
    const float4 wb = *(const float4*)(W + (size_t)(o0 + r0 + 64) * C + kk + cq0);
    __syncthreads();
    Xs[cq0 + 0][ca] = xa.x; Xs[cq0 + 1][ca] = xa.y;
    Xs[cq0 + 2][ca] = xa.z; Xs[cq0 + 3][ca] = xa.w;
    Xs[cq0 + 0][cb] = xb.x; Xs[cq0 + 1][cb] = xb.y;
    Xs[cq0 + 2][cb] = xb.z; Xs[cq0 + 3][cb] = xb.w;
    Ws[cq0 + 0][ca] = wa.x; Ws[cq0 + 1][ca] = wa.y;
    Ws[cq0 + 2][ca] = wa.z; Ws[cq0 + 3][ca] = wa.w;
    Ws[cq0 + 0][cb] = wb.x; Ws[cq0 + 1][cb] = wb.y;
    Ws[cq0 + 2][cb] = wb.z; Ws[cq0 + 3][cb] = wb.w;
    __syncthreads();
    #pragma unroll
    for (int k = 0; k < 16; ++k) {
      const float4 a0 = *(const float4*)&Xs[k][mq * 12];
      const float4 a1 = *(const float4*)&Xs[k][mq * 12 + 4];
      const float4 b0 = *(const float4*)&Ws[k][nq * 12];
      const float4 b1 = *(const float4*)&Ws[k][nq * 12 + 4];
      const float am[8] = {a0.x, a0.y, a0.z, a0.w, a1.x, a1.y, a1.z, a1.w};
      const float bm[8] = {b0.x, b0.y, b0.z, b0.w, b1.x, b1.y, b1.z, b1.w};
      #pragma unroll
      for (int i = 0; i < 8; ++i)
        #pragma unroll
        for (int j = 0; j < 8; ++j) acc[i][j] += am[i] * bm[j];
    }
  }

  const float SQ = sqrtf(1.0f + 1e-5f);
  float s[8], sh[8];
  #pragma unroll
  for (int j = 0; j < 8; ++j) {
    const int o = o0 + nq * 8 + j;
    const float sc = gamma ? (gamma[o] / SQ) : 1.0f;
    float bb = beta ? beta[o] : 0.0f;
    if (bias) bb = bb + bias[o] * sc;
    s[j] = sc; sh[j] = bb;
  }
  #pragma unroll
  for (int i = 0; i < 8; ++i) {
    float y[8];
    #pragma unroll
    for (int j = 0; j < 8; ++j) {
      float v = acc[i][j] * s[j] + sh[j];
      y[j] = relu ? fmaxf(v, 0.0f) : v;
    }
    const size_t off = (m0 + mq * 8 + i) * O + o0 + nq * 8;
    *(float4*)(Y + off) = make_float4(y[0], y[1], y[2], y[3]);
    *(float4*)(Y + off + 4) = make_float4(y[4], y[5], y[6], y[7]);
  }
}

// ---------------- segmented max over 32 samples ----------------
__global__ __launch_bounds__(256) void segmax_kernel(
    const float* __restrict__ Y, float* __restrict__ F, int O, int obits) {
  const int id = blockIdx.x * 256 + threadIdx.x;
  const int g = id >> obits;
  const int o = id & (O - 1);
  float m = -3.4e38f;
  #pragma unroll 8
  for (int k = 0; k < 32; ++k)
    m = fmaxf(m, Y[((size_t)g * 32 + k) * O + o]);
  F[(size_t)g * O + o] = m;
}

// ---------------- 3-NN search (stable, strict <) ----------------
__global__ __launch_bounds__(256) void nn3_kernel(
    const float* __restrict__ txyz, const float* __restrict__ sxyz,
    int* __restrict__ oi, float* __restrict__ ow, int s1bits, int S2) {
  __shared__ float ss[6144];
  const int t = threadIdx.x;
  const int row = blockIdx.x * 256 + t;
  const int b = row >> s1bits;
  for (int i = t; i < S2 * 3; i += 256) ss[i] = sxyz[(size_t)b * S2 * 3 + i];
  __syncthreads();
  const float ax = txyz[(size_t)row * 3 + 0];
  const float ay = txyz[(size_t)row * 3 + 1];
  const float az = txyz[(size_t)row * 3 + 2];
  const float an = __fadd_rn(__fadd_rn(__fmul_rn(ax, ax), __fmul_rn(ay, ay)),
                             __fmul_rn(az, az));
  float d0 = 3.4e38f, d1 = 3.4e38f, d2v = 3.4e38f;
  int i0 = 0, i1 = 0, i2 = 0;
  for (int j = 0; j < S2; ++j) {
    const float bx = ss[j * 3 + 0], by = ss[j * 3 + 1], bz = ss[j * 3 + 2];
    const float bb = __fadd_rn(__fadd_rn(__fmul_rn(bx, bx), __fmul_rn(by, by)),
                               __fmul_rn(bz, bz));
    const float dot = __fadd_rn(__fadd_rn(__fmul_rn(ax, bx), __fmul_rn(ay, by)),
                                __fmul_rn(az, bz));
    const float dd = __fsub_rn(__fadd_rn(an, bb), __fmul_rn(2.0f, dot));
    if (dd < d0) {
      d2v = d1; i2 = i1; d1 = d0; i1 = i0; d0 = dd; i0 = j;
    } else if (dd < d1) {
      d2v = d1; i2 = i1; d1 = dd; i1 = j;
    } else if (dd < d2v) {
      d2v = dd; i2 = j;
    }
  }
  const float r0 = 1.0f / (d0 + 1e-8f);
  const float r1 = 1.0f / (d1 + 1e-8f);
  const float r2 = 1.0f / (d2v + 1e-8f);
  const float sum = __fadd_rn(__fadd_rn(r0, r1), r2);
  oi[(size_t)row * 3 + 0] = i0;
  oi[(size_t)row * 3 + 1] = i1;
  oi[(size_t)row * 3 + 2] = i2;
  ow[(size_t)row * 3 + 0] = r0 / sum;
  ow[(size_t)row * 3 + 1] = r1 / sum;
  ow[(size_t)row * 3 + 2] = r2 / sum;
}

// ---------------- weighted 3-point interpolation into concat columns -------
__global__ __launch_bounds__(256) void interp_kernel(
    float* __restrict__ dst, int CT, int c0, const float* __restrict__ src,
    const int* __restrict__ idx, const float* __restrict__ w, int csbits,
    int s1bits, int S2) {
  const int id = blockIdx.x * 256 + threadIdx.x;
  const int row = id >> csbits;
  const int c4 = (id & ((1 << csbits) - 1)) * 4;
  const int Cs = 4 << csbits;
  const int b = row >> s1bits;
  const int j0 = idx[(size_t)row * 3 + 0];
  const int j1 = idx[(size_t)row * 3 + 1];
  const int j2 = idx[(size_t)row * 3 + 2];
  const float w0 = w[(size_t)row * 3 + 0];
  const float w1 = w[(size_t)row * 3 + 1];
  const float w2 = w[(size_t)row * 3 + 2];
  const float4 f0 = *(const float4*)(src + ((size_t)b * S2 + j0) * Cs + c4);
  const float4 f1 = *(const float4*)(src + ((size_t)b * S2 + j1) * Cs + c4);
  const float4 f2 = *(const float4*)(src + ((size_t)b * S2 + j2) * Cs + c4);
  float4 v;
  v.x = f0.x * w0 + f1.x * w1 + f2.x * w2;
  v.y = f0.y * w0 + f1.y * w1 + f2.y * w2;
  v.z = f0.z * w0 + f1.z * w1 + f2.z * w2;
  v.w = f0.w * w0 + f1.w * w1 + f2.w * w2;
  *(float4*)(dst + (size_t)row * CT + c0 + c4) = v;
}

// ---------------- copy columns into concat buffer ----------------
__global__ __launch_bounds__(256) void copycols_kernel(
    float* __restrict__ dst, int CT, int c0, const float* __restrict__ src,
    int csbits) {
  const int id = blockIdx.x * 256 + threadIdx.x;
  const int row = id >> csbits;
  const int c4 = (id & ((1 << csbits) - 1)) * 4;
  const int Cs = 4 << csbits;
  const float4 v = *(const float4*)(src + (size_t)row * Cs + c4);
  *(float4*)(dst + (size_t)row * CT + c0 + c4) = v;
}

// ---------------- final 128->8 conv + bias, point-major out ----------------
__global__ __launch_bounds__(256) void outfinal_kernel(
    const float* __restrict__ X, const float* __restrict__ Wt,
    const float* __restrict__ bias, float* __restrict__ out) {
  __shared__ float Xs[32][132];
  const int t = threadIdx.x;
  const int p0 = blockIdx.x * 32;
  #pragma unroll
  for (int q = 0; q < 4; ++q) {
    const int id = t + q * 256;
    const int r = id >> 5, c4 = (id & 31) * 4;
    const float4 v = *(const float4*)(X + (size_t)(p0 + r) * 128 + c4);
    Xs[r][c4 + 0] = v.x; Xs[r][c4 + 1] = v.y;
    Xs[r][c4 + 2] = v.z; Xs[r][c4 + 3] = v.w;
  }
  __syncthreads();
  const int p = t >> 3, o = t & 7;
  float acc = 0.0f;
  #pragma unroll 8
  for (int i = 0; i < 128; ++i) acc += Wt[o * 128 + i] * Xs[p][i];
  out[(size_t)(p0 + p) * 8 + o] = acc + bias[o];
}

// ---------------------------------------------------------------------------
extern "C" void kernel_launch(void* const* d_in, const int* in_sizes, int n_in,
                              void* d_out, int out_size, void* d_ws,
                              size_t ws_size, hipStream_t stream) {
  const float* x       = (const float*)d_in[0];
  const float* w_emb1  = (const float*)d_in[1];
  const float* g_emb1  = (const float*)d_in[2];
  const float* be_emb1 = (const float*)d_in[3];
  const float* w_emb2  = (const float*)d_in[4];
  const float* g_emb2  = (const float*)d_in[5];
  const float* be_emb2 = (const float*)d_in[6];
  const float* l0_w1 = (const float*)d_in[7];
  const float* l0_g1 = (const float*)d_in[8];
  const float* l0_b1 = (const float*)d_in[9];
  const float* l0_w2 = (const float*)d_in[10];
  const float* l0_g2 = (const float*)d_in[11];
  const float* l0_b2 = (const float*)d_in[12];
  const float* l1_w1 = (const float*)d_in[13];
  const float* l1_g1 = (const float*)d_in[14];
  const float* l1_b1 = (const float*)d_in[15];
  const float* l1_w2 = (const float*)d_in[16];
  const float* l1_g2 = (const float*)d_in[17];
  const float* l1_b2 = (const float*)d_in[18];
  const float* f0_w1 = (const float*)d_in[19];
  const float* f0_g1 = (const float*)d_in[20];
  const float* f0_b1 = (const float*)d_in[21];
  const float* f0_w2 = (const float*)d_in[22];
  const float* f0_g2 = (const float*)d_in[23];
  const float* f0_b2 = (const float*)d_in[24];
  const float* f1_w1 = (const float*)d_in[25];
  const float* f1_g1 = (const float*)d_in[26];
  const float* f1_b1 = (const float*)d_in[27];
  const float* f1_w2 = (const float*)d_in[28];
  const float* f1_g2 = (const float*)d_in[29];
  const float* f1_b2 = (const float*)d_in[30];
  const float* c1_w    = (const float*)d_in[31];
  const float* c1_bias = (const float*)d_in[32];
  const float* c1_g    = (const float*)d_in[33];
  const float* c1_beta = (const float*)d_in[34];
  const float* c2_w    = (const float*)d_in[35];
  const float* c2_bias = (const float*)d_in[36];
  const float* c2_g    = (const float*)d_in[37];
  const float* c2_beta = (const float*)d_in[38];
  const float* out_w    = (const float*)d_in[39];
  const float* out_bias = (const float*)d_in[40];

  if (ws_size < WS_NEED) return;  // cannot run without scratch

  char* ws = (char*)d_ws;
  float* feats0 = (float*)(ws + O_FEATS0);
  float* feats1 = (float*)(ws + O_FEATS1);
  float* feats2 = (float*)(ws + O_FEATS2);
  float* fp0out = (float*)(ws + O_FP0OUT);
  float* xyz1   = (float*)(ws + O_XYZ1);
  float* xyz2   = (float*)(ws + O_XYZ2);
  int*   fps1   = (int*)(ws + O_FPS1);
  int*   fps2   = (int*)(ws + O_FPS2);
  int*   ball1  = (int*)(ws + O_BALL1);
  int*   ball2  = (int*)(ws + O_BALL2);
  int*   nn0i   = (int*)(ws + O_NN0I);
  float* nn0w   = (float*)(ws + O_NN0W);
  int*   nn1i   = (int*)(ws + O_NN1I);
  float* nn1w   = (float*)(ws + O_NN1W);
  float* REG0   = (float*)(ws + O_REG0);
  float* REG1   = (float*)(ws + O_REG1);
  float* outp   = (float*)d_out;
  hipStream_t s = stream;

  // ---- embedding MLP: (B*8192, 64) ----
  emb_kernel<<<8192, 256, 0, s>>>(x, w_emb1, g_emb1, be_emb1, w_emb2, g_emb2,
                                  be_emb2, feats0);

  // ---- SA layer 1 ----
  fps_kernel<8192, 2048><<<4, 512, 0, s>>>(x, fps1);
  gatherxyz_kernel<<<32, 256, 0, s>>>(x, fps1, xyz1, 11, 8192);
  ball_kernel<<<2048, 256, 0, s>>>(x, xyz1, ball1, 11, 8192);
  for (int c = 0; c < 2; ++c) {
    groupmat_kernel<<<16384, 256, 0, s>>>(REG0, feats0, ball1, fps1, c * 4096,
                                          64, 5, 11, 8192);
    conv_kernel<<<dim3(1024, 1), 256, 0, s>>>(REG0, l0_w1, REG1, 128, 128,
                                              l0_g1, l0_b1, nullptr, 1);
    conv_kernel<<<dim3(1024, 1), 256, 0, s>>>(REG1, l0_w2, REG0, 128, 128,
                                              l0_g2, l0_b2, nullptr, 1);
    segmax_kernel<<<2048, 256, 0, s>>>(REG0, feats1 + (size_t)c * 4096 * 128,
                                       128, 7);
  }

  // ---- SA layer 2 ----
  fps_kernel<2048, 1024><<<4, 512, 0, s>>>(xyz1, fps2);
  gatherxyz_kernel<<<16, 256, 0, s>>>(xyz1, fps2, xyz2, 10, 2048);
  ball_kernel<<<1024, 256, 0, s>>>(xyz1, xyz2, ball2, 10, 2048);
  for (int c = 0; c < 2; ++c) {
    groupmat_kernel<<<16384, 256, 0, s>>>(REG0, feats1, ball2, fps2, c * 2048,
                                          128, 6, 10, 2048);
    conv_kernel<<<dim3(512, 2), 256, 0, s>>>(REG0, l1_w1, REG1, 256, 256,
                                             l1_g1, l1_b1, nullptr, 1);
    conv_kernel<<<dim3(512, 2), 256, 0, s>>>(REG1, l1_w2, REG0, 256, 256,
                                             l1_g2, l1_b2, nullptr, 1);
    segmax_kernel<<<2048, 256, 0, s>>>(REG0, feats2 + (size_t)c * 2048 * 256,
                                       256, 8);
  }

  // ---- feature propagation 0: 1024 -> 2048 points ----
  nn3_kernel<<<32, 256, 0, s>>>(xyz1, xyz2, nn0i, nn0w, 11, 1024);
  copycols_kernel<<<1024, 256, 0, s>>>(REG0, 384, 0, feats1, 5);
  interp_kernel<<<2048, 256, 0, s>>>(REG0, 384, 128, feats2, nn0i, nn0w, 6, 11,
                                     1024);
  conv_kernel<<<dim3(64, 2), 256, 0, s>>>(REG0, f0_w1, REG1, 384, 256, f0_g1,
                                          f0_b1, nullptr, 1);
  conv_kernel<<<dim3(64, 4), 256, 0, s>>>(REG1, f0_w2, fp0out, 256, 512, f0_g2,
                                          f0_b2, nullptr, 1);

  // ---- feature propagation 1 + head, chunked per 2 batches ----
  nn3_kernel<<<128, 256, 0, s>>>(x, xyz1, nn1i, nn1w, 13, 2048);
  for (int b = 0; b < 4; b += 2) {
    copycols_kernel<<<1024, 256, 0, s>>>(REG0, 576, 0,
                                         feats0 + (size_t)b * 8192 * 64, 4);
    interp_kernel<<<8192, 256, 0, s>>>(REG0, 576, 64,
                                       fp0out + (size_t)b * 2048 * 512,
                                       nn1i + (size_t)b * 8192 * 3,
                                       nn1w + (size_t)b * 8192 * 3, 7, 13,
                                       2048);
    conv_kernel<<<dim3(128, 4), 256, 0, s>>>(REG0, f1_w1, REG1, 576, 512,
                                             f1_g1, f1_b1, nullptr, 1);
    conv_kernel<<<dim3(128, 8), 256, 0, s>>>(REG1, f1_w2, REG0, 512, 1024,
                                             f1_g2, f1_b2, nullptr, 1);
    conv_kernel<<<dim3(128, 4), 256, 0, s>>>(REG0, c1_w, REG1, 1024, 512,
                                             c1_g, c1_beta, c1_bias, 1);
    conv_kernel<<<dim3(128, 1), 256, 0, s>>>(REG1, c2_w, REG0, 512, 128,
                                             c2_g, c2_beta, c2_bias, 1);
    outfinal_kernel<<<512, 256, 0, s>>>(REG0, out_w, out_bias,
                                        outp + (size_t)b * 8192 * 8);
  }
}

// Round 7
// 5159.559 us; speedup vs baseline: 1.3972x; 1.0071x over previous
//
#include <hip/hip_runtime.h>
#include <math.h>

// ---------------------------------------------------------------------------
// PointNet++ part-seg forward. All features stored point-major: row = point,
// C contiguous floats per row. B=4, N=8192 fixed by the problem.
// ---------------------------------------------------------------------------

// ---------------- workspace layout (bytes) ----------------
static constexpr size_t O_FEATS0 = 0;                    // (4*8192, 64)  f32
static constexpr size_t O_FEATS1 = 8388608;              // (4*2048, 128)
static constexpr size_t O_FEATS2 = 12582912;             // (4*1024, 256)
static constexpr size_t O_FP0OUT = 16777216;             // (4*2048, 512)
static constexpr size_t O_XYZ1   = 33554432;             // (4*2048, 3)
static constexpr size_t O_XYZ2   = 33652736;             // (4*1024, 3)
static constexpr size_t O_FPS1   = 33701888;             // (4*2048) int
static constexpr size_t O_FPS2   = 33734656;             // (4*1024) int
static constexpr size_t O_BALL1  = 33751040;             // (4*2048*32) int
static constexpr size_t O_BALL2  = 34799616;             // (4*1024*32) int
static constexpr size_t O_NN0I   = 35323904;             // (4*2048*3) int
static constexpr size_t O_NN0W   = 35422208;             // (4*2048*3) f32
static constexpr size_t O_NN1I   = 35520512;             // (4*8192*3) int
static constexpr size_t O_NN1W   = 35913728;             // (4*8192*3) f32
static constexpr size_t O_REG0   = 36306944;             // 67108864 scratch
static constexpr size_t O_REG1   = 103415808;            // 67108864 scratch
static constexpr size_t WS_NEED  = 170524672;

typedef float v2f __attribute__((ext_vector_type(2)));

// ---------------- emb: xyz -> relu(bn(W2*relu(bn(W1*xyz)))) ----------------
__global__ __launch_bounds__(256) void emb_kernel(
    const float* __restrict__ xyz, const float* __restrict__ w1,
    const float* __restrict__ g1, const float* __restrict__ b1,
    const float* __restrict__ w2, const float* __restrict__ g2,
    const float* __restrict__ b2, float* __restrict__ out) {
  const int t = threadIdx.x;
  const int o = t & 63, pl = t >> 6;
  const int pt = blockIdx.x * 4 + pl;
  const float x0 = xyz[(size_t)pt * 3 + 0];
  const float x1 = xyz[(size_t)pt * 3 + 1];
  const float x2 = xyz[(size_t)pt * 3 + 2];
  const float SQ = sqrtf(1.0f + 1e-5f);
  float v = w1[o * 3 + 0] * x0 + w1[o * 3 + 1] * x1 + w1[o * 3 + 2] * x2;
  v = fmaxf(v * (g1[o] / SQ) + b1[o], 0.0f);
  __shared__ float h[4][64];
  h[pl][o] = v;
  __syncthreads();
  float acc = 0.0f;
  #pragma unroll 8
  for (int i = 0; i < 64; ++i) acc += w2[o * 64 + i] * h[pl][i];
  float y = fmaxf(acc * (g2[o] / SQ) + b2[o], 0.0f);
  out[(size_t)pt * 64 + o] = y;
}

// ---------------- DPP helpers for wave-64 u64 max reduce -------------------
__device__ __forceinline__ unsigned long long u64max(unsigned long long a,
                                                     unsigned long long b) {
  return a > b ? a : b;
}
template <int CTRL>
__device__ __forceinline__ unsigned long long dpp_step(unsigned long long k) {
  const int lo = (int)(unsigned)k;
  const int hi = (int)(unsigned)(k >> 32);
  // old = self, bound_ctrl = false -> invalid source lanes keep own value
  const int nlo = __builtin_amdgcn_update_dpp(lo, lo, CTRL, 0xf, 0xf, false);
  const int nhi = __builtin_amdgcn_update_dpp(hi, hi, CTRL, 0xf, 0xf, false);
  return ((unsigned long long)(unsigned)nhi << 32) | (unsigned)nlo;
}

// ---------------- farthest point sampling ----------------
// 256 threads per batch (1 wave/SIMD: halves per-SIMD issue of the duplicated
// tail; __launch_bounds__(256,1) allows ~180 VGPRs with no spill). Packed v2f
// distance math, fp contract(off) -> bit-exact vs numpy (separate mul/add
// rounding). Local argmax: explicit max TREE, then parallel ==bv bitmask +
// ctz (first occurrence, short chain; replaces serial 16-select chain).
// Cross-lane argmax on packed u64 key = bits(d)<<32 | ~idx (d>=0 so float
// bits order-monotone; tie -> min idx, matching jnp.argmax). In-wave reduce
// via DPP (row_shr 1/2/4/8 + bcast15/31 -> lane 63), pure VALU. One barrier
// per iter (parity double-buffered 4-key scratch); stage 2 = 4 pipelined
// broadcast u64 reads + 3 compares. fps index history kept in LDS so the
// new_xyz gather is folded into the epilogue (gatherxyz kernel removed).
template <int N, int NP>
__global__ __launch_bounds__(256, 1) void fps_kernel(
    const float* __restrict__ xyz, int* __restrict__ out,
    float* __restrict__ oxyz) {
  #pragma clang fp contract(off)
  constexpr int PPT = N / 256;
  constexpr int PAIRS = PPT / 2;
  const int b = blockIdx.x, t = threadIdx.x;
  const float* xb = xyz + (size_t)b * N * 3;
  __shared__ float sx[N], sy[N], sz[N];
  __shared__ int sfar[NP];
  __shared__ unsigned long long skey[2][4];
  for (int i = t; i < N; i += 256) {
    sx[i] = xb[i * 3 + 0];
    sy[i] = xb[i * 3 + 1];
    sz[i] = xb[i * 3 + 2];
  }
  __syncthreads();
  v2f px[PAIRS], py[PAIRS], pz[PAIRS], ds[PAIRS];
  #pragma unroll
  for (int k = 0; k < PAIRS; ++k) {
    const int g = t * PPT + 2 * k;
    px[k].x = sx[g]; px[k].y = sx[g + 1];
    py[k].x = sy[g]; py[k].y = sy[g + 1];
    pz[k].x = sz[g]; pz[k].y = sz[g + 1];
    ds[k].x = 1e10f; ds[k].y = 1e10f;
  }
  const int wid = t >> 6, lane = t & 63;
  int far = 0;
  float ccx = sx[0], ccy = sy[0], ccz = sz[0];
  for (int it = 0; it < NP; ++it) {
    if (t == 0) {
      out[(size_t)b * NP + it] = far;
      sfar[it] = far;
    }
    v2f cx2, cy2, cz2;
    cx2.x = ccx; cx2.y = ccx;
    cy2.x = ccy; cy2.y = ccy;
    cz2.x = ccz; cz2.y = ccz;
    // ---- packed distance update ----
    #pragma unroll
    for (int k = 0; k < PAIRS; ++k) {
      const v2f dx = px[k] - cx2;
      const v2f dy = py[k] - cy2;
      const v2f dz = pz[k] - cz2;
      const v2f d = dx * dx + dy * dy + dz * dz;
      v2f nd;
      nd.x = fminf(ds[k].x, d.x);
      nd.y = fminf(ds[k].y, d.y);
      ds[k] = nd;
    }
    // ---- local max: explicit tree (short chain) ----
    v2f tv[PAIRS / 2];
    #pragma unroll
    for (int k = 0; k < PAIRS / 2; ++k) {
      tv[k].x = fmaxf(ds[k].x, ds[k + PAIRS / 2].x);
      tv[k].y = fmaxf(ds[k].y, ds[k + PAIRS / 2].y);
    }
    #pragma unroll
    for (int w = PAIRS / 4; w >= 1; w >>= 1) {
      #pragma unroll
      for (int k = 0; k < w; ++k) {
        tv[k].x = fmaxf(tv[k].x, tv[k + w].x);
        tv[k].y = fmaxf(tv[k].y, tv[k + w].y);
      }
    }
    const float bv = fmaxf(tv[0].x, tv[0].y);
    // ---- first-occurrence index via parallel ==bv mask + ctz ----
    unsigned mask = 0u;
    #pragma unroll
    for (int k = 0; k < PAIRS; ++k) {
      mask |= (ds[k].x == bv) ? (1u << (2 * k)) : 0u;
      mask |= (ds[k].y == bv) ? (1u << (2 * k + 1)) : 0u;
    }
    const int bjl = __builtin_ctz(mask);
    unsigned long long bk =
        ((unsigned long long)__float_as_uint(bv) << 32) |
        (unsigned long long)(unsigned)(~(unsigned)(t * PPT + bjl));
    // ---- in-wave max reduce to lane 63 via DPP (pure VALU) ----
    bk = u64max(bk, dpp_step<0x111>(bk));  // row_shr:1
    bk = u64max(bk, dpp_step<0x112>(bk));  // row_shr:2
    bk = u64max(bk, dpp_step<0x114>(bk));  // row_shr:4
    bk = u64max(bk, dpp_step<0x118>(bk));  // row_shr:8
    bk = u64max(bk, dpp_step<0x142>(bk));  // row_bcast:15
    bk = u64max(bk, dpp_step<0x143>(bk));  // row_bcast:31
    const int p = it & 1;
    if (lane == 63) skey[p][wid] = bk;
    __syncthreads();
    // ---- every thread reduces the 4 wave winners (pipelined reads) ----
    unsigned long long wk = skey[p][0];
    #pragma unroll
    for (int q = 1; q < 4; ++q) {
      const unsigned long long k2 = skey[p][q];
      wk = (k2 > wk) ? k2 : wk;
    }
    far = (int)(~(unsigned)wk);
    ccx = sx[far]; ccy = sy[far]; ccz = sz[far];
  }
  // ---- fused new_xyz gather (replaces gatherxyz kernel) ----
  __syncthreads();
  for (int i = t; i < NP; i += 256) {
    const int n = sfar[i];
    oxyz[((size_t)b * NP + i) * 3 + 0] = sx[n];
    oxyz[((size_t)b * NP + i) * 3 + 1] = sy[n];
    oxyz[((size_t)b * NP + i) * 3 + 2] = sz[n];
  }
}

// ---------------- ball query: first 32 indices with d2 <= 1 ----------------
__global__ __launch_bounds__(256) void ball_kernel(
    const float* __restrict__ xyz, const float* __restrict__ ctr,
    int* __restrict__ out, int sbits, int N) {
  const int t = threadIdx.x;
  const int lane = t & 63, wid = t >> 6;
  const int wg = blockIdx.x * 4 + wid;   // global center id
  const int b = wg >> sbits;
  __shared__ int lists[4][32];
  const float cx = ctr[(size_t)wg * 3 + 0];
  const float cy = ctr[(size_t)wg * 3 + 1];
  const float cz = ctr[(size_t)wg * 3 + 2];
  const float an = __fadd_rn(__fadd_rn(__fmul_rn(cx, cx), __fmul_rn(cy, cy)),
                             __fmul_rn(cz, cz));
  int fill = 0;
  for (int ch = 0; ch < (N >> 6) && fill < 32; ++ch) {
    const int n = ch * 64 + lane;
    const float bx = xyz[((size_t)b * N + n) * 3 + 0];
    const float by = xyz[((size_t)b * N + n) * 3 + 1];
    const float bz = xyz[((size_t)b * N + n) * 3 + 2];
    const float bb = __fadd_rn(__fadd_rn(__fmul_rn(bx, bx), __fmul_rn(by, by)),
                               __fmul_rn(bz, bz));
    const float dot = __fadd_rn(__fadd_rn(__fmul_rn(cx, bx), __fmul_rn(cy, by)),
                                __fmul_rn(cz, bz));
    const float d2 = __fsub_rn(__fadd_rn(an, bb), __fmul_rn(2.0f, dot));
    const bool q = (d2 <= 1.0f);
    const unsigned long long mask = __ballot(q);
    if (q) {
      const int pos = fill + __popcll(mask & ((1ull << lane) - 1ull));
      if (pos < 32) lists[wid][pos] = n;
    }
    fill += (int)__popcll(mask);
  }
  __syncthreads();
  if (lane < 32) {
    int v = lists[wid][0];
    if (lane < fill) v = lists[wid][lane];
    out[(size_t)wg * 32 + lane] = v;
  }
}

// ---------------- grouped feature materialization ----------------
// row (chunk-local) -> [f[src]-f[ctr] (Cf) ; f[ctr] (Cf)]
__global__ __launch_bounds__(256) void groupmat_kernel(
    float* __restrict__ Xo, const float* __restrict__ f,
    const int* __restrict__ ball, const int* __restrict__ fps, int g0, int Cf,
    int c4bits, int sbits, int Npts) {
  const int id = blockIdx.x * 256 + threadIdx.x;
  const int c4mask = (1 << c4bits) - 1;
  const int row = id >> c4bits;
  const int col = (id & c4mask) * 4;
  const int gl = g0 + (row >> 5);
  const int k = row & 31;
  const int b = gl >> sbits;
  const int src = ball[(size_t)gl * 32 + k];
  const int ctr = fps[gl];
  const int C = Cf * 2;
  const float* fb = f + (size_t)b * Npts * Cf;
  float4 v;
  if (col < Cf) {
    const float4 a = *(const float4*)(fb + (size_t)src * Cf + col);
    const float4 c = *(const float4*)(fb + (size_t)ctr * Cf + col);
    v = make_float4(a.x - c.x, a.y - c.y, a.z - c.z, a.w - c.w);
  } else {
    v = *(const float4*)(fb + (size_t)ctr * Cf + (col - Cf));
  }
  *(float4*)(Xo + (size_t)row * C + col) = v;
}

// ---------------- generic 1x1 conv (GEMM) with BN/bias/ReLU epilogue -------
// LDS tiles chunk-padded: 8-float chunk stored in a 12-float slot so the 16
// lanes' ds_read_b128 hit disjoint 16B bank ranges (kills the 4-way read
// conflict of the 32B-strided layout; writes stay <=2-way = free).
#define CMAP(c) ((((c) >> 3) * 12) + ((c) & 7))
__global__ __launch_bounds__(256) void conv_kernel(
    const float* __restrict__ X, const float* __restrict__ W,
    float* __restrict__ Y, int C, int O, const float* __restrict__ gamma,
    const float* __restrict__ beta, const float* __restrict__ bias, int relu) {
  __shared__ float Xs[16][188];
  __shared__ float Ws[16][188];
  const int t = threadIdx.x;
  const size_t m0 = (size_t)blockIdx.x * 128;
  const int o0 = blockIdx.y * 128;
  const int r0 = t >> 2;
  const int cq0 = (t & 3) * 4;
  const int mq = t & 15, nq = t >> 4;
  const int ca = CMAP(r0), cb = CMAP(r0 + 64);
  float acc[8][8];
  #pragma unroll
  for (int i = 0; i < 8; ++i)
    #pragma unroll
    for (int j = 0; j < 8; ++j) acc[i][j] = 0.0f;

  for (int kk = 0; kk < C; kk += 16) {
    const float4 xa = *(const float4*)(X + (m0 + r0) * C + kk + cq0);
    const float4 xb = *(const float4*)(X + (m0 + r0 + 64) * C + kk + cq0);
    const float4 wa = *(const float4*)(W + (size_t)(o0 + r0) * C + kk + cq0);
    const float4 wb = *(const float4*)(W + (size_t)(o0 + r0 + 64) * C + kk + cq0);
    __syncthreads();
    Xs[cq0 + 0][ca] = xa.x; Xs[cq0 + 1][ca] = xa.y;
    Xs[cq0 + 2][ca] = xa.z; Xs[cq0 + 3][ca] = xa.w;
    Xs[cq0 + 0][cb] = xb.x; Xs[cq0 + 1][cb] = xb.y;
    Xs[cq0 + 2][cb] = xb.z; Xs[cq0 + 3][cb] = xb.w;
    Ws[cq0 + 0][ca] = wa.x; Ws[cq0 + 1][ca] = wa.y;
    Ws[cq0 + 2][ca] = wa.z; Ws[cq0 + 3][ca] = wa.w;
    Ws[cq0 + 0][cb] = wb.x; Ws[cq0 + 1][cb] = wb.y;
    Ws[cq0 + 2][cb] = wb.z; Ws[cq0 + 3][cb] = wb.w;
    __syncthreads();
    #pragma unroll
    for (int k = 0; k < 16; ++k) {
      const float4 a0 = *(const float4*)&Xs[k][mq * 12];
      const float4 a1 = *(const float4*)&Xs[k][mq * 12 + 4];
      const float4 b0 = *(const float4*)&Ws[k][nq * 12];
      const float4 b1 = *(const float4*)&Ws[k][nq * 12 + 4];
      const float am[8] = {a0.x, a0.y, a0.z, a0.w, a1.x, a1.y, a1.z, a1.w};
      const float bm[8] = {b0.x, b0.y, b0.z, b0.w, b1.x, b1.y, b1.z, b1.w};
      #pragma unroll
      for (int i = 0; i < 8; ++i)
        #pragma unroll
        for (int j = 0; j < 8; ++j) acc[i][j] += am[i] * bm[j];
    }
  }

  const float SQ = sqrtf(1.0f + 1e-5f);
  float s[8], sh[8];
  #pragma unroll
  for (int j = 0; j < 8; ++j) {
    const int o = o0 + nq * 8 + j;
    const float sc = gamma ? (gamma[o] / SQ) : 1.0f;
    float bb = beta ? beta[o] : 0.0f;
    if (bias) bb = bb + bias[o] * sc;
    s[j] = sc; sh[j] = bb;
  }
  #pragma unroll
  for (int i = 0; i < 8; ++i) {
    float y[8];
    #pragma unroll
    for (int j = 0; j < 8; ++j) {
      float v = acc[i][j] * s[j] + sh[j];
      y[j] = relu ? fmaxf(v, 0.0f) : v;
    }
    const size_t off = (m0 + mq * 8 + i) * O + o0 + nq * 8;
    *(float4*)(Y + off) = make_float4(y[0], y[1], y[2], y[3]);
    *(float4*)(Y + off + 4) = make_float4(y[4], y[5], y[6], y[7]);
  }
}

// ---------------- segmented max over 32 samples ----------------
__global__ __launch_bounds__(256) void segmax_kernel(
    const float* __restrict__ Y, float* __restrict__ F, int O, int obits) {
  const int id = blockIdx.x * 256 + threadIdx.x;
  const int g = id >> obits;
  const int o = id & (O - 1);
  float m = -3.4e38f;
  #pragma unroll 8
  for (int k = 0; k < 32; ++k)
    m = fmaxf(m, Y[((size_t)g * 32 + k) * O + o]);
  F[(size_t)g * O + o] = m;
}

// ---------------- 3-NN search (stable, strict <) ----------------
__global__ __launch_bounds__(256) void nn3_kernel(
    const float* __restrict__ txyz, const float* __restrict__ sxyz,
    int* __restrict__ oi, float* __restrict__ ow, int s1bits, int S2) {
  __shared__ float ss[6144];
  const int t = threadIdx.x;
  const int row = blockIdx.x * 256 + t;
  const int b = row >> s1bits;
  for (int i = t; i < S2 * 3; i += 256) ss[i] = sxyz[(size_t)b * S2 * 3 + i];
  __syncthreads();
  const float ax = txyz[(size_t)row * 3 + 0];
  const float ay = txyz[(size_t)row * 3 + 1];
  const float az = txyz[(size_t)row * 3 + 2];
  const float an = __fadd_rn(__fadd_rn(__fmul_rn(ax, ax), __fmul_rn(ay, ay)),
                             __fmul_rn(az, az));
  float d0 = 3.4e38f, d1 = 3.4e38f, d2v = 3.4e38f;
  int i0 = 0, i1 = 0, i2 = 0;
  for (int j = 0; j < S2; ++j) {
    const float bx = ss[j * 3 + 0], by = ss[j * 3 + 1], bz = ss[j * 3 + 2];
    const float bb = __fadd_rn(__fadd_rn(__fmul_rn(bx, bx), __fmul_rn(by, by)),
                               __fmul_rn(bz, bz));
    const float dot = __fadd_rn(__fadd_rn(__fmul_rn(ax, bx), __fmul_rn(ay, by)),
                                __fmul_rn(az, bz));
    const float dd = __fsub_rn(__fadd_rn(an, bb), __fmul_rn(2.0f, dot));
    if (dd < d0) {
      d2v = d1; i2 = i1; d1 = d0; i1 = i0; d0 = dd; i0 = j;
    } else if (dd < d1) {
      d2v = d1; i2 = i1; d1 = dd; i1 = j;
    } else if (dd < d2v) {
      d2v = dd; i2 = j;
    }
  }
  const float r0 = 1.0f / (d0 + 1e-8f);
  const float r1 = 1.0f / (d1 + 1e-8f);
  const float r2 = 1.0f / (d2v + 1e-8f);
  const float sum = __fadd_rn(__fadd_rn(r0, r1), r2);
  oi[(size_t)row * 3 + 0] = i0;
  oi[(size_t)row * 3 + 1] = i1;
  oi[(size_t)row * 3 + 2] = i2;
  ow[(size_t)row * 3 + 0] = r0 / sum;
  ow[(size_t)row * 3 + 1] = r1 / sum;
  ow[(size_t)row * 3 + 2] = r2 / sum;
}

// ---------------- weighted 3-point interpolation into concat columns -------
__global__ __launch_bounds__(256) void interp_kernel(
    float* __restrict__ dst, int CT, int c0, const float* __restrict__ src,
    const int* __restrict__ idx, const float* __restrict__ w, int csbits,
    int s1bits, int S2) {
  const int id = blockIdx.x * 256 + threadIdx.x;
  const int row = id >> csbits;
  const int c4 = (id & ((1 << csbits) - 1)) * 4;
  const int Cs = 4 << csbits;
  const int b = row >> s1bits;
  const int j0 = idx[(size_t)row * 3 + 0];
  const int j1 = idx[(size_t)row * 3 + 1];
  const int j2 = idx[(size_t)row * 3 + 2];
  const float w0 = w[(size_t)row * 3 + 0];
  const float w1 = w[(size_t)row * 3 + 1];
  const float w2 = w[(size_t)row * 3 + 2];
  const float4 f0 = *(const float4*)(src + ((size_t)b * S2 + j0) * Cs + c4);
  const float4 f1 = *(const float4*)(src + ((size_t)b * S2 + j1) * Cs + c4);
  const float4 f2 = *(const float4*)(src + ((size_t)b * S2 + j2) * Cs + c4);
  float4 v;
  v.x = f0.x * w0 + f1.x * w1 + f2.x * w2;
  v.y = f0.y * w0 + f1.y * w1 + f2.y * w2;
  v.z = f0.z * w0 + f1.z * w1 + f2.z * w2;
  v.w = f0.w * w0 + f1.w * w1 + f2.w * w2;
  *(float4*)(dst + (size_t)row * CT + c0 + c4) = v;
}

// ---------------- copy columns into concat buffer ----------------
__global__ __launch_bounds__(256) void copycols_kernel(
    float* __restrict__ dst, int CT, int c0, const float* __restrict__ src,
    int csbits) {
  const int id = blockIdx.x * 256 + threadIdx.x;
  const int row = id >> csbits;
  const int c4 = (id & ((1 << csbits) - 1)) * 4;
  const int Cs = 4 << csbits;
  const float4 v = *(const float4*)(src + (size_t)row * Cs + c4);
  *(float4*)(dst + (size_t)row * CT + c0 + c4) = v;
}

// ---------------- final 128->8 conv + bias, point-major out ----------------
__global__ __launch_bounds__(256) void outfinal_kernel(
    const float* __restrict__ X, const float* __restrict__ Wt,
    const float* __restrict__ bias, float* __restrict__ out) {
  __shared__ float Xs[32][132];
  const int t = threadIdx.x;
  const int p0 = blockIdx.x * 32;
  #pragma unroll
  for (int q = 0; q < 4; ++q) {
    const int id = t + q * 256;
    const int r = id >> 5, c4 = (id & 31) * 4;
    const float4 v = *(const float4*)(X + (size_t)(p0 + r) * 128 + c4);
    Xs[r][c4 + 0] = v.x; Xs[r][c4 + 1] = v.y;
    Xs[r][c4 + 2] = v.z; Xs[r][c4 + 3] = v.w;
  }
  __syncthreads();
  const int p = t >> 3, o = t & 7;
  float acc = 0.0f;
  #pragma unroll 8
  for (int i = 0; i < 128; ++i) acc += Wt[o * 128 + i] * Xs[p][i];
  out[(size_t)(p0 + p) * 8 + o] = acc + bias[o];
}

// ---------------------------------------------------------------------------
extern "C" void kernel_launch(void* const* d_in, const int* in_sizes, int n_in,
                              void* d_out, int out_size, void* d_ws,
                              size_t ws_size, hipStream_t stream) {
  const float* x       = (const float*)d_in[0];
  const float* w_emb1  = (const float*)d_in[1];
  const float* g_emb1  = (const float*)d_in[2];
  const float* be_emb1 = (const float*)d_in[3];
  const float* w_emb2  = (const float*)d_in[4];
  const float* g_emb2  = (const float*)d_in[5];
  const float* be_emb2 = (const float*)d_in[6];
  const float* l0_w1 = (const float*)d_in[7];
  const float* l0_g1 = (const float*)d_in[8];
  const float* l0_b1 = (const float*)d_in[9];
  const float* l0_w2 = (const float*)d_in[10];
  const float* l0_g2 = (const float*)d_in[11];
  const float* l0_b2 = (const float*)d_in[12];
  const float* l1_w1 = (const float*)d_in[13];
  const float* l1_g1 = (const float*)d_in[14];
  const float* l1_b1 = (const float*)d_in[15];
  const float* l1_w2 = (const float*)d_in[16];
  const float* l1_g2 = (const float*)d_in[17];
  const float* l1_b2 = (const float*)d_in[18];
  const float* f0_w1 = (const float*)d_in[19];
  const float* f0_g1 = (const float*)d_in[20];
  const float* f0_b1 = (const float*)d_in[21];
  const float* f0_w2 = (const float*)d_in[22];
  const float* f0_g2 = (const float*)d_in[23];
  const float* f0_b2 = (const float*)d_in[24];
  const float* f1_w1 = (const float*)d_in[25];
  const float* f1_g1 = (const float*)d_in[26];
  const float* f1_b1 = (const float*)d_in[27];
  const float* f1_w2 = (const float*)d_in[28];
  const float* f1_g2 = (const float*)d_in[29];
  const float* f1_b2 = (const float*)d_in[30];
  const float* c1_w    = (const float*)d_in[31];
  const float* c1_bias = (const float*)d_in[32];
  const float* c1_g    = (const float*)d_in[33];
  const float* c1_beta = (const float*)d_in[34];
  const float* c2_w    = (const float*)d_in[35];
  const float* c2_bias = (const float*)d_in[36];
  const float* c2_g    = (const float*)d_in[37];
  const float* c2_beta = (const float*)d_in[38];
  const float* out_w    = (const float*)d_in[39];
  const float* out_bias = (const float*)d_in[40];

  if (ws_size < WS_NEED) return;  // cannot run without scratch

  char* ws = (char*)d_ws;
  float* feats0 = (float*)(ws + O_FEATS0);
  float* feats1 = (float*)(ws + O_FEATS1);
  float* feats2 = (float*)(ws + O_FEATS2);
  float* fp0out = (float*)(ws + O_FP0OUT);
  float* xyz1   = (float*)(ws + O_XYZ1);
  float* xyz2   = (float*)(ws + O_XYZ2);
  int*   fps1   = (int*)(ws + O_FPS1);
  int*   fps2   = (int*)(ws + O_FPS2);
  int*   ball1  = (int*)(ws + O_BALL1);
  int*   ball2  = (int*)(ws + O_BALL2);
  int*   nn0i   = (int*)(ws + O_NN0I);
  float* nn0w   = (float*)(ws + O_NN0W);
  int*   nn1i   = (int*)(ws + O_NN1I);
  float* nn1w   = (float*)(ws + O_NN1W);
  float* REG0   = (float*)(ws + O_REG0);
  float* REG1   = (float*)(ws + O_REG1);
  float* outp   = (float*)d_out;
  hipStream_t s = stream;

  // ---- embedding MLP: (B*8192, 64) ----
  emb_kernel<<<8192, 256, 0, s>>>(x, w_emb1, g_emb1, be_emb1, w_emb2, g_emb2,
                                  be_emb2, feats0);

  // ---- SA layer 1 ----
  fps_kernel<8192, 2048><<<4, 256, 0, s>>>(x, fps1, xyz1);
  ball_kernel<<<2048, 256, 0, s>>>(x, xyz1, ball1, 11, 8192);
  for (int c = 0; c < 2; ++c) {
    groupmat_kernel<<<16384, 256, 0, s>>>(REG0, feats0, ball1, fps1, c * 4096,
                                          64, 5, 11, 8192);
    conv_kernel<<<dim3(1024, 1), 256, 0, s>>>(REG0, l0_w1, REG1, 128, 128,
                                              l0_g1, l0_b1, nullptr, 1);
    conv_kernel<<<dim3(1024, 1), 256, 0, s>>>(REG1, l0_w2, REG0, 128, 128,
                                              l0_g2, l0_b2, nullptr, 1);
    segmax_kernel<<<2048, 256, 0, s>>>(REG0, feats1 + (size_t)c * 4096 * 128,
                                       128, 7);
  }

  // ---- SA layer 2 ----
  fps_kernel<2048, 1024><<<4, 256, 0, s>>>(xyz1, fps2, xyz2);
  ball_kernel<<<1024, 256, 0, s>>>(xyz1, xyz2, ball2, 10, 2048);
  for (int c = 0; c < 2; ++c) {
    groupmat_kernel<<<16384, 256, 0, s>>>(REG0, feats1, ball2, fps2, c * 2048,
                                          128, 6, 10, 2048);
    conv_kernel<<<dim3(512, 2), 256, 0, s>>>(REG0, l1_w1, REG1, 256, 256,
                                             l1_g1, l1_b1, nullptr, 1);
    conv_kernel<<<dim3(512, 2), 256, 0, s>>>(REG1, l1_w2, REG0, 256, 256,
                                             l1_g2, l1_b2, nullptr, 1);
    segmax_kernel<<<2048, 256, 0, s>>>(REG0, feats2 + (size_t)c * 2048 * 256,
                                       256, 8);
  }

  // ---- feature propagation 0: 1024 -> 2048 points ----
  nn3_kernel<<<32, 256, 0, s>>>(xyz1, xyz2, nn0i, nn0w, 11, 1024);
  copycols_kernel<<<1024, 256, 0, s>>>(REG0, 384, 0, feats1, 5);
  interp_kernel<<<2048, 256, 0, s>>>(REG0, 384, 128, feats2, nn0i, nn0w, 6, 11,
                                     1024);
  conv_kernel<<<dim3(64, 2), 256, 0, s>>>(REG0, f0_w1, REG1, 384, 256, f0_g1,
                                          f0_b1, nullptr, 1);
  conv_kernel<<<dim3(64, 4), 256, 0, s>>>(REG1, f0_w2, fp0out, 256, 512, f0_g2,
                                          f0_b2, nullptr, 1);

  // ---- feature propagation 1 + head, chunked per 2 batches ----
  nn3_kernel<<<128, 256, 0, s>>>(x, xyz1, nn1i, nn1w, 13, 2048);
  for (int b = 0; b < 4; b += 2) {
    copycols_kernel<<<1024, 256, 0, s>>>(REG0, 576, 0,
                                         feats0 + (size_t)b * 8192 * 64, 4);
    interp_kernel<<<8192, 256, 0, s>>>(REG0, 576, 64,
                                       fp0out + (size_t)b * 2048 * 512,
                                       nn1i + (size_t)b * 8192 * 3,
                                       nn1w + (size_t)b * 8192 * 3, 7, 13,
                                       2048);
    conv_kernel<<<dim3(128, 4), 256, 0, s>>>(REG0, f1_w1, REG1, 576, 512,
                                             f1_g1, f1_b1, nullptr, 1);
    conv_kernel<<<dim3(128, 8), 256, 0, s>>>(REG1, f1_w2, REG0, 512, 1024,
                                             f1_g2, f1_b2, nullptr, 1);
    conv_kernel<<<dim3(128, 4), 256, 0, s>>>(REG0, c1_w, REG1, 1024, 512,
                                             c1_g, c1_beta, c1_bias, 1);
    conv_kernel<<<dim3(128, 1), 256, 0, s>>>(REG1, c2_w, REG0, 512, 128,
                                             c2_g, c2_beta, c2_bias, 1);
    outfinal_kernel<<<512, 256, 0, s>>>(REG0, out_w, out_bias,
                                        outp + (size_t)b * 8192 * 8);
  }
}

// Round 8
// 4994.735 us; speedup vs baseline: 1.4433x; 1.0330x over previous
//
#include <hip/hip_runtime.h>
#include <math.h>

// ---------------------------------------------------------------------------
// PointNet++ part-seg forward. All features stored point-major: row = point,
// C contiguous floats per row. B=4, N=8192 fixed by the problem.
// ---------------------------------------------------------------------------

// ---------------- workspace layout (bytes) ----------------
static constexpr size_t O_FEATS0 = 0;                    // (4*8192, 64)  f32
static constexpr size_t O_FEATS1 = 8388608;              // (4*2048, 128)
static constexpr size_t O_FEATS2 = 12582912;             // (4*1024, 256)
static constexpr size_t O_FP0OUT = 16777216;             // (4*2048, 512)
static constexpr size_t O_XYZ1   = 33554432;             // (4*2048, 3)
static constexpr size_t O_XYZ2   = 33652736;             // (4*1024, 3)
static constexpr size_t O_FPS1   = 33701888;             // (4*2048) int
static constexpr size_t O_FPS2   = 33734656;             // (4*1024) int
static constexpr size_t O_BALL1  = 33751040;             // (4*2048*32) int
static constexpr size_t O_BALL2  = 34799616;             // (4*1024*32) int
static constexpr size_t O_NN0I   = 35323904;             // (4*2048*3) int
static constexpr size_t O_NN0W   = 35422208;             // (4*2048*3) f32
static constexpr size_t O_NN1I   = 35520512;             // (4*8192*3) int
static constexpr size_t O_NN1W   = 35913728;             // (4*8192*3) f32
static constexpr size_t O_REG0   = 36306944;             // 67108864 scratch
static constexpr size_t O_REG1   = 103415808;            // 67108864 scratch
static constexpr size_t WS_NEED  = 170524672;

typedef float v2f __attribute__((ext_vector_type(2)));

// ---------------- emb: xyz -> relu(bn(W2*relu(bn(W1*xyz)))) ----------------
__global__ __launch_bounds__(256) void emb_kernel(
    const float* __restrict__ xyz, const float* __restrict__ w1,
    const float* __restrict__ g1, const float* __restrict__ b1,
    const float* __restrict__ w2, const float* __restrict__ g2,
    const float* __restrict__ b2, float* __restrict__ out) {
  const int t = threadIdx.x;
  const int o = t & 63, pl = t >> 6;
  const int pt = blockIdx.x * 4 + pl;
  const float x0 = xyz[(size_t)pt * 3 + 0];
  const float x1 = xyz[(size_t)pt * 3 + 1];
  const float x2 = xyz[(size_t)pt * 3 + 2];
  const float SQ = sqrtf(1.0f + 1e-5f);
  float v = w1[o * 3 + 0] * x0 + w1[o * 3 + 1] * x1 + w1[o * 3 + 2] * x2;
  v = fmaxf(v * (g1[o] / SQ) + b1[o], 0.0f);
  __shared__ float h[4][64];
  h[pl][o] = v;
  __syncthreads();
  float acc = 0.0f;
  #pragma unroll 8
  for (int i = 0; i < 64; ++i) acc += w2[o * 64 + i] * h[pl][i];
  float y = fmaxf(acc * (g2[o] / SQ) + b2[o], 0.0f);
  out[(size_t)pt * 64 + o] = y;
}

// ---------------- DPP helpers for wave-64 u64 max reduce -------------------
__device__ __forceinline__ unsigned long long u64max(unsigned long long a,
                                                     unsigned long long b) {
  return a > b ? a : b;
}
template <int CTRL>
__device__ __forceinline__ unsigned long long dpp_step(unsigned long long k) {
  const int lo = (int)(unsigned)k;
  const int hi = (int)(unsigned)(k >> 32);
  // old = self, bound_ctrl = false -> invalid source lanes keep own value
  const int nlo = __builtin_amdgcn_update_dpp(lo, lo, CTRL, 0xf, 0xf, false);
  const int nhi = __builtin_amdgcn_update_dpp(hi, hi, CTRL, 0xf, 0xf, false);
  return ((unsigned long long)(unsigned)nhi << 32) | (unsigned)nlo;
}

// ---------------- farthest point sampling ----------------
// 256 threads per batch. Packed v2f distance math, fp contract(off) ->
// bit-exact vs numpy (separate mul/add rounding). Local argmax: max tree +
// parallel ==bv bitmask + ctz (first occurrence). Cross-lane argmax on
// packed u64 key = bits(d)<<32 | ~idx (d>=0 so float bits order-monotone;
// tie -> min idx, matching jnp.argmax). In-wave reduce via DPP
// (row_shr 1/2/4/8 + bcast15/31 -> lane 63), pure VALU. One barrier/iter
// (parity double-buffered 4-key scratch); stage 2 = 4 pipelined broadcast
// u64 reads + 3 compares. out[] + new_xyz both written in the epilogue from
// the sfar history (global store removed from the serial loop).
template <int N, int NP>
__global__ __launch_bounds__(256, 1) void fps_kernel(
    const float* __restrict__ xyz, int* __restrict__ out,
    float* __restrict__ oxyz) {
  #pragma clang fp contract(off)
  constexpr int PPT = N / 256;
  constexpr int PAIRS = PPT / 2;
  const int b = blockIdx.x, t = threadIdx.x;
  const float* xb = xyz + (size_t)b * N * 3;
  __shared__ float sx[N], sy[N], sz[N];
  __shared__ int sfar[NP];
  __shared__ unsigned long long skey[2][4];
  for (int i = t; i < N; i += 256) {
    sx[i] = xb[i * 3 + 0];
    sy[i] = xb[i * 3 + 1];
    sz[i] = xb[i * 3 + 2];
  }
  __syncthreads();
  v2f px[PAIRS], py[PAIRS], pz[PAIRS], ds[PAIRS];
  #pragma unroll
  for (int k = 0; k < PAIRS; ++k) {
    const int g = t * PPT + 2 * k;
    px[k].x = sx[g]; px[k].y = sx[g + 1];
    py[k].x = sy[g]; py[k].y = sy[g + 1];
    pz[k].x = sz[g]; pz[k].y = sz[g + 1];
    ds[k].x = 1e10f; ds[k].y = 1e10f;
  }
  const int wid = t >> 6, lane = t & 63;
  int far = 0;
  float ccx = sx[0], ccy = sy[0], ccz = sz[0];
  for (int it = 0; it < NP; ++it) {
    if (t == 0) sfar[it] = far;
    v2f cx2, cy2, cz2;
    cx2.x = ccx; cx2.y = ccx;
    cy2.x = ccy; cy2.y = ccy;
    cz2.x = ccz; cz2.y = ccz;
    // ---- packed distance update ----
    #pragma unroll
    for (int k = 0; k < PAIRS; ++k) {
      const v2f dx = px[k] - cx2;
      const v2f dy = py[k] - cy2;
      const v2f dz = pz[k] - cz2;
      const v2f d = dx * dx + dy * dy + dz * dz;
      v2f nd;
      nd.x = fminf(ds[k].x, d.x);
      nd.y = fminf(ds[k].y, d.y);
      ds[k] = nd;
    }
    // ---- local max: explicit tree (short chain) ----
    v2f tv[PAIRS / 2];
    #pragma unroll
    for (int k = 0; k < PAIRS / 2; ++k) {
      tv[k].x = fmaxf(ds[k].x, ds[k + PAIRS / 2].x);
      tv[k].y = fmaxf(ds[k].y, ds[k + PAIRS / 2].y);
    }
    #pragma unroll
    for (int w = PAIRS / 4; w >= 1; w >>= 1) {
      #pragma unroll
      for (int k = 0; k < w; ++k) {
        tv[k].x = fmaxf(tv[k].x, tv[k + w].x);
        tv[k].y = fmaxf(tv[k].y, tv[k + w].y);
      }
    }
    const float bv = fmaxf(tv[0].x, tv[0].y);
    // ---- first-occurrence index via parallel ==bv mask + ctz ----
    unsigned mask = 0u;
    #pragma unroll
    for (int k = 0; k < PAIRS; ++k) {
      mask |= (ds[k].x == bv) ? (1u << (2 * k)) : 0u;
      mask |= (ds[k].y == bv) ? (1u << (2 * k + 1)) : 0u;
    }
    const int bjl = __builtin_ctz(mask);
    unsigned long long bk =
        ((unsigned long long)__float_as_uint(bv) << 32) |
        (unsigned long long)(unsigned)(~(unsigned)(t * PPT + bjl));
    // ---- in-wave max reduce to lane 63 via DPP (pure VALU) ----
    bk = u64max(bk, dpp_step<0x111>(bk));  // row_shr:1
    bk = u64max(bk, dpp_step<0x112>(bk));  // row_shr:2
    bk = u64max(bk, dpp_step<0x114>(bk));  // row_shr:4
    bk = u64max(bk, dpp_step<0x118>(bk));  // row_shr:8
    bk = u64max(bk, dpp_step<0x142>(bk));  // row_bcast:15
    bk = u64max(bk, dpp_step<0x143>(bk));  // row_bcast:31
    const int p = it & 1;
    if (lane == 63) skey[p][wid] = bk;
    __syncthreads();
    // ---- every thread reduces the 4 wave winners (pipelined reads) ----
    unsigned long long wk = skey[p][0];
    #pragma unroll
    for (int q = 1; q < 4; ++q) {
      const unsigned long long k2 = skey[p][q];
      wk = (k2 > wk) ? k2 : wk;
    }
    far = (int)(~(unsigned)wk);
    ccx = sx[far]; ccy = sy[far]; ccz = sz[far];
  }
  // ---- epilogue: write fps indices + gathered new_xyz from history ----
  __syncthreads();
  for (int i = t; i < NP; i += 256) {
    const int n = sfar[i];
    out[(size_t)b * NP + i] = n;
    oxyz[((size_t)b * NP + i) * 3 + 0] = sx[n];
    oxyz[((size_t)b * NP + i) * 3 + 1] = sy[n];
    oxyz[((size_t)b * NP + i) * 3 + 2] = sz[n];
  }
}

// ---------------- ball query: first 32 indices with d2 <= 1 ----------------
__global__ __launch_bounds__(256) void ball_kernel(
    const float* __restrict__ xyz, const float* __restrict__ ctr,
    int* __restrict__ out, int sbits, int N) {
  const int t = threadIdx.x;
  const int lane = t & 63, wid = t >> 6;
  const int wg = blockIdx.x * 4 + wid;   // global center id
  const int b = wg >> sbits;
  __shared__ int lists[4][32];
  const float cx = ctr[(size_t)wg * 3 + 0];
  const float cy = ctr[(size_t)wg * 3 + 1];
  const float cz = ctr[(size_t)wg * 3 + 2];
  const float an = __fadd_rn(__fadd_rn(__fmul_rn(cx, cx), __fmul_rn(cy, cy)),
                             __fmul_rn(cz, cz));
  int fill = 0;
  for (int ch = 0; ch < (N >> 6) && fill < 32; ++ch) {
    const int n = ch * 64 + lane;
    const float bx = xyz[((size_t)b * N + n) * 3 + 0];
    const float by = xyz[((size_t)b * N + n) * 3 + 1];
    const float bz = xyz[((size_t)b * N + n) * 3 + 2];
    const float bb = __fadd_rn(__fadd_rn(__fmul_rn(bx, bx), __fmul_rn(by, by)),
                               __fmul_rn(bz, bz));
    const float dot = __fadd_rn(__fadd_rn(__fmul_rn(cx, bx), __fmul_rn(cy, by)),
                                __fmul_rn(cz, bz));
    const float d2 = __fsub_rn(__fadd_rn(an, bb), __fmul_rn(2.0f, dot));
    const bool q = (d2 <= 1.0f);
    const unsigned long long mask = __ballot(q);
    if (q) {
      const int pos = fill + __popcll(mask & ((1ull << lane) - 1ull));
      if (pos < 32) lists[wid][pos] = n;
    }
    fill += (int)__popcll(mask);
  }
  __syncthreads();
  if (lane < 32) {
    int v = lists[wid][0];
    if (lane < fill) v = lists[wid][lane];
    out[(size_t)wg * 32 + lane] = v;
  }
}

// ---------------- grouped feature materialization ----------------
// row (chunk-local) -> [f[src]-f[ctr] (Cf) ; f[ctr] (Cf)]
__global__ __launch_bounds__(256) void groupmat_kernel(
    float* __restrict__ Xo, const float* __restrict__ f,
    const int* __restrict__ ball, const int* __restrict__ fps, int g0, int Cf,
    int c4bits, int sbits, int Npts) {
  const int id = blockIdx.x * 256 + threadIdx.x;
  const int c4mask = (1 << c4bits) - 1;
  const int row = id >> c4bits;
  const int col = (id & c4mask) * 4;
  const int gl = g0 + (row >> 5);
  const int k = row & 31;
  const int b = gl >> sbits;
  const int src = ball[(size_t)gl * 32 + k];
  const int ctr = fps[gl];
  const int C = Cf * 2;
  const float* fb = f + (size_t)b * Npts * Cf;
  float4 v;
  if (col < Cf) {
    const float4 a = *(const float4*)(fb + (size_t)src * Cf + col);
    const float4 c = *(const float4*)(fb + (size_t)ctr * Cf + col);
    v = make_float4(a.x - c.x, a.y - c.y, a.z - c.z, a.w - c.w);
  } else {
    v = *(const float4*)(fb + (size_t)ctr * Cf + (col - Cf));
  }
  *(float4*)(Xo + (size_t)row * C + col) = v;
}

// ---------------- generic 1x1 conv (GEMM) with BN/bias/ReLU epilogue -------
// LDS tiles chunk-padded (8-float chunk in a 12-float slot, conflict-free
// b128 reads). Inner loop uses PACKED f32 accumulation: acc[i][j] is v2f and
// each update is splat(am[i]) * bpair[j] + acc -> maps to v_pk_fma_f32
// (VOP3P packed FP32, gfx90a+), halving FMA instruction issue vs scalar.
#define CMAP(c) ((((c) >> 3) * 12) + ((c) & 7))
__global__ __launch_bounds__(256) void conv_kernel(
    const float* __restrict__ X, const float* __restrict__ W,
    float* __restrict__ Y, int C, int O, const float* __restrict__ gamma,
    const float* __restrict__ beta, const float* __restrict__ bias, int relu) {
  __shared__ float Xs[16][188];
  __shared__ float Ws[16][188];
  const int t = threadIdx.x;
  const size_t m0 = (size_t)blockIdx.x * 128;
  const int o0 = blockIdx.y * 128;
  const int r0 = t >> 2;
  const int cq0 = (t & 3) * 4;
  const int mq = t & 15, nq = t >> 4;
  const int ca = CMAP(r0), cb = CMAP(r0 + 64);
  v2f acc[8][4];
  #pragma unroll
  for (int i = 0; i < 8; ++i)
    #pragma unroll
    for (int j = 0; j < 4; ++j) acc[i][j] = (v2f){0.0f, 0.0f};

  for (int kk = 0; kk < C; kk += 16) {
    const float4 xa = *(const float4*)(X + (m0 + r0) * C + kk + cq0);
    const float4 xb = *(const float4*)(X + (m0 + r0 + 64) * C + kk + cq0);
    const float4 wa = *(const float4*)(W + (size_t)(o0 + r0) * C + kk + cq0);
    const float4 wb = *(const float4*)(W + (size_t)(o0 + r0 + 64) * C + kk + cq0);
    __syncthreads();
    Xs[cq0 + 0][ca] = xa.x; Xs[cq0 + 1][ca] = xa.y;
    Xs[cq0 + 2][ca] = xa.z; Xs[cq0 + 3][ca] = xa.w;
    Xs[cq0 + 0][cb] = xb.x; Xs[cq0 + 1][cb] = xb.y;
    Xs[cq0 + 2][cb] = xb.z; Xs[cq0 + 3][cb] = xb.w;
    Ws[cq0 + 0][ca] = wa.x; Ws[cq0 + 1][ca] = wa.y;
    Ws[cq0 + 2][ca] = wa.z; Ws[cq0 + 3][ca] = wa.w;
    Ws[cq0 + 0][cb] = wb.x; Ws[cq0 + 1][cb] = wb.y;
    Ws[cq0 + 2][cb] = wb.z; Ws[cq0 + 3][cb] = wb.w;
    __syncthreads();
    #pragma unroll
    for (int k = 0; k < 16; ++k) {
      const float4 a0 = *(const float4*)&Xs[k][mq * 12];
      const float4 a1 = *(const float4*)&Xs[k][mq * 12 + 4];
      const float4 b0 = *(const float4*)&Ws[k][nq * 12];
      const float4 b1 = *(const float4*)&Ws[k][nq * 12 + 4];
      const float am[8] = {a0.x, a0.y, a0.z, a0.w, a1.x, a1.y, a1.z, a1.w};
      v2f bv[4];
      bv[0] = (v2f){b0.x, b0.y};
      bv[1] = (v2f){b0.z, b0.w};
      bv[2] = (v2f){b1.x, b1.y};
      bv[3] = (v2f){b1.z, b1.w};
      #pragma unroll
      for (int i = 0; i < 8; ++i) {
        const v2f as = (v2f){am[i], am[i]};
        #pragma unroll
        for (int j = 0; j < 4; ++j) acc[i][j] += as * bv[j];
      }
    }
  }

  const float SQ = sqrtf(1.0f + 1e-5f);
  float s[8], sh[8];
  #pragma unroll
  for (int j = 0; j < 8; ++j) {
    const int o = o0 + nq * 8 + j;
    const float sc = gamma ? (gamma[o] / SQ) : 1.0f;
    float bb = beta ? beta[o] : 0.0f;
    if (bias) bb = bb + bias[o] * sc;
    s[j] = sc; sh[j] = bb;
  }
  #pragma unroll
  for (int i = 0; i < 8; ++i) {
    float y[8];
    #pragma unroll
    for (int j = 0; j < 4; ++j) {
      float va = acc[i][j].x * s[2 * j] + sh[2 * j];
      float vb = acc[i][j].y * s[2 * j + 1] + sh[2 * j + 1];
      y[2 * j] = relu ? fmaxf(va, 0.0f) : va;
      y[2 * j + 1] = relu ? fmaxf(vb, 0.0f) : vb;
    }
    const size_t off = (m0 + mq * 8 + i) * O + o0 + nq * 8;
    *(float4*)(Y + off) = make_float4(y[0], y[1], y[2], y[3]);
    *(float4*)(Y + off + 4) = make_float4(y[4], y[5], y[6], y[7]);
  }
}

// ---------------- segmented max over 32 samples ----------------
__global__ __launch_bounds__(256) void segmax_kernel(
    const float* __restrict__ Y, float* __restrict__ F, int O, int obits) {
  const int id = blockIdx.x * 256 + threadIdx.x;
  const int g = id >> obits;
  const int o = id & (O - 1);
  float m = -3.4e38f;
  #pragma unroll 8
  for (int k = 0; k < 32; ++k)
    m = fmaxf(m, Y[((size_t)g * 32 + k) * O + o]);
  F[(size_t)g * O + o] = m;
}

// ---------------- 3-NN search (stable, strict <) ----------------
__global__ __launch_bounds__(256) void nn3_kernel(
    const float* __restrict__ txyz, const float* __restrict__ sxyz,
    int* __restrict__ oi, float* __restrict__ ow, int s1bits, int S2) {
  __shared__ float ss[6144];
  const int t = threadIdx.x;
  const int row = blockIdx.x * 256 + t;
  const int b = row >> s1bits;
  for (int i = t; i < S2 * 3; i += 256) ss[i] = sxyz[(size_t)b * S2 * 3 + i];
  __syncthreads();
  const float ax = txyz[(size_t)row * 3 + 0];
  const float ay = txyz[(size_t)row * 3 + 1];
  const float az = txyz[(size_t)row * 3 + 2];
  const float an = __fadd_rn(__fadd_rn(__fmul_rn(ax, ax), __fmul_rn(ay, ay)),
                             __fmul_rn(az, az));
  float d0 = 3.4e38f, d1 = 3.4e38f, d2v = 3.4e38f;
  int i0 = 0, i1 = 0, i2 = 0;
  for (int j = 0; j < S2; ++j) {
    const float bx = ss[j * 3 + 0], by = ss[j * 3 + 1], bz = ss[j * 3 + 2];
    const float bb = __fadd_rn(__fadd_rn(__fmul_rn(bx, bx), __fmul_rn(by, by)),
                               __fmul_rn(bz, bz));
    const float dot = __fadd_rn(__fadd_rn(__fmul_rn(ax, bx), __fmul_rn(ay, by)),
                                __fmul_rn(az, bz));
    const float dd = __fsub_rn(__fadd_rn(an, bb), __fmul_rn(2.0f, dot));
    if (dd < d0) {
      d2v = d1; i2 = i1; d1 = d0; i1 = i0; d0 = dd; i0 = j;
    } else if (dd < d1) {
      d2v = d1; i2 = i1; d1 = dd; i1 = j;
    } else if (dd < d2v) {
      d2v = dd; i2 = j;
    }
  }
  const float r0 = 1.0f / (d0 + 1e-8f);
  const float r1 = 1.0f / (d1 + 1e-8f);
  const float r2 = 1.0f / (d2v + 1e-8f);
  const float sum = __fadd_rn(__fadd_rn(r0, r1), r2);
  oi[(size_t)row * 3 + 0] = i0;
  oi[(size_t)row * 3 + 1] = i1;
  oi[(size_t)row * 3 + 2] = i2;
  ow[(size_t)row * 3 + 0] = r0 / sum;
  ow[(size_t)row * 3 + 1] = r1 / sum;
  ow[(size_t)row * 3 + 2] = r2 / sum;
}

// ---------------- weighted 3-point interpolation into concat columns -------
__global__ __launch_bounds__(256) void interp_kernel(
    float* __restrict__ dst, int CT, int c0, const float* __restrict__ src,
    const int* __restrict__ idx, const float* __restrict__ w, int csbits,
    int s1bits, int S2) {
  const int id = blockIdx.x * 256 + threadIdx.x;
  const int row = id >> csbits;
  const int c4 = (id & ((1 << csbits) - 1)) * 4;
  const int Cs = 4 << csbits;
  const int b = row >> s1bits;
  const int j0 = idx[(size_t)row * 3 + 0];
  const int j1 = idx[(size_t)row * 3 + 1];
  const int j2 = idx[(size_t)row * 3 + 2];
  const float w0 = w[(size_t)row * 3 + 0];
  const float w1 = w[(size_t)row * 3 + 1];
  const float w2 = w[(size_t)row * 3 + 2];
  const float4 f0 = *(const float4*)(src + ((size_t)b * S2 + j0) * Cs + c4);
  const float4 f1 = *(const float4*)(src + ((size_t)b * S2 + j1) * Cs + c4);
  const float4 f2 = *(const float4*)(src + ((size_t)b * S2 + j2) * Cs + c4);
  float4 v;
  v.x = f0.x * w0 + f1.x * w1 + f2.x * w2;
  v.y = f0.y * w0 + f1.y * w1 + f2.y * w2;
  v.z = f0.z * w0 + f1.z * w1 + f2.z * w2;
  v.w = f0.w * w0 + f1.w * w1 + f2.w * w2;
  *(float4*)(dst + (size_t)row * CT + c0 + c4) = v;
}

// ---------------- copy columns into concat buffer ----------------
__global__ __launch_bounds__(256) void copycols_kernel(
    float* __restrict__ dst, int CT, int c0, const float* __restrict__ src,
    int csbits) {
  const int id = blockIdx.x * 256 + threadIdx.x;
  const int row = id >> csbits;
  const int c4 = (id & ((1 << csbits) - 1)) * 4;
  const int Cs = 4 << csbits;
  const float4 v = *(const float4*)(src + (size_t)row * Cs + c4);
  *(float4*)(dst + (size_t)row * CT + c0 + c4) = v;
}

// ---------------- final 128->8 conv + bias, point-major out ----------------
__global__ __launch_bounds__(256) void outfinal_kernel(
    const float* __restrict__ X, const float* __restrict__ Wt,
    const float* __restrict__ bias, float* __restrict__ out) {
  __shared__ float Xs[32][132];
  const int t = threadIdx.x;
  const int p0 = blockIdx.x * 32;
  #pragma unroll
  for (int q = 0; q < 4; ++q) {
    const int id = t + q * 256;
    const int r = id >> 5, c4 = (id & 31) * 4;
    const float4 v = *(const float4*)(X + (size_t)(p0 + r) * 128 + c4);
    Xs[r][c4 + 0] = v.x; Xs[r][c4 + 1] = v.y;
    Xs[r][c4 + 2] = v.z; Xs[r][c4 + 3] = v.w;
  }
  __syncthreads();
  const int p = t >> 3, o = t & 7;
  float acc = 0.0f;
  #pragma unroll 8
  for (int i = 0; i < 128; ++i) acc += Wt[o * 128 + i] * Xs[p][i];
  out[(size_t)(p0 + p) * 8 + o] = acc + bias[o];
}

// ---------------------------------------------------------------------------
extern "C" void kernel_launch(void* const* d_in, const int* in_sizes, int n_in,
                              void* d_out, int out_size, void* d_ws,
                              size_t ws_size, hipStream_t stream) {
  const float* x       = (const float*)d_in[0];
  const float* w_emb1  = (const float*)d_in[1];
  const float* g_emb1  = (const float*)d_in[2];
  const float* be_emb1 = (const float*)d_in[3];
  const float* w_emb2  = (const float*)d_in[4];
  const float* g_emb2  = (const float*)d_in[5];
  const float* be_emb2 = (const float*)d_in[6];
  const float* l0_w1 = (const float*)d_in[7];
  const float* l0_g1 = (const float*)d_in[8];
  const float* l0_b1 = (const float*)d_in[9];
  const float* l0_w2 = (const float*)d_in[10];
  const float* l0_g2 = (const float*)d_in[11];
  const float* l0_b2 = (const float*)d_in[12];
  const float* l1_w1 = (const float*)d_in[13];
  const float* l1_g1 = (const float*)d_in[14];
  const float* l1_b1 = (const float*)d_in[15];
  const float* l1_w2 = (const float*)d_in[16];
  const float* l1_g2 = (const float*)d_in[17];
  const float* l1_b2 = (const float*)d_in[18];
  const float* f0_w1 = (const float*)d_in[19];
  const float* f0_g1 = (const float*)d_in[20];
  const float* f0_b1 = (const float*)d_in[21];
  const float* f0_w2 = (const float*)d_in[22];
  const float* f0_g2 = (const float*)d_in[23];
  const float* f0_b2 = (const float*)d_in[24];
  const float* f1_w1 = (const float*)d_in[25];
  const float* f1_g1 = (const float*)d_in[26];
  const float* f1_b1 = (const float*)d_in[27];
  const float* f1_w2 = (const float*)d_in[28];
  const float* f1_g2 = (const float*)d_in[29];
  const float* f1_b2 = (const float*)d_in[30];
  const float* c1_w    = (const float*)d_in[31];
  const float* c1_bias = (const float*)d_in[32];
  const float* c1_g    = (const float*)d_in[33];
  const float* c1_beta = (const float*)d_in[34];
  const float* c2_w    = (const float*)d_in[35];
  const float* c2_bias = (const float*)d_in[36];
  const float* c2_g    = (const float*)d_in[37];
  const float* c2_beta = (const float*)d_in[38];
  const float* out_w    = (const float*)d_in[39];
  const float* out_bias = (const float*)d_in[40];

  if (ws_size < WS_NEED) return;  // cannot run without scratch

  char* ws = (char*)d_ws;
  float* feats0 = (float*)(ws + O_FEATS0);
  float* feats1 = (float*)(ws + O_FEATS1);
  float* feats2 = (float*)(ws + O_FEATS2);
  float* fp0out = (float*)(ws + O_FP0OUT);
  float* xyz1   = (float*)(ws + O_XYZ1);
  float* xyz2   = (float*)(ws + O_XYZ2);
  int*   fps1   = (int*)(ws + O_FPS1);
  int*   fps2   = (int*)(ws + O_FPS2);
  int*   ball1  = (int*)(ws + O_BALL1);
  int*   ball2  = (int*)(ws + O_BALL2);
  int*   nn0i   = (int*)(ws + O_NN0I);
  float* nn0w   = (float*)(ws + O_NN0W);
  int*   nn1i   = (int*)(ws + O_NN1I);
  float* nn1w   = (float*)(ws + O_NN1W);
  float* REG0   = (float*)(ws + O_REG0);
  float* REG1   = (float*)(ws + O_REG1);
  float* outp   = (float*)d_out;
  hipStream_t s = stream;

  // ---- embedding MLP: (B*8192, 64) ----
  emb_kernel<<<8192, 256, 0, s>>>(x, w_emb1, g_emb1, be_emb1, w_emb2, g_emb2,
                                  be_emb2, feats0);

  // ---- SA layer 1 ----
  fps_kernel<8192, 2048><<<4, 256, 0, s>>>(x, fps1, xyz1);
  ball_kernel<<<2048, 256, 0, s>>>(x, xyz1, ball1, 11, 8192);
  for (int c = 0; c < 2; ++c) {
    groupmat_kernel<<<16384, 256, 0, s>>>(REG0, feats0, ball1, fps1, c * 4096,
                                          64, 5, 11, 8192);
    conv_kernel<<<dim3(1024, 1), 256, 0, s>>>(REG0, l0_w1, REG1, 128, 128,
                                              l0_g1, l0_b1, nullptr, 1);
    conv_kernel<<<dim3(1024, 1), 256, 0, s>>>(REG1, l0_w2, REG0, 128, 128,
                                              l0_g2, l0_b2, nullptr, 1);
    segmax_kernel<<<2048, 256, 0, s>>>(REG0, feats1 + (size_t)c * 4096 * 128,
                                       128, 7);
  }

  // ---- SA layer 2 ----
  fps_kernel<2048, 1024><<<4, 256, 0, s>>>(xyz1, fps2, xyz2);
  ball_kernel<<<1024, 256, 0, s>>>(xyz1, xyz2, ball2, 10, 2048);
  for (int c = 0; c < 2; ++c) {
    groupmat_kernel<<<16384, 256, 0, s>>>(REG0, feats1, ball2, fps2, c * 2048,
                                          128, 6, 10, 2048);
    conv_kernel<<<dim3(512, 2), 256, 0, s>>>(REG0, l1_w1, REG1, 256, 256,
                                             l1_g1, l1_b1, nullptr, 1);
    conv_kernel<<<dim3(512, 2), 256, 0, s>>>(REG1, l1_w2, REG0, 256, 256,
                                             l1_g2, l1_b2, nullptr, 1);
    segmax_kernel<<<2048, 256, 0, s>>>(REG0, feats2 + (size_t)c * 2048 * 256,
                                       256, 8);
  }

  // ---- feature propagation 0: 1024 -> 2048 points ----
  nn3_kernel<<<32, 256, 0, s>>>(xyz1, xyz2, nn0i, nn0w, 11, 1024);
  copycols_kernel<<<1024, 256, 0, s>>>(REG0, 384, 0, feats1, 5);
  interp_kernel<<<2048, 256, 0, s>>>(REG0, 384, 128, feats2, nn0i, nn0w, 6, 11,
                                     1024);
  conv_kernel<<<dim3(64, 2), 256, 0, s>>>(REG0, f0_w1, REG1, 384, 256, f0_g1,
                                          f0_b1, nullptr, 1);
  conv_kernel<<<dim3(64, 4), 256, 0, s>>>(REG1, f0_w2, fp0out, 256, 512, f0_g2,
                                          f0_b2, nullptr, 1);

  // ---- feature propagation 1 + head, chunked per 2 batches ----
  nn3_kernel<<<128, 256, 0, s>>>(x, xyz1, nn1i, nn1w, 13, 2048);
  for (int b = 0; b < 4; b += 2) {
    copycols_kernel<<<1024, 256, 0, s>>>(REG0, 576, 0,
                                         feats0 + (size_t)b * 8192 * 64, 4);
    interp_kernel<<<8192, 256, 0, s>>>(REG0, 576, 64,
                                       fp0out + (size_t)b * 2048 * 512,
                                       nn1i + (size_t)b * 8192 * 3,
                                       nn1w + (size_t)b * 8192 * 3, 7, 13,
                                       2048);
    conv_kernel<<<dim3(128, 4), 256, 0, s>>>(REG0, f1_w1, REG1, 576, 512,
                                             f1_g1, f1_b1, nullptr, 1);
    conv_kernel<<<dim3(128, 8), 256, 0, s>>>(REG1, f1_w2, REG0, 512, 1024,
                                             f1_g2, f1_b2, nullptr, 1);
    conv_kernel<<<dim3(128, 4), 256, 0, s>>>(REG0, c1_w, REG1, 1024, 512,
                                             c1_g, c1_beta, c1_bias, 1);
    conv_kernel<<<dim3(128, 1), 256, 0, s>>>(REG1, c2_w, REG0, 512, 128,
                                             c2_g, c2_beta, c2_bias, 1);
    outfinal_kernel<<<512, 256, 0, s>>>(REG0, out_w, out_bias,
                                        outp + (size_t)b * 8192 * 8);
  }
}

// Round 9
// 4906.802 us; speedup vs baseline: 1.4692x; 1.0179x over previous
//
#include <hip/hip_runtime.h>
#include <math.h>

// ---------------------------------------------------------------------------
// PointNet++ part-seg forward. All features stored point-major: row = point,
// C contiguous floats per row. B=4, N=8192 fixed by the problem.
// ---------------------------------------------------------------------------

// ---------------- workspace layout (bytes) ----------------
static constexpr size_t O_FEATS0 = 0;                    // (4*8192, 64)  f32
static constexpr size_t O_FEATS1 = 8388608;              // (4*2048, 128)
static constexpr size_t O_FEATS2 = 12582912;             // (4*1024, 256)
static constexpr size_t O_FP0OUT = 16777216;             // (4*2048, 512)
static constexpr size_t O_XYZ1   = 33554432;             // (4*2048, 3)
static constexpr size_t O_XYZ2   = 33652736;             // (4*1024, 3)
static constexpr size_t O_FPS1   = 33701888;             // (4*2048) int
static constexpr size_t O_FPS2   = 33734656;             // (4*1024) int
static constexpr size_t O_BALL1  = 33751040;             // (4*2048*32) int
static constexpr size_t O_BALL2  = 34799616;             // (4*1024*32) int
static constexpr size_t O_NN0I   = 35323904;             // (4*2048*3) int
static constexpr size_t O_NN0W   = 35422208;             // (4*2048*3) f32
static constexpr size_t O_NN1I   = 35520512;             // (4*8192*3) int
static constexpr size_t O_NN1W   = 35913728;             // (4*8192*3) f32
static constexpr size_t O_REG0   = 36306944;             // 67108864 scratch
static constexpr size_t O_REG1   = 103415808;            // 67108864 scratch
static constexpr size_t WS_NEED  = 170524672;

typedef float v2f __attribute__((ext_vector_type(2)));

// ---------------- DPP helpers for wave-64 u64 max reduce -------------------
__device__ __forceinline__ unsigned long long u64max(unsigned long long a,
                                                     unsigned long long b) {
  return a > b ? a : b;
}
template <int CTRL>
__device__ __forceinline__ unsigned long long dpp_step(unsigned long long k) {
  const int lo = (int)(unsigned)k;
  const int hi = (int)(unsigned)(k >> 32);
  const int nlo = __builtin_amdgcn_update_dpp(lo, lo, CTRL, 0xf, 0xf, false);
  const int nhi = __builtin_amdgcn_update_dpp(hi, hi, CTRL, 0xf, 0xf, false);
  return ((unsigned long long)(unsigned)nhi << 32) | (unsigned)nlo;
}

// ---------------- farthest point sampling (+ optional fused emb) ----------
// Blocks 0..3: fps for 4 batches (serial chain-bound, ~2% of chip).
// If EMB: blocks 4.. run the embedding MLP concurrently (independent of fps;
// its ~100us hides fully under fps1's ~1.8ms).
template <int N, int NP, bool EMB>
__global__ __launch_bounds__(256, 1) void fps_kernel(
    const float* __restrict__ xyz, int* __restrict__ out,
    float* __restrict__ oxyz, const float* __restrict__ w1,
    const float* __restrict__ g1, const float* __restrict__ b1,
    const float* __restrict__ w2, const float* __restrict__ g2,
    const float* __restrict__ b2, float* __restrict__ femb) {
  #pragma clang fp contract(off)
  constexpr int PPT = N / 256;
  constexpr int PAIRS = PPT / 2;
  __shared__ float sx[N], sy[N], sz[N];
  __shared__ int sfar[NP];
  __shared__ unsigned long long skey[2][4];

  if constexpr (EMB) {
    if (blockIdx.x >= 4) {
      #pragma clang fp contract(fast)
      const int bid = blockIdx.x - 4;
      const int t = threadIdx.x;
      const int o = t & 63, pl = t >> 6;
      const int pt = bid * 4 + pl;
      const float x0 = xyz[(size_t)pt * 3 + 0];
      const float x1 = xyz[(size_t)pt * 3 + 1];
      const float x2 = xyz[(size_t)pt * 3 + 2];
      const float SQ = sqrtf(1.0f + 1e-5f);
      float v = w1[o * 3 + 0] * x0 + w1[o * 3 + 1] * x1 + w1[o * 3 + 2] * x2;
      v = fmaxf(v * (g1[o] / SQ) + b1[o], 0.0f);
      float* h = sx;  // reuse LDS
      h[pl * 64 + o] = v;
      __syncthreads();
      float acc = 0.0f;
      #pragma unroll 8
      for (int i = 0; i < 64; ++i) acc += w2[o * 64 + i] * h[pl * 64 + i];
      float y = fmaxf(acc * (g2[o] / SQ) + b2[o], 0.0f);
      femb[(size_t)pt * 64 + o] = y;
      return;
    }
  }

  const int b = blockIdx.x, t = threadIdx.x;
  const float* xb = xyz + (size_t)b * N * 3;
  for (int i = t; i < N; i += 256) {
    sx[i] = xb[i * 3 + 0];
    sy[i] = xb[i * 3 + 1];
    sz[i] = xb[i * 3 + 2];
  }
  __syncthreads();
  v2f px[PAIRS], py[PAIRS], pz[PAIRS], ds[PAIRS];
  #pragma unroll
  for (int k = 0; k < PAIRS; ++k) {
    const int g = t * PPT + 2 * k;
    px[k].x = sx[g]; px[k].y = sx[g + 1];
    py[k].x = sy[g]; py[k].y = sy[g + 1];
    pz[k].x = sz[g]; pz[k].y = sz[g + 1];
    ds[k].x = 1e10f; ds[k].y = 1e10f;
  }
  const int wid = t >> 6, lane = t & 63;
  int far = 0;
  float ccx = sx[0], ccy = sy[0], ccz = sz[0];
  for (int it = 0; it < NP; ++it) {
    if (t == 0) sfar[it] = far;
    v2f cx2, cy2, cz2;
    cx2.x = ccx; cx2.y = ccx;
    cy2.x = ccy; cy2.y = ccy;
    cz2.x = ccz; cz2.y = ccz;
    #pragma unroll
    for (int k = 0; k < PAIRS; ++k) {
      const v2f dx = px[k] - cx2;
      const v2f dy = py[k] - cy2;
      const v2f dz = pz[k] - cz2;
      const v2f d = dx * dx + dy * dy + dz * dz;
      v2f nd;
      nd.x = fminf(ds[k].x, d.x);
      nd.y = fminf(ds[k].y, d.y);
      ds[k] = nd;
    }
    v2f tv[PAIRS / 2];
    #pragma unroll
    for (int k = 0; k < PAIRS / 2; ++k) {
      tv[k].x = fmaxf(ds[k].x, ds[k + PAIRS / 2].x);
      tv[k].y = fmaxf(ds[k].y, ds[k + PAIRS / 2].y);
    }
    #pragma unroll
    for (int w = PAIRS / 4; w >= 1; w >>= 1) {
      #pragma unroll
      for (int k = 0; k < w; ++k) {
        tv[k].x = fmaxf(tv[k].x, tv[k + w].x);
        tv[k].y = fmaxf(tv[k].y, tv[k + w].y);
      }
    }
    const float bv = fmaxf(tv[0].x, tv[0].y);
    unsigned mask = 0u;
    #pragma unroll
    for (int k = 0; k < PAIRS; ++k) {
      mask |= (ds[k].x == bv) ? (1u << (2 * k)) : 0u;
      mask |= (ds[k].y == bv) ? (1u << (2 * k + 1)) : 0u;
    }
    const int bjl = __builtin_ctz(mask);
    unsigned long long bk =
        ((unsigned long long)__float_as_uint(bv) << 32) |
        (unsigned long long)(unsigned)(~(unsigned)(t * PPT + bjl));
    bk = u64max(bk, dpp_step<0x111>(bk));  // row_shr:1
    bk = u64max(bk, dpp_step<0x112>(bk));  // row_shr:2
    bk = u64max(bk, dpp_step<0x114>(bk));  // row_shr:4
    bk = u64max(bk, dpp_step<0x118>(bk));  // row_shr:8
    bk = u64max(bk, dpp_step<0x142>(bk));  // row_bcast:15
    bk = u64max(bk, dpp_step<0x143>(bk));  // row_bcast:31
    const int p = it & 1;
    if (lane == 63) skey[p][wid] = bk;
    __syncthreads();
    unsigned long long wk = skey[p][0];
    #pragma unroll
    for (int q = 1; q < 4; ++q) {
      const unsigned long long k2 = skey[p][q];
      wk = (k2 > wk) ? k2 : wk;
    }
    far = (int)(~(unsigned)wk);
    ccx = sx[far]; ccy = sy[far]; ccz = sz[far];
  }
  __syncthreads();
  for (int i = t; i < NP; i += 256) {
    const int n = sfar[i];
    out[(size_t)b * NP + i] = n;
    oxyz[((size_t)b * NP + i) * 3 + 0] = sx[n];
    oxyz[((size_t)b * NP + i) * 3 + 1] = sy[n];
    oxyz[((size_t)b * NP + i) * 3 + 2] = sz[n];
  }
}

// ---------------- fused ball query + 3-NN search ---------------------------
// Blocks [0, nBallBlk): ball query. Blocks [nBallBlk, ...): 3-NN. Both only
// depend on the fps outputs, so they share one launch (max, not sum, of
// durations).
__global__ __launch_bounds__(256) void ballnn_kernel(
    const float* __restrict__ cloud, const float* __restrict__ ctr,
    int* __restrict__ ballOut, int sbits, int N, int nBallBlk,
    const float* __restrict__ txyz, const float* __restrict__ sxyz,
    int* __restrict__ oi, float* __restrict__ ow, int s1bits, int S2) {
  __shared__ int lists[4][32];
  __shared__ float ss[6144];
  const int t = threadIdx.x;
  if ((int)blockIdx.x < nBallBlk) {
    const int lane = t & 63, wid = t >> 6;
    const int wg = blockIdx.x * 4 + wid;
    const int b = wg >> sbits;
    const float cx = ctr[(size_t)wg * 3 + 0];
    const float cy = ctr[(size_t)wg * 3 + 1];
    const float cz = ctr[(size_t)wg * 3 + 2];
    const float an = __fadd_rn(__fadd_rn(__fmul_rn(cx, cx), __fmul_rn(cy, cy)),
                               __fmul_rn(cz, cz));
    int fill = 0;
    for (int ch = 0; ch < (N >> 6) && fill < 32; ++ch) {
      const int n = ch * 64 + lane;
      const float bx = cloud[((size_t)b * N + n) * 3 + 0];
      const float by = cloud[((size_t)b * N + n) * 3 + 1];
      const float bz = cloud[((size_t)b * N + n) * 3 + 2];
      const float bb = __fadd_rn(
          __fadd_rn(__fmul_rn(bx, bx), __fmul_rn(by, by)), __fmul_rn(bz, bz));
      const float dot = __fadd_rn(
          __fadd_rn(__fmul_rn(cx, bx), __fmul_rn(cy, by)), __fmul_rn(cz, bz));
      const float d2 = __fsub_rn(__fadd_rn(an, bb), __fmul_rn(2.0f, dot));
      const bool q = (d2 <= 1.0f);
      const unsigned long long mask = __ballot(q);
      if (q) {
        const int pos = fill + __popcll(mask & ((1ull << lane) - 1ull));
        if (pos < 32) lists[wid][pos] = n;
      }
      fill += (int)__popcll(mask);
    }
    __syncthreads();
    if (lane < 32) {
      int v = lists[wid][0];
      if (lane < fill) v = lists[wid][lane];
      ballOut[(size_t)wg * 32 + lane] = v;
    }
    return;
  }
  // ---- 3-NN path ----
  const int row = (blockIdx.x - nBallBlk) * 256 + t;
  const int b = row >> s1bits;
  for (int i = t; i < S2 * 3; i += 256) ss[i] = sxyz[(size_t)b * S2 * 3 + i];
  __syncthreads();
  const float ax = txyz[(size_t)row * 3 + 0];
  const float ay = txyz[(size_t)row * 3 + 1];
  const float az = txyz[(size_t)row * 3 + 2];
  const float an = __fadd_rn(__fadd_rn(__fmul_rn(ax, ax), __fmul_rn(ay, ay)),
                             __fmul_rn(az, az));
  float d0 = 3.4e38f, d1 = 3.4e38f, d2v = 3.4e38f;
  int i0 = 0, i1 = 0, i2 = 0;
  for (int j = 0; j < S2; ++j) {
    const float bx = ss[j * 3 + 0], by = ss[j * 3 + 1], bz = ss[j * 3 + 2];
    const float bb = __fadd_rn(__fadd_rn(__fmul_rn(bx, bx), __fmul_rn(by, by)),
                               __fmul_rn(bz, bz));
    const float dot = __fadd_rn(__fadd_rn(__fmul_rn(ax, bx), __fmul_rn(ay, by)),
                                __fmul_rn(az, bz));
    const float dd = __fsub_rn(__fadd_rn(an, bb), __fmul_rn(2.0f, dot));
    if (dd < d0) {
      d2v = d1; i2 = i1; d1 = d0; i1 = i0; d0 = dd; i0 = j;
    } else if (dd < d1) {
      d2v = d1; i2 = i1; d1 = dd; i1 = j;
    } else if (dd < d2v) {
      d2v = dd; i2 = j;
    }
  }
  const float r0 = 1.0f / (d0 + 1e-8f);
  const float r1 = 1.0f / (d1 + 1e-8f);
  const float r2 = 1.0f / (d2v + 1e-8f);
  const float sum = __fadd_rn(__fadd_rn(r0, r1), r2);
  oi[(size_t)row * 3 + 0] = i0;
  oi[(size_t)row * 3 + 1] = i1;
  oi[(size_t)row * 3 + 2] = i2;
  ow[(size_t)row * 3 + 0] = r0 / sum;
  ow[(size_t)row * 3 + 1] = r1 / sum;
  ow[(size_t)row * 3 + 2] = r2 / sum;
}

#define CMAP(c) ((((c) >> 3) * 12) + ((c) & 7))

// ---------------- SA conv1: gather (groupmat) fused into the X-tile load ---
// X row m (chunk-local) = group gl=g0+m/32, sample k=m&31:
//   X[m][col] = col<Cf ? f[src][col]-f[ctr][col] : f[ctr][col-Cf]
// Indices precomputed once per row before the K loop. BN+ReLU epilogue.
__global__ __launch_bounds__(256) void conv_gather_kernel(
    const float* __restrict__ f, const int* __restrict__ ball,
    const int* __restrict__ fps, int g0, int Cf, int sbits, int Npts,
    const float* __restrict__ W, float* __restrict__ Y, int O,
    const float* __restrict__ gamma, const float* __restrict__ beta) {
  const int C = Cf * 2;
  __shared__ float Xs[16][188];
  __shared__ float Ws[16][188];
  const int t = threadIdx.x;
  const size_t m0 = (size_t)blockIdx.x * 128;
  const int o0 = blockIdx.y * 128;
  const int r0 = t >> 2;
  const int cq0 = (t & 3) * 4;
  const int mq = t & 15, nq = t >> 4;
  const int ca = CMAP(r0), cb = CMAP(r0 + 64);
  const int mA = (int)m0 + r0, mB = (int)m0 + r0 + 64;
  const int glA = g0 + (mA >> 5), glB = g0 + (mB >> 5);
  const int srcA = ball[(size_t)glA * 32 + (mA & 31)];
  const int srcB = ball[(size_t)glB * 32 + (mB & 31)];
  const int ctrA = fps[glA], ctrB = fps[glB];
  const float* fbA = f + (size_t)(glA >> sbits) * Npts * Cf;
  const float* fbB = f + (size_t)(glB >> sbits) * Npts * Cf;
  v2f acc[8][4];
  #pragma unroll
  for (int i = 0; i < 8; ++i)
    #pragma unroll
    for (int j = 0; j < 4; ++j) acc[i][j] = (v2f){0.0f, 0.0f};

  for (int kk = 0; kk < C; kk += 16) {
    const int col = kk + cq0;
    const bool lo = col < Cf;
    const int col2 = lo ? col : col - Cf;
    float4 xa, xb;
    {
      const float4 c4 = *(const float4*)(fbA + (size_t)ctrA * Cf + col2);
      if (lo) {
        const float4 s4 = *(const float4*)(fbA + (size_t)srcA * Cf + col);
        xa = make_float4(s4.x - c4.x, s4.y - c4.y, s4.z - c4.z, s4.w - c4.w);
      } else {
        xa = c4;
      }
    }
    {
      const float4 c4 = *(const float4*)(fbB + (size_t)ctrB * Cf + col2);
      if (lo) {
        const float4 s4 = *(const float4*)(fbB + (size_t)srcB * Cf + col);
        xb = make_float4(s4.x - c4.x, s4.y - c4.y, s4.z - c4.z, s4.w - c4.w);
      } else {
        xb = c4;
      }
    }
    const float4 wa = *(const float4*)(W + (size_t)(o0 + r0) * C + kk + cq0);
    const float4 wb =
        *(const float4*)(W + (size_t)(o0 + r0 + 64) * C + kk + cq0);
    __syncthreads();
    Xs[cq0 + 0][ca] = xa.x; Xs[cq0 + 1][ca] = xa.y;
    Xs[cq0 + 2][ca] = xa.z; Xs[cq0 + 3][ca] = xa.w;
    Xs[cq0 + 0][cb] = xb.x; Xs[cq0 + 1][cb] = xb.y;
    Xs[cq0 + 2][cb] = xb.z; Xs[cq0 + 3][cb] = xb.w;
    Ws[cq0 + 0][ca] = wa.x; Ws[cq0 + 1][ca] = wa.y;
    Ws[cq0 + 2][ca] = wa.z; Ws[cq0 + 3][ca] = wa.w;
    Ws[cq0 + 0][cb] = wb.x; Ws[cq0 + 1][cb] = wb.y;
    Ws[cq0 + 2][cb] = wb.z; Ws[cq0 + 3][cb] = wb.w;
    __syncthreads();
    #pragma unroll
    for (int k = 0; k < 16; ++k) {
      const float4 a0 = *(const float4*)&Xs[k][mq * 12];
      const float4 a1 = *(const float4*)&Xs[k][mq * 12 + 4];
      const float4 b0 = *(const float4*)&Ws[k][nq * 12];
      const float4 b1 = *(const float4*)&Ws[k][nq * 12 + 4];
      const float am[8] = {a0.x, a0.y, a0.z, a0.w, a1.x, a1.y, a1.z, a1.w};
      v2f bv[4];
      bv[0] = (v2f){b0.x, b0.y};
      bv[1] = (v2f){b0.z, b0.w};
      bv[2] = (v2f){b1.x, b1.y};
      bv[3] = (v2f){b1.z, b1.w};
      #pragma unroll
      for (int i = 0; i < 8; ++i) {
        const v2f as = (v2f){am[i], am[i]};
        #pragma unroll
        for (int j = 0; j < 4; ++j) acc[i][j] += as * bv[j];
      }
    }
  }

  const float SQ = sqrtf(1.0f + 1e-5f);
  float s[8], sh[8];
  #pragma unroll
  for (int j = 0; j < 8; ++j) {
    const int o = o0 + nq * 8 + j;
    s[j] = gamma[o] / SQ;
    sh[j] = beta[o];
  }
  #pragma unroll
  for (int i = 0; i < 8; ++i) {
    float y[8];
    #pragma unroll
    for (int j = 0; j < 4; ++j) {
      y[2 * j] = fmaxf(acc[i][j].x * s[2 * j] + sh[2 * j], 0.0f);
      y[2 * j + 1] = fmaxf(acc[i][j].y * s[2 * j + 1] + sh[2 * j + 1], 0.0f);
    }
    const size_t off = (m0 + mq * 8 + i) * O + o0 + nq * 8;
    *(float4*)(Y + off) = make_float4(y[0], y[1], y[2], y[3]);
    *(float4*)(Y + off + 4) = make_float4(y[4], y[5], y[6], y[7]);
  }
}

// ---------------- SA conv2 with fused segmented max epilogue ---------------
// A group's 32 rows are fully inside one 128-row tile: per-thread col-max
// over its 8 rows -> LDS (stride 132, conflict-free) -> 4-way max -> feats.
__global__ __launch_bounds__(256) void conv2sm_kernel(
    const float* __restrict__ X, const float* __restrict__ W,
    float* __restrict__ F, int C, int O, const float* __restrict__ gamma,
    const float* __restrict__ beta) {
  __shared__ float Xs[16][188];
  __shared__ float Ws[16][188];
  const int t = threadIdx.x;
  const size_t m0 = (size_t)blockIdx.x * 128;
  const int o0 = blockIdx.y * 128;
  const int r0 = t >> 2;
  const int cq0 = (t & 3) * 4;
  const int mq = t & 15, nq = t >> 4;
  const int ca = CMAP(r0), cb = CMAP(r0 + 64);
  v2f acc[8][4];
  #pragma unroll
  for (int i = 0; i < 8; ++i)
    #pragma unroll
    for (int j = 0; j < 4; ++j) acc[i][j] = (v2f){0.0f, 0.0f};

  for (int kk = 0; kk < C; kk += 16) {
    const float4 xa = *(const float4*)(X + (m0 + r0) * C + kk + cq0);
    const float4 xb = *(const float4*)(X + (m0 + r0 + 64) * C + kk + cq0);
    const float4 wa = *(const float4*)(W + (size_t)(o0 + r0) * C + kk + cq0);
    const float4 wb =
        *(const float4*)(W + (size_t)(o0 + r0 + 64) * C + kk + cq0);
    __syncthreads();
    Xs[cq0 + 0][ca] = xa.x; Xs[cq0 + 1][ca] = xa.y;
    Xs[cq0 + 2][ca] = xa.z; Xs[cq0 + 3][ca] = xa.w;
    Xs[cq0 + 0][cb] = xb.x; Xs[cq0 + 1][cb] = xb.y;
    Xs[cq0 + 2][cb] = xb.z; Xs[cq0 + 3][cb] = xb.w;
    Ws[cq0 + 0][ca] = wa.x; Ws[cq0 + 1][ca] = wa.y;
    Ws[cq0 + 2][ca] = wa.z; Ws[cq0 + 3][ca] = wa.w;
    Ws[cq0 + 0][cb] = wb.x; Ws[cq0 + 1][cb] = wb.y;
    Ws[cq0 + 2][cb] = wb.z; Ws[cq0 + 3][cb] = wb.w;
    __syncthreads();
    #pragma unroll
    for (int k = 0; k < 16; ++k) {
      const float4 a0 = *(const float4*)&Xs[k][mq * 12];
      const float4 a1 = *(const float4*)&Xs[k][mq * 12 + 4];
      const float4 b0 = *(const float4*)&Ws[k][nq * 12];
      const float4 b1 = *(const float4*)&Ws[k][nq * 12 + 4];
      const float am[8] = {a0.x, a0.y, a0.z, a0.w, a1.x, a1.y, a1.z, a1.w};
      v2f bv[4];
      bv[0] = (v2f){b0.x, b0.y};
      bv[1] = (v2f){b0.z, b0.w};
      bv[2] = (v2f){b1.x, b1.y};
      bv[3] = (v2f){b1.z, b1.w};
      #pragma unroll
      for (int i = 0; i < 8; ++i) {
        const v2f as = (v2f){am[i], am[i]};
        #pragma unroll
        for (int j = 0; j < 4; ++j) acc[i][j] += as * bv[j];
      }
    }
  }

  const float SQ = sqrtf(1.0f + 1e-5f);
  float s[8], sh[8];
  #pragma unroll
  for (int j = 0; j < 8; ++j) {
    const int o = o0 + nq * 8 + j;
    s[j] = gamma[o] / SQ;
    sh[j] = beta[o];
  }
  float colmax[8];
  #pragma unroll
  for (int j = 0; j < 8; ++j) colmax[j] = -3.4e38f;
  #pragma unroll
  for (int i = 0; i < 8; ++i) {
    #pragma unroll
    for (int j = 0; j < 4; ++j) {
      const float va = fmaxf(acc[i][j].x * s[2 * j] + sh[2 * j], 0.0f);
      const float vb = fmaxf(acc[i][j].y * s[2 * j + 1] + sh[2 * j + 1], 0.0f);
      colmax[2 * j] = fmaxf(colmax[2 * j], va);
      colmax[2 * j + 1] = fmaxf(colmax[2 * j + 1], vb);
    }
  }
  __syncthreads();
  float* smax = &Xs[0][0];  // 16*188 floats >= 16*132
  #pragma unroll
  for (int j = 0; j < 8; ++j) smax[mq * 132 + nq * 8 + j] = colmax[j];
  __syncthreads();
  #pragma unroll
  for (int q = 0; q < 2; ++q) {
    const int idx = t + q * 256;
    const int g = idx >> 7;           // group within tile (0..3)
    const int col = idx & 127;        // column within o-range
    const float m =
        fmaxf(fmaxf(smax[(4 * g + 0) * 132 + col], smax[(4 * g + 1) * 132 + col]),
              fmaxf(smax[(4 * g + 2) * 132 + col], smax[(4 * g + 3) * 132 + col]));
    F[(size_t)(blockIdx.x * 4 + g) * O + o0 + col] = m;
  }
}

// ---------------- generic 1x1 conv (GEMM) with BN/bias/ReLU epilogue -------
__global__ __launch_bounds__(256) void conv_kernel(
    const float* __restrict__ X, const float* __restrict__ W,
    float* __restrict__ Y, int C, int O, const float* __restrict__ gamma,
    const float* __restrict__ beta, const float* __restrict__ bias, int relu) {
  __shared__ float Xs[16][188];
  __shared__ float Ws[16][188];
  const int t = threadIdx.x;
  const size_t m0 = (size_t)blockIdx.x * 128;
  const int o0 = blockIdx.y * 128;
  const int r0 = t >> 2;
  const int cq0 = (t & 3) * 4;
  const int mq = t & 15, nq = t >> 4;
  const int ca = CMAP(r0), cb = CMAP(r0 + 64);
  v2f acc[8][4];
  #pragma unroll
  for (int i = 0; i < 8; ++i)
    #pragma unroll
    for (int j = 0; j < 4; ++j) acc[i][j] = (v2f){0.0f, 0.0f};

  for (int kk = 0; kk < C; kk += 16) {
    const float4 xa = *(const float4*)(X + (m0 + r0) * C + kk + cq0);
    const float4 xb = *(const float4*)(X + (m0 + r0 + 64) * C + kk + cq0);
    const float4 wa = *(const float4*)(W + (size_t)(o0 + r0) * C + kk + cq0);
    const float4 wb =
        *(const float4*)(W + (size_t)(o0 + r0 + 64) * C + kk + cq0);
    __syncthreads();
    Xs[cq0 + 0][ca] = xa.x; Xs[cq0 + 1][ca] = xa.y;
    Xs[cq0 + 2][ca] = xa.z; Xs[cq0 + 3][ca] = xa.w;
    Xs[cq0 + 0][cb] = xb.x; Xs[cq0 + 1][cb] = xb.y;
    Xs[cq0 + 2][cb] = xb.z; Xs[cq0 + 3][cb] = xb.w;
    Ws[cq0 + 0][ca] = wa.x; Ws[cq0 + 1][ca] = wa.y;
    Ws[cq0 + 2][ca] = wa.z; Ws[cq0 + 3][ca] = wa.w;
    Ws[cq0 + 0][cb] = wb.x; Ws[cq0 + 1][cb] = wb.y;
    Ws[cq0 + 2][cb] = wb.z; Ws[cq0 + 3][cb] = wb.w;
    __syncthreads();
    #pragma unroll
    for (int k = 0; k < 16; ++k) {
      const float4 a0 = *(const float4*)&Xs[k][mq * 12];
      const float4 a1 = *(const float4*)&Xs[k][mq * 12 + 4];
      const float4 b0 = *(const float4*)&Ws[k][nq * 12];
      const float4 b1 = *(const float4*)&Ws[k][nq * 12 + 4];
      const float am[8] = {a0.x, a0.y, a0.z, a0.w, a1.x, a1.y, a1.z, a1.w};
      v2f bv[4];
      bv[0] = (v2f){b0.x, b0.y};
      bv[1] = (v2f){b0.z, b0.w};
      bv[2] = (v2f){b1.x, b1.y};
      bv[3] = (v2f){b1.z, b1.w};
      #pragma unroll
      for (int i = 0; i < 8; ++i) {
        const v2f as = (v2f){am[i], am[i]};
        #pragma unroll
        for (int j = 0; j < 4; ++j) acc[i][j] += as * bv[j];
      }
    }
  }

  const float SQ = sqrtf(1.0f + 1e-5f);
  float s[8], sh[8];
  #pragma unroll
  for (int j = 0; j < 8; ++j) {
    const int o = o0 + nq * 8 + j;
    const float sc = gamma ? (gamma[o] / SQ) : 1.0f;
    float bb = beta ? beta[o] : 0.0f;
    if (bias) bb = bb + bias[o] * sc;
    s[j] = sc; sh[j] = bb;
  }
  #pragma unroll
  for (int i = 0; i < 8; ++i) {
    float y[8];
    #pragma unroll
    for (int j = 0; j < 4; ++j) {
      float va = acc[i][j].x * s[2 * j] + sh[2 * j];
      float vb = acc[i][j].y * s[2 * j + 1] + sh[2 * j + 1];
      y[2 * j] = relu ? fmaxf(va, 0.0f) : va;
      y[2 * j + 1] = relu ? fmaxf(vb, 0.0f) : vb;
    }
    const size_t off = (m0 + mq * 8 + i) * O + o0 + nq * 8;
    *(float4*)(Y + off) = make_float4(y[0], y[1], y[2], y[3]);
    *(float4*)(Y + off + 4) = make_float4(y[4], y[5], y[6], y[7]);
  }
}

// ---------------- weighted 3-point interpolation into concat columns -------
__global__ __launch_bounds__(256) void interp_kernel(
    float* __restrict__ dst, int CT, int c0, const float* __restrict__ src,
    const int* __restrict__ idx, const float* __restrict__ w, int csbits,
    int s1bits, int S2) {
  const int id = blockIdx.x * 256 + threadIdx.x;
  const int row = id >> csbits;
  const int c4 = (id & ((1 << csbits) - 1)) * 4;
  const int Cs = 4 << csbits;
  const int b = row >> s1bits;
  const int j0 = idx[(size_t)row * 3 + 0];
  const int j1 = idx[(size_t)row * 3 + 1];
  const int j2 = idx[(size_t)row * 3 + 2];
  const float w0 = w[(size_t)row * 3 + 0];
  const float w1 = w[(size_t)row * 3 + 1];
  const float w2 = w[(size_t)row * 3 + 2];
  const float4 f0 = *(const float4*)(src + ((size_t)b * S2 + j0) * Cs + c4);
  const float4 f1 = *(const float4*)(src + ((size_t)b * S2 + j1) * Cs + c4);
  const float4 f2 = *(const float4*)(src + ((size_t)b * S2 + j2) * Cs + c4);
  float4 v;
  v.x = f0.x * w0 + f1.x * w1 + f2.x * w2;
  v.y = f0.y * w0 + f1.y * w1 + f2.y * w2;
  v.z = f0.z * w0 + f1.z * w1 + f2.z * w2;
  v.w = f0.w * w0 + f1.w * w1 + f2.w * w2;
  *(float4*)(dst + (size_t)row * CT + c0 + c4) = v;
}

// ---------------- copy columns into concat buffer ----------------
__global__ __launch_bounds__(256) void copycols_kernel(
    float* __restrict__ dst, int CT, int c0, const float* __restrict__ src,
    int csbits) {
  const int id = blockIdx.x * 256 + threadIdx.x;
  const int row = id >> csbits;
  const int c4 = (id & ((1 << csbits) - 1)) * 4;
  const int Cs = 4 << csbits;
  const float4 v = *(const float4*)(src + (size_t)row * Cs + c4);
  *(float4*)(dst + (size_t)row * CT + c0 + c4) = v;
}

// ---------------- final 128->8 conv + bias, point-major out ----------------
__global__ __launch_bounds__(256) void outfinal_kernel(
    const float* __restrict__ X, const float* __restrict__ Wt,
    const float* __restrict__ bias, float* __restrict__ out) {
  __shared__ float Xs[32][132];
  const int t = threadIdx.x;
  const int p0 = blockIdx.x * 32;
  #pragma unroll
  for (int q = 0; q < 4; ++q) {
    const int id = t + q * 256;
    const int r = id >> 5, c4 = (id & 31) * 4;
    const float4 v = *(const float4*)(X + (size_t)(p0 + r) * 128 + c4);
    Xs[r][c4 + 0] = v.x; Xs[r][c4 + 1] = v.y;
    Xs[r][c4 + 2] = v.z; Xs[r][c4 + 3] = v.w;
  }
  __syncthreads();
  const int p = t >> 3, o = t & 7;
  float acc = 0.0f;
  #pragma unroll 8
  for (int i = 0; i < 128; ++i) acc += Wt[o * 128 + i] * Xs[p][i];
  out[(size_t)(p0 + p) * 8 + o] = acc + bias[o];
}

// ---------------------------------------------------------------------------
extern "C" void kernel_launch(void* const* d_in, const int* in_sizes, int n_in,
                              void* d_out, int out_size, void* d_ws,
                              size_t ws_size, hipStream_t stream) {
  const float* x       = (const float*)d_in[0];
  const float* w_emb1  = (const float*)d_in[1];
  const float* g_emb1  = (const float*)d_in[2];
  const float* be_emb1 = (const float*)d_in[3];
  const float* w_emb2  = (const float*)d_in[4];
  const float* g_emb2  = (const float*)d_in[5];
  const float* be_emb2 = (const float*)d_in[6];
  const float* l0_w1 = (const float*)d_in[7];
  const float* l0_g1 = (const float*)d_in[8];
  const float* l0_b1 = (const float*)d_in[9];
  const float* l0_w2 = (const float*)d_in[10];
  const float* l0_g2 = (const float*)d_in[11];
  const float* l0_b2 = (const float*)d_in[12];
  const float* l1_w1 = (const float*)d_in[13];
  const float* l1_g1 = (const float*)d_in[14];
  const float* l1_b1 = (const float*)d_in[15];
  const float* l1_w2 = (const float*)d_in[16];
  const float* l1_g2 = (const float*)d_in[17];
  const float* l1_b2 = (const float*)d_in[18];
  const float* f0_w1 = (const float*)d_in[19];
  const float* f0_g1 = (const float*)d_in[20];
  const float* f0_b1 = (const float*)d_in[21];
  const float* f0_w2 = (const float*)d_in[22];
  const float* f0_g2 = (const float*)d_in[23];
  const float* f0_b2 = (const float*)d_in[24];
  const float* f1_w1 = (const float*)d_in[25];
  const float* f1_g1 = (const float*)d_in[26];
  const float* f1_b1 = (const float*)d_in[27];
  const float* f1_w2 = (const float*)d_in[28];
  const float* f1_g2 = (const float*)d_in[29];
  const float* f1_b2 = (const float*)d_in[30];
  const float* c1_w    = (const float*)d_in[31];
  const float* c1_bias = (const float*)d_in[32];
  const float* c1_g    = (const float*)d_in[33];
  const float* c1_beta = (const float*)d_in[34];
  const float* c2_w    = (const float*)d_in[35];
  const float* c2_bias = (const float*)d_in[36];
  const float* c2_g    = (const float*)d_in[37];
  const float* c2_beta = (const float*)d_in[38];
  const float* out_w    = (const float*)d_in[39];
  const float* out_bias = (const float*)d_in[40];

  if (ws_size < WS_NEED) return;  // cannot run without scratch

  char* ws = (char*)d_ws;
  float* feats0 = (float*)(ws + O_FEATS0);
  float* feats1 = (float*)(ws + O_FEATS1);
  float* feats2 = (float*)(ws + O_FEATS2);
  float* fp0out = (float*)(ws + O_FP0OUT);
  float* xyz1   = (float*)(ws + O_XYZ1);
  float* xyz2   = (float*)(ws + O_XYZ2);
  int*   fps1   = (int*)(ws + O_FPS1);
  int*   fps2   = (int*)(ws + O_FPS2);
  int*   ball1  = (int*)(ws + O_BALL1);
  int*   ball2  = (int*)(ws + O_BALL2);
  int*   nn0i   = (int*)(ws + O_NN0I);
  float* nn0w   = (float*)(ws + O_NN0W);
  int*   nn1i   = (int*)(ws + O_NN1I);
  float* nn1w   = (float*)(ws + O_NN1W);
  float* REG0   = (float*)(ws + O_REG0);
  float* REG1   = (float*)(ws + O_REG1);
  float* outp   = (float*)d_out;
  hipStream_t s = stream;

  // ---- fps1 (+ fused embedding MLP on blocks 4..8195) ----
  fps_kernel<8192, 2048, true><<<4 + 8192, 256, 0, s>>>(
      x, fps1, xyz1, w_emb1, g_emb1, be_emb1, w_emb2, g_emb2, be_emb2, feats0);

  // ---- ball1 + nn1 (FP1's 3-NN) in one launch ----
  ballnn_kernel<<<2048 + 128, 256, 0, s>>>(x, xyz1, ball1, 11, 8192, 2048,
                                           x, xyz1, nn1i, nn1w, 13, 2048);

  // ---- SA layer 1: gather-conv1 -> conv2+segmax ----
  for (int c = 0; c < 2; ++c) {
    conv_gather_kernel<<<dim3(1024, 1), 256, 0, s>>>(
        feats0, ball1, fps1, c * 4096, 64, 11, 8192, l0_w1, REG1, 128, l0_g1,
        l0_b1);
    conv2sm_kernel<<<dim3(1024, 1), 256, 0, s>>>(
        REG1, l0_w2, feats1 + (size_t)c * 4096 * 128, 128, 128, l0_g2, l0_b2);
  }

  // ---- fps2 ----
  fps_kernel<2048, 1024, false><<<4, 256, 0, s>>>(
      xyz1, fps2, xyz2, nullptr, nullptr, nullptr, nullptr, nullptr, nullptr,
      nullptr);

  // ---- ball2 + nn0 (FP0's 3-NN) in one launch ----
  ballnn_kernel<<<1024 + 32, 256, 0, s>>>(xyz1, xyz2, ball2, 10, 2048, 1024,
                                          xyz1, xyz2, nn0i, nn0w, 11, 1024);

  // ---- SA layer 2 ----
  for (int c = 0; c < 2; ++c) {
    conv_gather_kernel<<<dim3(512, 2), 256, 0, s>>>(
        feats1, ball2, fps2, c * 2048, 128, 10, 2048, l1_w1, REG1, 256, l1_g1,
        l1_b1);
    conv2sm_kernel<<<dim3(512, 2), 256, 0, s>>>(
        REG1, l1_w2, feats2 + (size_t)c * 2048 * 256, 256, 256, l1_g2, l1_b2);
  }

  // ---- feature propagation 0: 1024 -> 2048 points ----
  copycols_kernel<<<1024, 256, 0, s>>>(REG0, 384, 0, feats1, 5);
  interp_kernel<<<2048, 256, 0, s>>>(REG0, 384, 128, feats2, nn0i, nn0w, 6, 11,
                                     1024);
  conv_kernel<<<dim3(64, 2), 256, 0, s>>>(REG0, f0_w1, REG1, 384, 256, f0_g1,
                                          f0_b1, nullptr, 1);
  conv_kernel<<<dim3(64, 4), 256, 0, s>>>(REG1, f0_w2, fp0out, 256, 512, f0_g2,
                                          f0_b2, nullptr, 1);

  // ---- feature propagation 1 + head, chunked per 2 batches ----
  for (int b = 0; b < 4; b += 2) {
    copycols_kernel<<<1024, 256, 0, s>>>(REG0, 576, 0,
                                         feats0 + (size_t)b * 8192 * 64, 4);
    interp_kernel<<<8192, 256, 0, s>>>(REG0, 576, 64,
                                       fp0out + (size_t)b * 2048 * 512,
                                       nn1i + (size_t)b * 8192 * 3,
                                       nn1w + (size_t)b * 8192 * 3, 7, 13,
                                       2048);
    conv_kernel<<<dim3(128, 4), 256, 0, s>>>(REG0, f1_w1, REG1, 576, 512,
                                             f1_g1, f1_b1, nullptr, 1);
    conv_kernel<<<dim3(128, 8), 256, 0, s>>>(REG1, f1_w2, REG0, 512, 1024,
                                             f1_g2, f1_b2, nullptr, 1);
    conv_kernel<<<dim3(128, 4), 256, 0, s>>>(REG0, c1_w, REG1, 1024, 512,
                                             c1_g, c1_beta, c1_bias, 1);
    conv_kernel<<<dim3(128, 1), 256, 0, s>>>(REG1, c2_w, REG0, 512, 128,
                                             c2_g, c2_beta, c2_bias, 1);
    outfinal_kernel<<<512, 256, 0, s>>>(REG0, out_w, out_bias,
                                        outp + (size_t)b * 8192 * 8);
  }
}

// Round 10
// 4617.764 us; speedup vs baseline: 1.5611x; 1.0626x over previous
//
#include <hip/hip_runtime.h>
#include <math.h>

// ---------------------------------------------------------------------------
// PointNet++ part-seg forward. All features stored point-major: row = point,
// C contiguous floats per row. B=4, N=8192 fixed by the problem.
// ---------------------------------------------------------------------------

// ---------------- workspace layout (bytes) ----------------
static constexpr size_t O_FEATS0 = 0;                    // (4*8192, 64)  f32
static constexpr size_t O_FEATS1 = 8388608;              // (4*2048, 128)
static constexpr size_t O_FEATS2 = 12582912;             // (4*1024, 256)
static constexpr size_t O_FP0OUT = 16777216;             // (4*2048, 512)
static constexpr size_t O_XYZ1   = 33554432;             // (4*2048, 3)
static constexpr size_t O_XYZ2   = 33652736;             // (4*1024, 3)
static constexpr size_t O_FPS1   = 33701888;             // (4*2048) int
static constexpr size_t O_FPS2   = 33734656;             // (4*1024) int
static constexpr size_t O_BALL1  = 33751040;             // (4*2048*32) int
static constexpr size_t O_BALL2  = 34799616;             // (4*1024*32) int
static constexpr size_t O_NN0I   = 35323904;             // (4*2048*3) int
static constexpr size_t O_NN0W   = 35422208;             // (4*2048*3) f32
static constexpr size_t O_NN1I   = 35520512;             // (4*8192*3) int
static constexpr size_t O_NN1W   = 35913728;             // (4*8192*3) f32
static constexpr size_t O_REG0   = 36306944;             // 67108864 scratch
static constexpr size_t O_REG1   = 103415808;            // 67108864 scratch
static constexpr size_t WS_NEED  = 170524672;

typedef float v2f __attribute__((ext_vector_type(2)));

// ---------------- DPP helpers for wave-64 u64 max reduce -------------------
__device__ __forceinline__ unsigned long long u64max(unsigned long long a,
                                                     unsigned long long b) {
  return a > b ? a : b;
}
template <int CTRL>
__device__ __forceinline__ unsigned long long dpp_step(unsigned long long k) {
  const int lo = (int)(unsigned)k;
  const int hi = (int)(unsigned)(k >> 32);
  const int nlo = __builtin_amdgcn_update_dpp(lo, lo, CTRL, 0xf, 0xf, false);
  const int nhi = __builtin_amdgcn_update_dpp(hi, hi, CTRL, 0xf, 0xf, false);
  return ((unsigned long long)(unsigned)nhi << 32) | (unsigned)nlo;
}

// ---------------- fps core (LDS provided by caller) ------------------------
// 256 threads per batch. Packed v2f distance math, fp contract(off) ->
// bit-exact vs numpy. Local argmax: max tree + ==bv bitmask + ctz (first
// occurrence). Cross-lane argmax on packed u64 key = bits(d)<<32 | ~idx.
// In-wave reduce via DPP to lane 63; one barrier/iter; stage 2 = 4 broadcast
// u64 reads + 3 compares. Indices + gathered coords written in epilogue.
template <int N, int NP>
__device__ void fps_core(const float* __restrict__ xyz, int* __restrict__ out,
                         float* __restrict__ oxyz, float* sx, float* sy,
                         float* sz, int* sfar, unsigned long long* skey,
                         int b, int t) {
  #pragma clang fp contract(off)
  constexpr int PPT = N / 256;
  constexpr int PAIRS = PPT / 2;
  const float* xb = xyz + (size_t)b * N * 3;
  for (int i = t; i < N; i += 256) {
    sx[i] = xb[i * 3 + 0];
    sy[i] = xb[i * 3 + 1];
    sz[i] = xb[i * 3 + 2];
  }
  __syncthreads();
  v2f px[PAIRS], py[PAIRS], pz[PAIRS], ds[PAIRS];
  #pragma unroll
  for (int k = 0; k < PAIRS; ++k) {
    const int g = t * PPT + 2 * k;
    px[k].x = sx[g]; px[k].y = sx[g + 1];
    py[k].x = sy[g]; py[k].y = sy[g + 1];
    pz[k].x = sz[g]; pz[k].y = sz[g + 1];
    ds[k].x = 1e10f; ds[k].y = 1e10f;
  }
  const int wid = t >> 6, lane = t & 63;
  int far = 0;
  float ccx = sx[0], ccy = sy[0], ccz = sz[0];
  for (int it = 0; it < NP; ++it) {
    if (t == 0) sfar[it] = far;
    v2f cx2, cy2, cz2;
    cx2.x = ccx; cx2.y = ccx;
    cy2.x = ccy; cy2.y = ccy;
    cz2.x = ccz; cz2.y = ccz;
    #pragma unroll
    for (int k = 0; k < PAIRS; ++k) {
      const v2f dx = px[k] - cx2;
      const v2f dy = py[k] - cy2;
      const v2f dz = pz[k] - cz2;
      const v2f d = dx * dx + dy * dy + dz * dz;
      v2f nd;
      nd.x = fminf(ds[k].x, d.x);
      nd.y = fminf(ds[k].y, d.y);
      ds[k] = nd;
    }
    v2f tv[PAIRS / 2];
    #pragma unroll
    for (int k = 0; k < PAIRS / 2; ++k) {
      tv[k].x = fmaxf(ds[k].x, ds[k + PAIRS / 2].x);
      tv[k].y = fmaxf(ds[k].y, ds[k + PAIRS / 2].y);
    }
    #pragma unroll
    for (int w = PAIRS / 4; w >= 1; w >>= 1) {
      #pragma unroll
      for (int k = 0; k < w; ++k) {
        tv[k].x = fmaxf(tv[k].x, tv[k + w].x);
        tv[k].y = fmaxf(tv[k].y, tv[k + w].y);
      }
    }
    const float bv = fmaxf(tv[0].x, tv[0].y);
    unsigned mask = 0u;
    #pragma unroll
    for (int k = 0; k < PAIRS; ++k) {
      mask |= (ds[k].x == bv) ? (1u << (2 * k)) : 0u;
      mask |= (ds[k].y == bv) ? (1u << (2 * k + 1)) : 0u;
    }
    const int bjl = __builtin_ctz(mask);
    unsigned long long bk =
        ((unsigned long long)__float_as_uint(bv) << 32) |
        (unsigned long long)(unsigned)(~(unsigned)(t * PPT + bjl));
    bk = u64max(bk, dpp_step<0x111>(bk));  // row_shr:1
    bk = u64max(bk, dpp_step<0x112>(bk));  // row_shr:2
    bk = u64max(bk, dpp_step<0x114>(bk));  // row_shr:4
    bk = u64max(bk, dpp_step<0x118>(bk));  // row_shr:8
    bk = u64max(bk, dpp_step<0x142>(bk));  // row_bcast:15
    bk = u64max(bk, dpp_step<0x143>(bk));  // row_bcast:31
    const int p = it & 1;
    if (lane == 63) skey[p * 4 + wid] = bk;
    __syncthreads();
    unsigned long long wk = skey[p * 4 + 0];
    #pragma unroll
    for (int q = 1; q < 4; ++q) {
      const unsigned long long k2 = skey[p * 4 + q];
      wk = (k2 > wk) ? k2 : wk;
    }
    far = (int)(~(unsigned)wk);
    ccx = sx[far]; ccy = sy[far]; ccz = sz[far];
  }
  __syncthreads();
  for (int i = t; i < NP; i += 256) {
    const int n = sfar[i];
    out[(size_t)b * NP + i] = n;
    oxyz[((size_t)b * NP + i) * 3 + 0] = sx[n];
    oxyz[((size_t)b * NP + i) * 3 + 1] = sy[n];
    oxyz[((size_t)b * NP + i) * 3 + 2] = sz[n];
  }
}

// ---------------- fps1 (+ fused emb on blocks 4..) -------------------------
template <int N, int NP>
__global__ __launch_bounds__(256, 1) void fps_emb_kernel(
    const float* __restrict__ xyz, int* __restrict__ out,
    float* __restrict__ oxyz, const float* __restrict__ w1,
    const float* __restrict__ g1, const float* __restrict__ b1,
    const float* __restrict__ w2, const float* __restrict__ g2,
    const float* __restrict__ b2, float* __restrict__ femb) {
  __shared__ float sx[N], sy[N], sz[N];
  __shared__ int sfar[NP];
  __shared__ unsigned long long skey[8];
  if (blockIdx.x >= 4) {
    const int bid = blockIdx.x - 4;
    const int t = threadIdx.x;
    const int o = t & 63, pl = t >> 6;
    const int pt = bid * 4 + pl;
    const float x0 = xyz[(size_t)pt * 3 + 0];
    const float x1 = xyz[(size_t)pt * 3 + 1];
    const float x2 = xyz[(size_t)pt * 3 + 2];
    const float SQ = sqrtf(1.0f + 1e-5f);
    float v = w1[o * 3 + 0] * x0 + w1[o * 3 + 1] * x1 + w1[o * 3 + 2] * x2;
    v = fmaxf(v * (g1[o] / SQ) + b1[o], 0.0f);
    float* h = sx;  // reuse LDS
    h[pl * 64 + o] = v;
    __syncthreads();
    float acc = 0.0f;
    #pragma unroll 8
    for (int i = 0; i < 64; ++i) acc += w2[o * 64 + i] * h[pl * 64 + i];
    float y = fmaxf(acc * (g2[o] / SQ) + b2[o], 0.0f);
    femb[(size_t)pt * 64 + o] = y;
    return;
  }
  fps_core<N, NP>(xyz, out, oxyz, sx, sy, sz, sfar, skey, blockIdx.x,
                  threadIdx.x);
}

// ---------------- fused fps2 + ball query + 3-NN ---------------------------
// Blocks 0..3: fps2 (serial-chain, placed FIRST so it dispatches first and
// its ~460us covers the ball/nn work). Blocks [4, 4+nBall): ball query.
// Blocks [4+nBall, ...): 3-NN. All paths depend only on prior-launch data.
__global__ __launch_bounds__(256, 1) void ballnnfps_kernel(
    const float* __restrict__ cloud, const float* __restrict__ ctr,
    int* __restrict__ ballOut, int sbits, int N, int nBallBlk,
    const float* __restrict__ txyz, const float* __restrict__ sxyz,
    int* __restrict__ oi, float* __restrict__ ow, int s1bits, int S2,
    const float* __restrict__ fxyz, int* __restrict__ fout,
    float* __restrict__ foxyz) {
  __shared__ __align__(16) char smem[28800];
  const int t = threadIdx.x;
  if ((int)blockIdx.x < 4) {
    unsigned long long* skey = (unsigned long long*)smem;  // 64B
    int* sfar = (int*)(smem + 64);                         // 4KB
    float* sx = (float*)(smem + 64 + 4096);
    float* sy = sx + 2048;
    float* sz = sy + 2048;
    fps_core<2048, 1024>(fxyz, fout, foxyz, sx, sy, sz, sfar, skey,
                         blockIdx.x, t);
    return;
  }
  if ((int)blockIdx.x < 4 + nBallBlk) {
    int* lists = (int*)smem;  // [4][32]
    const int lane = t & 63, wid = t >> 6;
    const int wg = (blockIdx.x - 4) * 4 + wid;
    const int b = wg >> sbits;
    const float cx = ctr[(size_t)wg * 3 + 0];
    const float cy = ctr[(size_t)wg * 3 + 1];
    const float cz = ctr[(size_t)wg * 3 + 2];
    const float an = __fadd_rn(__fadd_rn(__fmul_rn(cx, cx), __fmul_rn(cy, cy)),
                               __fmul_rn(cz, cz));
    int fill = 0;
    for (int ch = 0; ch < (N >> 6) && fill < 32; ++ch) {
      const int n = ch * 64 + lane;
      const float bx = cloud[((size_t)b * N + n) * 3 + 0];
      const float by = cloud[((size_t)b * N + n) * 3 + 1];
      const float bz = cloud[((size_t)b * N + n) * 3 + 2];
      const float bb = __fadd_rn(
          __fadd_rn(__fmul_rn(bx, bx), __fmul_rn(by, by)), __fmul_rn(bz, bz));
      const float dot = __fadd_rn(
          __fadd_rn(__fmul_rn(cx, bx), __fmul_rn(cy, by)), __fmul_rn(cz, bz));
      const float d2 = __fsub_rn(__fadd_rn(an, bb), __fmul_rn(2.0f, dot));
      const bool q = (d2 <= 1.0f);
      const unsigned long long mask = __ballot(q);
      if (q) {
        const int pos = fill + __popcll(mask & ((1ull << lane) - 1ull));
        if (pos < 32) lists[wid * 32 + pos] = n;
      }
      fill += (int)__popcll(mask);
    }
    __syncthreads();
    if (lane < 32) {
      int v = lists[wid * 32 + 0];
      if (lane < fill) v = lists[wid * 32 + lane];
      ballOut[(size_t)wg * 32 + lane] = v;
    }
    return;
  }
  // ---- 3-NN path ----
  float* ss = (float*)smem;  // S2*3 floats (<= 6144)
  const int row = (blockIdx.x - 4 - nBallBlk) * 256 + t;
  const int b = row >> s1bits;
  for (int i = t; i < S2 * 3; i += 256) ss[i] = sxyz[(size_t)b * S2 * 3 + i];
  __syncthreads();
  const float ax = txyz[(size_t)row * 3 + 0];
  const float ay = txyz[(size_t)row * 3 + 1];
  const float az = txyz[(size_t)row * 3 + 2];
  const float an = __fadd_rn(__fadd_rn(__fmul_rn(ax, ax), __fmul_rn(ay, ay)),
                             __fmul_rn(az, az));
  float d0 = 3.4e38f, d1 = 3.4e38f, d2v = 3.4e38f;
  int i0 = 0, i1 = 0, i2 = 0;
  for (int j = 0; j < S2; ++j) {
    const float bx = ss[j * 3 + 0], by = ss[j * 3 + 1], bz = ss[j * 3 + 2];
    const float bb = __fadd_rn(__fadd_rn(__fmul_rn(bx, bx), __fmul_rn(by, by)),
                               __fmul_rn(bz, bz));
    const float dot = __fadd_rn(__fadd_rn(__fmul_rn(ax, bx), __fmul_rn(ay, by)),
                                __fmul_rn(az, bz));
    const float dd = __fsub_rn(__fadd_rn(an, bb), __fmul_rn(2.0f, dot));
    if (dd < d0) {
      d2v = d1; i2 = i1; d1 = d0; i1 = i0; d0 = dd; i0 = j;
    } else if (dd < d1) {
      d2v = d1; i2 = i1; d1 = dd; i1 = j;
    } else if (dd < d2v) {
      d2v = dd; i2 = j;
    }
  }
  const float r0 = 1.0f / (d0 + 1e-8f);
  const float r1 = 1.0f / (d1 + 1e-8f);
  const float r2 = 1.0f / (d2v + 1e-8f);
  const float sum = __fadd_rn(__fadd_rn(r0, r1), r2);
  oi[(size_t)row * 3 + 0] = i0;
  oi[(size_t)row * 3 + 1] = i1;
  oi[(size_t)row * 3 + 2] = i2;
  ow[(size_t)row * 3 + 0] = r0 / sum;
  ow[(size_t)row * 3 + 1] = r1 / sum;
  ow[(size_t)row * 3 + 2] = r2 / sum;
}

// ---------------- plain ball + 3-NN (layer 2: needs xyz2 first) ------------
__global__ __launch_bounds__(256) void ballnn_kernel(
    const float* __restrict__ cloud, const float* __restrict__ ctr,
    int* __restrict__ ballOut, int sbits, int N, int nBallBlk,
    const float* __restrict__ txyz, const float* __restrict__ sxyz,
    int* __restrict__ oi, float* __restrict__ ow, int s1bits, int S2) {
  __shared__ int lists[4][32];
  __shared__ float ss[6144];
  const int t = threadIdx.x;
  if ((int)blockIdx.x < nBallBlk) {
    const int lane = t & 63, wid = t >> 6;
    const int wg = blockIdx.x * 4 + wid;
    const int b = wg >> sbits;
    const float cx = ctr[(size_t)wg * 3 + 0];
    const float cy = ctr[(size_t)wg * 3 + 1];
    const float cz = ctr[(size_t)wg * 3 + 2];
    const float an = __fadd_rn(__fadd_rn(__fmul_rn(cx, cx), __fmul_rn(cy, cy)),
                               __fmul_rn(cz, cz));
    int fill = 0;
    for (int ch = 0; ch < (N >> 6) && fill < 32; ++ch) {
      const int n = ch * 64 + lane;
      const float bx = cloud[((size_t)b * N + n) * 3 + 0];
      const float by = cloud[((size_t)b * N + n) * 3 + 1];
      const float bz = cloud[((size_t)b * N + n) * 3 + 2];
      const float bb = __fadd_rn(
          __fadd_rn(__fmul_rn(bx, bx), __fmul_rn(by, by)), __fmul_rn(bz, bz));
      const float dot = __fadd_rn(
          __fadd_rn(__fmul_rn(cx, bx), __fmul_rn(cy, by)), __fmul_rn(cz, bz));
      const float d2 = __fsub_rn(__fadd_rn(an, bb), __fmul_rn(2.0f, dot));
      const bool q = (d2 <= 1.0f);
      const unsigned long long mask = __ballot(q);
      if (q) {
        const int pos = fill + __popcll(mask & ((1ull << lane) - 1ull));
        if (pos < 32) lists[wid][pos] = n;
      }
      fill += (int)__popcll(mask);
    }
    __syncthreads();
    if (lane < 32) {
      int v = lists[wid][0];
      if (lane < fill) v = lists[wid][lane];
      ballOut[(size_t)wg * 32 + lane] = v;
    }
    return;
  }
  const int row = (blockIdx.x - nBallBlk) * 256 + t;
  const int b = row >> s1bits;
  for (int i = t; i < S2 * 3; i += 256) ss[i] = sxyz[(size_t)b * S2 * 3 + i];
  __syncthreads();
  const float ax = txyz[(size_t)row * 3 + 0];
  const float ay = txyz[(size_t)row * 3 + 1];
  const float az = txyz[(size_t)row * 3 + 2];
  const float an = __fadd_rn(__fadd_rn(__fmul_rn(ax, ax), __fmul_rn(ay, ay)),
                             __fmul_rn(az, az));
  float d0 = 3.4e38f, d1 = 3.4e38f, d2v = 3.4e38f;
  int i0 = 0, i1 = 0, i2 = 0;
  for (int j = 0; j < S2; ++j) {
    const float bx = ss[j * 3 + 0], by = ss[j * 3 + 1], bz = ss[j * 3 + 2];
    const float bb = __fadd_rn(__fadd_rn(__fmul_rn(bx, bx), __fmul_rn(by, by)),
                               __fmul_rn(bz, bz));
    const float dot = __fadd_rn(__fadd_rn(__fmul_rn(ax, bx), __fmul_rn(ay, by)),
                                __fmul_rn(az, bz));
    const float dd = __fsub_rn(__fadd_rn(an, bb), __fmul_rn(2.0f, dot));
    if (dd < d0) {
      d2v = d1; i2 = i1; d1 = d0; i1 = i0; d0 = dd; i0 = j;
    } else if (dd < d1) {
      d2v = d1; i2 = i1; d1 = dd; i1 = j;
    } else if (dd < d2v) {
      d2v = dd; i2 = j;
    }
  }
  const float r0 = 1.0f / (d0 + 1e-8f);
  const float r1 = 1.0f / (d1 + 1e-8f);
  const float r2 = 1.0f / (d2v + 1e-8f);
  const float sum = __fadd_rn(__fadd_rn(r0, r1), r2);
  oi[(size_t)row * 3 + 0] = i0;
  oi[(size_t)row * 3 + 1] = i1;
  oi[(size_t)row * 3 + 2] = i2;
  ow[(size_t)row * 3 + 0] = r0 / sum;
  ow[(size_t)row * 3 + 1] = r1 / sum;
  ow[(size_t)row * 3 + 2] = r2 / sum;
}

#define CMAP(c) ((((c) >> 3) * 12) + ((c) & 7))

// ---------------- SA conv1: gather (groupmat) fused into the X-tile load ---
__global__ __launch_bounds__(256) void conv_gather_kernel(
    const float* __restrict__ f, const int* __restrict__ ball,
    const int* __restrict__ fps, int g0, int Cf, int sbits, int Npts,
    const float* __restrict__ W, float* __restrict__ Y, int O,
    const float* __restrict__ gamma, const float* __restrict__ beta) {
  const int C = Cf * 2;
  __shared__ float Xs[16][188];
  __shared__ float Ws[16][188];
  const int t = threadIdx.x;
  const size_t m0 = (size_t)blockIdx.x * 128;
  const int o0 = blockIdx.y * 128;
  const int r0 = t >> 2;
  const int cq0 = (t & 3) * 4;
  const int mq = t & 15, nq = t >> 4;
  const int ca = CMAP(r0), cb = CMAP(r0 + 64);
  const int mA = (int)m0 + r0, mB = (int)m0 + r0 + 64;
  const int glA = g0 + (mA >> 5), glB = g0 + (mB >> 5);
  const int srcA = ball[(size_t)glA * 32 + (mA & 31)];
  const int srcB = ball[(size_t)glB * 32 + (mB & 31)];
  const int ctrA = fps[glA], ctrB = fps[glB];
  const float* fbA = f + (size_t)(glA >> sbits) * Npts * Cf;
  const float* fbB = f + (size_t)(glB >> sbits) * Npts * Cf;
  v2f acc[8][4];
  #pragma unroll
  for (int i = 0; i < 8; ++i)
    #pragma unroll
    for (int j = 0; j < 4; ++j) acc[i][j] = (v2f){0.0f, 0.0f};

  for (int kk = 0; kk < C; kk += 16) {
    const int col = kk + cq0;
    const bool lo = col < Cf;
    const int col2 = lo ? col : col - Cf;
    float4 xa, xb;
    {
      const float4 c4 = *(const float4*)(fbA + (size_t)ctrA * Cf + col2);
      if (lo) {
        const float4 s4 = *(const float4*)(fbA + (size_t)srcA * Cf + col);
        xa = make_float4(s4.x - c4.x, s4.y - c4.y, s4.z - c4.z, s4.w - c4.w);
      } else {
        xa = c4;
      }
    }
    {
      const float4 c4 = *(const float4*)(fbB + (size_t)ctrB * Cf + col2);
      if (lo) {
        const float4 s4 = *(const float4*)(fbB + (size_t)srcB * Cf + col);
        xb = make_float4(s4.x - c4.x, s4.y - c4.y, s4.z - c4.z, s4.w - c4.w);
      } else {
        xb = c4;
      }
    }
    const float4 wa = *(const float4*)(W + (size_t)(o0 + r0) * C + kk + cq0);
    const float4 wb =
        *(const float4*)(W + (size_t)(o0 + r0 + 64) * C + kk + cq0);
    __syncthreads();
    Xs[cq0 + 0][ca] = xa.x; Xs[cq0 + 1][ca] = xa.y;
    Xs[cq0 + 2][ca] = xa.z; Xs[cq0 + 3][ca] = xa.w;
    Xs[cq0 + 0][cb] = xb.x; Xs[cq0 + 1][cb] = xb.y;
    Xs[cq0 + 2][cb] = xb.z; Xs[cq0 + 3][cb] = xb.w;
    Ws[cq0 + 0][ca] = wa.x; Ws[cq0 + 1][ca] = wa.y;
    Ws[cq0 + 2][ca] = wa.z; Ws[cq0 + 3][ca] = wa.w;
    Ws[cq0 + 0][cb] = wb.x; Ws[cq0 + 1][cb] = wb.y;
    Ws[cq0 + 2][cb] = wb.z; Ws[cq0 + 3][cb] = wb.w;
    __syncthreads();
    #pragma unroll
    for (int k = 0; k < 16; ++k) {
      const float4 a0 = *(const float4*)&Xs[k][mq * 12];
      const float4 a1 = *(const float4*)&Xs[k][mq * 12 + 4];
      const float4 b0 = *(const float4*)&Ws[k][nq * 12];
      const float4 b1 = *(const float4*)&Ws[k][nq * 12 + 4];
      const float am[8] = {a0.x, a0.y, a0.z, a0.w, a1.x, a1.y, a1.z, a1.w};
      v2f bv[4];
      bv[0] = (v2f){b0.x, b0.y};
      bv[1] = (v2f){b0.z, b0.w};
      bv[2] = (v2f){b1.x, b1.y};
      bv[3] = (v2f){b1.z, b1.w};
      #pragma unroll
      for (int i = 0; i < 8; ++i) {
        const v2f as = (v2f){am[i], am[i]};
        #pragma unroll
        for (int j = 0; j < 4; ++j) acc[i][j] += as * bv[j];
      }
    }
  }

  const float SQ = sqrtf(1.0f + 1e-5f);
  float s[8], sh[8];
  #pragma unroll
  for (int j = 0; j < 8; ++j) {
    const int o = o0 + nq * 8 + j;
    s[j] = gamma[o] / SQ;
    sh[j] = beta[o];
  }
  #pragma unroll
  for (int i = 0; i < 8; ++i) {
    float y[8];
    #pragma unroll
    for (int j = 0; j < 4; ++j) {
      y[2 * j] = fmaxf(acc[i][j].x * s[2 * j] + sh[2 * j], 0.0f);
      y[2 * j + 1] = fmaxf(acc[i][j].y * s[2 * j + 1] + sh[2 * j + 1], 0.0f);
    }
    const size_t off = (m0 + mq * 8 + i) * O + o0 + nq * 8;
    *(float4*)(Y + off) = make_float4(y[0], y[1], y[2], y[3]);
    *(float4*)(Y + off + 4) = make_float4(y[4], y[5], y[6], y[7]);
  }
}

// ---------------- SA conv2 with fused segmented max epilogue ---------------
__global__ __launch_bounds__(256) void conv2sm_kernel(
    const float* __restrict__ X, const float* __restrict__ W,
    float* __restrict__ F, int C, int O, const float* __restrict__ gamma,
    const float* __restrict__ beta) {
  __shared__ float Xs[16][188];
  __shared__ float Ws[16][188];
  const int t = threadIdx.x;
  const size_t m0 = (size_t)blockIdx.x * 128;
  const int o0 = blockIdx.y * 128;
  const int r0 = t >> 2;
  const int cq0 = (t & 3) * 4;
  const int mq = t & 15, nq = t >> 4;
  const int ca = CMAP(r0), cb = CMAP(r0 + 64);
  v2f acc[8][4];
  #pragma unroll
  for (int i = 0; i < 8; ++i)
    #pragma unroll
    for (int j = 0; j < 4; ++j) acc[i][j] = (v2f){0.0f, 0.0f};

  for (int kk = 0; kk < C; kk += 16) {
    const float4 xa = *(const float4*)(X + (m0 + r0) * C + kk + cq0);
    const float4 xb = *(const float4*)(X + (m0 + r0 + 64) * C + kk + cq0);
    const float4 wa = *(const float4*)(W + (size_t)(o0 + r0) * C + kk + cq0);
    const float4 wb =
        *(const float4*)(W + (size_t)(o0 + r0 + 64) * C + kk + cq0);
    __syncthreads();
    Xs[cq0 + 0][ca] = xa.x; Xs[cq0 + 1][ca] = xa.y;
    Xs[cq0 + 2][ca] = xa.z; Xs[cq0 + 3][ca] = xa.w;
    Xs[cq0 + 0][cb] = xb.x; Xs[cq0 + 1][cb] = xb.y;
    Xs[cq0 + 2][cb] = xb.z; Xs[cq0 + 3][cb] = xb.w;
    Ws[cq0 + 0][ca] = wa.x; Ws[cq0 + 1][ca] = wa.y;
    Ws[cq0 + 2][ca] = wa.z; Ws[cq0 + 3][ca] = wa.w;
    Ws[cq0 + 0][cb] = wb.x; Ws[cq0 + 1][cb] = wb.y;
    Ws[cq0 + 2][cb] = wb.z; Ws[cq0 + 3][cb] = wb.w;
    __syncthreads();
    #pragma unroll
    for (int k = 0; k < 16; ++k) {
      const float4 a0 = *(const float4*)&Xs[k][mq * 12];
      const float4 a1 = *(const float4*)&Xs[k][mq * 12 + 4];
      const float4 b0 = *(const float4*)&Ws[k][nq * 12];
      const float4 b1 = *(const float4*)&Ws[k][nq * 12 + 4];
      const float am[8] = {a0.x, a0.y, a0.z, a0.w, a1.x, a1.y, a1.z, a1.w};
      v2f bv[4];
      bv[0] = (v2f){b0.x, b0.y};
      bv[1] = (v2f){b0.z, b0.w};
      bv[2] = (v2f){b1.x, b1.y};
      bv[3] = (v2f){b1.z, b1.w};
      #pragma unroll
      for (int i = 0; i < 8; ++i) {
        const v2f as = (v2f){am[i], am[i]};
        #pragma unroll
        for (int j = 0; j < 4; ++j) acc[i][j] += as * bv[j];
      }
    }
  }

  const float SQ = sqrtf(1.0f + 1e-5f);
  float s[8], sh[8];
  #pragma unroll
  for (int j = 0; j < 8; ++j) {
    const int o = o0 + nq * 8 + j;
    s[j] = gamma[o] / SQ;
    sh[j] = beta[o];
  }
  float colmax[8];
  #pragma unroll
  for (int j = 0; j < 8; ++j) colmax[j] = -3.4e38f;
  #pragma unroll
  for (int i = 0; i < 8; ++i) {
    #pragma unroll
    for (int j = 0; j < 4; ++j) {
      const float va = fmaxf(acc[i][j].x * s[2 * j] + sh[2 * j], 0.0f);
      const float vb = fmaxf(acc[i][j].y * s[2 * j + 1] + sh[2 * j + 1], 0.0f);
      colmax[2 * j] = fmaxf(colmax[2 * j], va);
      colmax[2 * j + 1] = fmaxf(colmax[2 * j + 1], vb);
    }
  }
  __syncthreads();
  float* smax = &Xs[0][0];  // 16*188 floats >= 16*132
  #pragma unroll
  for (int j = 0; j < 8; ++j) smax[mq * 132 + nq * 8 + j] = colmax[j];
  __syncthreads();
  #pragma unroll
  for (int q = 0; q < 2; ++q) {
    const int idx = t + q * 256;
    const int g = idx >> 7;
    const int col = idx & 127;
    const float m =
        fmaxf(fmaxf(smax[(4 * g + 0) * 132 + col], smax[(4 * g + 1) * 132 + col]),
              fmaxf(smax[(4 * g + 2) * 132 + col], smax[(4 * g + 3) * 132 + col]));
    F[(size_t)(blockIdx.x * 4 + g) * O + o0 + col] = m;
  }
}

// ---------------- generic 1x1 conv (GEMM) with BN/bias/ReLU epilogue -------
__global__ __launch_bounds__(256) void conv_kernel(
    const float* __restrict__ X, const float* __restrict__ W,
    float* __restrict__ Y, int C, int O, const float* __restrict__ gamma,
    const float* __restrict__ beta, const float* __restrict__ bias, int relu) {
  __shared__ float Xs[16][188];
  __shared__ float Ws[16][188];
  const int t = threadIdx.x;
  const size_t m0 = (size_t)blockIdx.x * 128;
  const int o0 = blockIdx.y * 128;
  const int r0 = t >> 2;
  const int cq0 = (t & 3) * 4;
  const int mq = t & 15, nq = t >> 4;
  const int ca = CMAP(r0), cb = CMAP(r0 + 64);
  v2f acc[8][4];
  #pragma unroll
  for (int i = 0; i < 8; ++i)
    #pragma unroll
    for (int j = 0; j < 4; ++j) acc[i][j] = (v2f){0.0f, 0.0f};

  for (int kk = 0; kk < C; kk += 16) {
    const float4 xa = *(const float4*)(X + (m0 + r0) * C + kk + cq0);
    const float4 xb = *(const float4*)(X + (m0 + r0 + 64) * C + kk + cq0);
    const float4 wa = *(const float4*)(W + (size_t)(o0 + r0) * C + kk + cq0);
    const float4 wb =
        *(const float4*)(W + (size_t)(o0 + r0 + 64) * C + kk + cq0);
    __syncthreads();
    Xs[cq0 + 0][ca] = xa.x; Xs[cq0 + 1][ca] = xa.y;
    Xs[cq0 + 2][ca] = xa.z; Xs[cq0 + 3][ca] = xa.w;
    Xs[cq0 + 0][cb] = xb.x; Xs[cq0 + 1][cb] = xb.y;
    Xs[cq0 + 2][cb] = xb.z; Xs[cq0 + 3][cb] = xb.w;
    Ws[cq0 + 0][ca] = wa.x; Ws[cq0 + 1][ca] = wa.y;
    Ws[cq0 + 2][ca] = wa.z; Ws[cq0 + 3][ca] = wa.w;
    Ws[cq0 + 0][cb] = wb.x; Ws[cq0 + 1][cb] = wb.y;
    Ws[cq0 + 2][cb] = wb.z; Ws[cq0 + 3][cb] = wb.w;
    __syncthreads();
    #pragma unroll
    for (int k = 0; k < 16; ++k) {
      const float4 a0 = *(const float4*)&Xs[k][mq * 12];
      const float4 a1 = *(const float4*)&Xs[k][mq * 12 + 4];
      const float4 b0 = *(const float4*)&Ws[k][nq * 12];
      const float4 b1 = *(const float4*)&Ws[k][nq * 12 + 4];
      const float am[8] = {a0.x, a0.y, a0.z, a0.w, a1.x, a1.y, a1.z, a1.w};
      v2f bv[4];
      bv[0] = (v2f){b0.x, b0.y};
      bv[1] = (v2f){b0.z, b0.w};
      bv[2] = (v2f){b1.x, b1.y};
      bv[3] = (v2f){b1.z, b1.w};
      #pragma unroll
      for (int i = 0; i < 8; ++i) {
        const v2f as = (v2f){am[i], am[i]};
        #pragma unroll
        for (int j = 0; j < 4; ++j) acc[i][j] += as * bv[j];
      }
    }
  }

  const float SQ = sqrtf(1.0f + 1e-5f);
  float s[8], sh[8];
  #pragma unroll
  for (int j = 0; j < 8; ++j) {
    const int o = o0 + nq * 8 + j;
    const float sc = gamma ? (gamma[o] / SQ) : 1.0f;
    float bb = beta ? beta[o] : 0.0f;
    if (bias) bb = bb + bias[o] * sc;
    s[j] = sc; sh[j] = bb;
  }
  #pragma unroll
  for (int i = 0; i < 8; ++i) {
    float y[8];
    #pragma unroll
    for (int j = 0; j < 4; ++j) {
      float va = acc[i][j].x * s[2 * j] + sh[2 * j];
      float vb = acc[i][j].y * s[2 * j + 1] + sh[2 * j + 1];
      y[2 * j] = relu ? fmaxf(va, 0.0f) : va;
      y[2 * j + 1] = relu ? fmaxf(vb, 0.0f) : vb;
    }
    const size_t off = (m0 + mq * 8 + i) * O + o0 + nq * 8;
    *(float4*)(Y + off) = make_float4(y[0], y[1], y[2], y[3]);
    *(float4*)(Y + off + 4) = make_float4(y[4], y[5], y[6], y[7]);
  }
}

// ---------------- fused concat: copy cols [0,C0) + interp cols [C0,CT) -----
template <int CT, int C0, int CS2>
__global__ __launch_bounds__(256) void concat_interp_kernel(
    float* __restrict__ dst, const float* __restrict__ srcA,
    const float* __restrict__ srcB, const int* __restrict__ idx,
    const float* __restrict__ w, int s1bits, int S2) {
  const int id = blockIdx.x * 256 + threadIdx.x;
  constexpr int CPR = CT / 4;
  const int row = id / CPR;
  const int c4 = (id - row * CPR) * 4;
  if (c4 < C0) {
    const float4 v = *(const float4*)(srcA + (size_t)row * C0 + c4);
    *(float4*)(dst + (size_t)row * CT + c4) = v;
  } else {
    const int b = row >> s1bits;
    const int cc = c4 - C0;
    const int j0 = idx[(size_t)row * 3 + 0];
    const int j1 = idx[(size_t)row * 3 + 1];
    const int j2 = idx[(size_t)row * 3 + 2];
    const float w0 = w[(size_t)row * 3 + 0];
    const float w1 = w[(size_t)row * 3 + 1];
    const float w2 = w[(size_t)row * 3 + 2];
    const float4 f0 = *(const float4*)(srcB + ((size_t)b * S2 + j0) * CS2 + cc);
    const float4 f1 = *(const float4*)(srcB + ((size_t)b * S2 + j1) * CS2 + cc);
    const float4 f2 = *(const float4*)(srcB + ((size_t)b * S2 + j2) * CS2 + cc);
    float4 v;
    v.x = f0.x * w0 + f1.x * w1 + f2.x * w2;
    v.y = f0.y * w0 + f1.y * w1 + f2.y * w2;
    v.z = f0.z * w0 + f1.z * w1 + f2.z * w2;
    v.w = f0.w * w0 + f1.w * w1 + f2.w * w2;
    *(float4*)(dst + (size_t)row * CT + c4) = v;
  }
}

// ---------------- final 128->8 conv + bias, point-major out ----------------
__global__ __launch_bounds__(256) void outfinal_kernel(
    const float* __restrict__ X, const float* __restrict__ Wt,
    const float* __restrict__ bias, float* __restrict__ out) {
  __shared__ float Xs[32][132];
  const int t = threadIdx.x;
  const int p0 = blockIdx.x * 32;
  #pragma unroll
  for (int q = 0; q < 4; ++q) {
    const int id = t + q * 256;
    const int r = id >> 5, c4 = (id & 31) * 4;
    const float4 v = *(const float4*)(X + (size_t)(p0 + r) * 128 + c4);
    Xs[r][c4 + 0] = v.x; Xs[r][c4 + 1] = v.y;
    Xs[r][c4 + 2] = v.z; Xs[r][c4 + 3] = v.w;
  }
  __syncthreads();
  const int p = t >> 3, o = t & 7;
  float acc = 0.0f;
  #pragma unroll 8
  for (int i = 0; i < 128; ++i) acc += Wt[o * 128 + i] * Xs[p][i];
  out[(size_t)(p0 + p) * 8 + o] = acc + bias[o];
}

// ---------------------------------------------------------------------------
extern "C" void kernel_launch(void* const* d_in, const int* in_sizes, int n_in,
                              void* d_out, int out_size, void* d_ws,
                              size_t ws_size, hipStream_t stream) {
  const float* x       = (const float*)d_in[0];
  const float* w_emb1  = (const float*)d_in[1];
  const float* g_emb1  = (const float*)d_in[2];
  const float* be_emb1 = (const float*)d_in[3];
  const float* w_emb2  = (const float*)d_in[4];
  const float* g_emb2  = (const float*)d_in[5];
  const float* be_emb2 = (const float*)d_in[6];
  const float* l0_w1 = (const float*)d_in[7];
  const float* l0_g1 = (const float*)d_in[8];
  const float* l0_b1 = (const float*)d_in[9];
  const float* l0_w2 = (const float*)d_in[10];
  const float* l0_g2 = (const float*)d_in[11];
  const float* l0_b2 = (const float*)d_in[12];
  const float* l1_w1 = (const float*)d_in[13];
  const float* l1_g1 = (const float*)d_in[14];
  const float* l1_b1 = (const float*)d_in[15];
  const float* l1_w2 = (const float*)d_in[16];
  const float* l1_g2 = (const float*)d_in[17];
  const float* l1_b2 = (const float*)d_in[18];
  const float* f0_w1 = (const float*)d_in[19];
  const float* f0_g1 = (const float*)d_in[20];
  const float* f0_b1 = (const float*)d_in[21];
  const float* f0_w2 = (const float*)d_in[22];
  const float* f0_g2 = (const float*)d_in[23];
  const float* f0_b2 = (const float*)d_in[24];
  const float* f1_w1 = (const float*)d_in[25];
  const float* f1_g1 = (const float*)d_in[26];
  const float* f1_b1 = (const float*)d_in[27];
  const float* f1_w2 = (const float*)d_in[28];
  const float* f1_g2 = (const float*)d_in[29];
  const float* f1_b2 = (const float*)d_in[30];
  const float* c1_w    = (const float*)d_in[31];
  const float* c1_bias = (const float*)d_in[32];
  const float* c1_g    = (const float*)d_in[33];
  const float* c1_beta = (const float*)d_in[34];
  const float* c2_w    = (const float*)d_in[35];
  const float* c2_bias = (const float*)d_in[36];
  const float* c2_g    = (const float*)d_in[37];
  const float* c2_beta = (const float*)d_in[38];
  const float* out_w    = (const float*)d_in[39];
  const float* out_bias = (const float*)d_in[40];

  if (ws_size < WS_NEED) return;  // cannot run without scratch

  char* ws = (char*)d_ws;
  float* feats0 = (float*)(ws + O_FEATS0);
  float* feats1 = (float*)(ws + O_FEATS1);
  float* feats2 = (float*)(ws + O_FEATS2);
  float* fp0out = (float*)(ws + O_FP0OUT);
  float* xyz1   = (float*)(ws + O_XYZ1);
  float* xyz2   = (float*)(ws + O_XYZ2);
  int*   fps1   = (int*)(ws + O_FPS1);
  int*   fps2   = (int*)(ws + O_FPS2);
  int*   ball1  = (int*)(ws + O_BALL1);
  int*   ball2  = (int*)(ws + O_BALL2);
  int*   nn0i   = (int*)(ws + O_NN0I);
  float* nn0w   = (float*)(ws + O_NN0W);
  int*   nn1i   = (int*)(ws + O_NN1I);
  float* nn1w   = (float*)(ws + O_NN1W);
  float* REG0   = (float*)(ws + O_REG0);
  float* REG1   = (float*)(ws + O_REG1);
  float* outp   = (float*)d_out;
  hipStream_t s = stream;

  // ---- fps1 (+ fused embedding MLP on blocks 4..8195) ----
  fps_emb_kernel<8192, 2048><<<4 + 8192, 256, 0, s>>>(
      x, fps1, xyz1, w_emb1, g_emb1, be_emb1, w_emb2, g_emb2, be_emb2, feats0);

  // ---- fps2 + ball1 + nn1 in ONE launch (all depend only on fps1 outputs;
  //      fps2 blocks are first so they dispatch immediately) ----
  ballnnfps_kernel<<<4 + 2048 + 128, 256, 0, s>>>(
      x, xyz1, ball1, 11, 8192, 2048, x, xyz1, nn1i, nn1w, 13, 2048,
      xyz1, fps2, xyz2);

  // ---- SA layer 1: gather-conv1 -> conv2+segmax ----
  for (int c = 0; c < 2; ++c) {
    conv_gather_kernel<<<dim3(1024, 1), 256, 0, s>>>(
        feats0, ball1, fps1, c * 4096, 64, 11, 8192, l0_w1, REG1, 128, l0_g1,
        l0_b1);
    conv2sm_kernel<<<dim3(1024, 1), 256, 0, s>>>(
        REG1, l0_w2, feats1 + (size_t)c * 4096 * 128, 128, 128, l0_g2, l0_b2);
  }

  // ---- ball2 + nn0 in one launch (need xyz2 from fps2) ----
  ballnn_kernel<<<1024 + 32, 256, 0, s>>>(xyz1, xyz2, ball2, 10, 2048, 1024,
                                          xyz1, xyz2, nn0i, nn0w, 11, 1024);

  // ---- SA layer 2 ----
  for (int c = 0; c < 2; ++c) {
    conv_gather_kernel<<<dim3(512, 2), 256, 0, s>>>(
        feats1, ball2, fps2, c * 2048, 128, 10, 2048, l1_w1, REG1, 256, l1_g1,
        l1_b1);
    conv2sm_kernel<<<dim3(512, 2), 256, 0, s>>>(
        REG1, l1_w2, feats2 + (size_t)c * 2048 * 256, 256, 256, l1_g2, l1_b2);
  }

  // ---- feature propagation 0: 1024 -> 2048 points ----
  concat_interp_kernel<384, 128, 256><<<3072, 256, 0, s>>>(
      REG0, feats1, feats2, nn0i, nn0w, 11, 1024);
  conv_kernel<<<dim3(64, 2), 256, 0, s>>>(REG0, f0_w1, REG1, 384, 256, f0_g1,
                                          f0_b1, nullptr, 1);
  conv_kernel<<<dim3(64, 4), 256, 0, s>>>(REG1, f0_w2, fp0out, 256, 512, f0_g2,
                                          f0_b2, nullptr, 1);

  // ---- feature propagation 1 + head, chunked per 2 batches ----
  for (int b = 0; b < 4; b += 2) {
    concat_interp_kernel<576, 64, 512><<<9216, 256, 0, s>>>(
        REG0, feats0 + (size_t)b * 8192 * 64, fp0out + (size_t)b * 2048 * 512,
        nn1i + (size_t)b * 8192 * 3, nn1w + (size_t)b * 8192 * 3, 13, 2048);
    conv_kernel<<<dim3(128, 4), 256, 0, s>>>(REG0, f1_w1, REG1, 576, 512,
                                             f1_g1, f1_b1, nullptr, 1);
    conv_kernel<<<dim3(128, 8), 256, 0, s>>>(REG1, f1_w2, REG0, 512, 1024,
                                             f1_g2, f1_b2, nullptr, 1);
    conv_kernel<<<dim3(128, 4), 256, 0, s>>>(REG0, c1_w, REG1, 1024, 512,
                                             c1_g, c1_beta, c1_bias, 1);
    conv_kernel<<<dim3(128, 1), 256, 0, s>>>(REG1, c2_w, REG0, 512, 128,
                                             c2_g, c2_beta, c2_bias, 1);
    outfinal_kernel<<<512, 256, 0, s>>>(REG0, out_w, out_bias,
                                        outp + (size_t)b * 8192 * 8);
  }
}